// Round 13
// baseline (336.641 us; speedup 1.0000x reference)
//
#include <hip/hip_runtime.h>

static constexpr int Bc = 4, Tc = 1024, Sc = 1024, Dc = 1024, Hc = 16, DHc = 64, FFc = 4096;

typedef __attribute__((ext_vector_type(8))) short short8;
typedef __attribute__((ext_vector_type(4))) short short4v;
typedef __attribute__((ext_vector_type(4))) float f32x4;

struct P8 { unsigned short* o[8]; };

__device__ __forceinline__ unsigned short f2bf(float f) {
    unsigned int u = __float_as_uint(f);
    unsigned int r = u + 0x7fffu + ((u >> 16) & 1u);
    return (unsigned short)(r >> 16);
}
__device__ __forceinline__ float bf2f(unsigned short u) {
    return __uint_as_float(((unsigned int)u) << 16);
}
__device__ __forceinline__ float fexp2(float x) {
    float r; asm("v_exp_f32 %0, %1" : "=v"(r) : "v"(x)); return r;
}
__device__ __forceinline__ unsigned int cvtpk(float a, float b) {
    unsigned int r;
    asm("v_cvt_pk_bf16_f32 %0, %1, %2" : "=v"(r) : "v"(a), "v"(b));
    return r;
}

__device__ __forceinline__ void gload_lds16(const void* g, void* l) {
    __builtin_amdgcn_global_load_lds((const __attribute__((address_space(1))) void*)g,
                                     (__attribute__((address_space(3))) void*)l, 16, 0, 0);
}

// ---------------- cast f32 -> bf16 (two tensors in one launch) ----------------
__global__ __launch_bounds__(256) void cast2_f32_bf16(const float* __restrict__ inA,
                                                      const float* __restrict__ inB,
                                                      unsigned short* __restrict__ outA,
                                                      unsigned short* __restrict__ outB, int n8) {
    int i = blockIdx.x * 256 + threadIdx.x;
    if (i >= n8) return;
    const float* in = blockIdx.y ? inB : inA;
    unsigned short* out = blockIdx.y ? outB : outA;
    const float4* p = (const float4*)in + (size_t)i * 2;
    float4 a = p[0], b = p[1];
    short8 o;
    o[0] = f2bf(a.x); o[1] = f2bf(a.y); o[2] = f2bf(a.z); o[3] = f2bf(a.w);
    o[4] = f2bf(b.x); o[5] = f2bf(b.y); o[6] = f2bf(b.z); o[7] = f2bf(b.w);
    *(short8*)(out + (size_t)i * 8) = o;
}

// ---------------- transpose + cast: W(K,N) f32 -> Wt(N,K) bf16 ----------------
__global__ __launch_bounds__(256) void transpose_cast(const float* __restrict__ W,
                                                      unsigned short* __restrict__ Wt,
                                                      int K, int N) {
    __shared__ float tile[32][33];
    int n0 = blockIdx.x * 32, k0 = blockIdx.y * 32;
    int tx = threadIdx.x, ty = threadIdx.y;  // (32,8)
#pragma unroll
    for (int i = 0; i < 4; i++)
        tile[ty + i * 8][tx] = W[(size_t)(k0 + ty + i * 8) * N + n0 + tx];
    __syncthreads();
#pragma unroll
    for (int i = 0; i < 4; i++)
        Wt[(size_t)(n0 + ty + i * 8) * K + k0 + tx] = f2bf(tile[tx][ty + i * 8]);
}

// batched version for 8 square 1024x1024 weights (per-matrix output scale)
struct TP8 { const float* s[8]; unsigned short* d[8]; float scl[8]; };
__global__ __launch_bounds__(256) void transpose_cast8(TP8 p) {
    __shared__ float tile[32][33];
    const float* W = p.s[blockIdx.z];
    unsigned short* Wt = p.d[blockIdx.z];
    const float sc = p.scl[blockIdx.z];
    int n0 = blockIdx.x * 32, k0 = blockIdx.y * 32;
    int tx = threadIdx.x, ty = threadIdx.y;
#pragma unroll
    for (int i = 0; i < 4; i++)
        tile[ty + i * 8][tx] = W[(size_t)(k0 + ty + i * 8) * 1024 + n0 + tx];
    __syncthreads();
#pragma unroll
    for (int i = 0; i < 4; i++)
        Wt[(size_t)(n0 + ty + i * 8) * 1024 + k0 + tx] = f2bf(tile[tx][ty + i * 8] * sc);
}

// ---------------- all bias prep in one launch (6144 elems) ----------------
__global__ void prep_bias(const float* dbq, const float* dbk, const float* dbv,
                          const float* ebk, const float* ebv, const float* ebq,
                          float* __restrict__ bqkv, float* __restrict__ bekv,
                          float* __restrict__ ebq_s, float SC) {
    int i = blockIdx.x * 256 + threadIdx.x;
    int seg = i >> 10, j = i & 1023;
    switch (seg) {
        case 0: bqkv[j] = dbq[j] * SC; break;
        case 1: bqkv[1024 + j] = dbk[j]; break;
        case 2: bqkv[2048 + j] = dbv[j]; break;
        case 3: bekv[j] = ebk[j]; break;
        case 4: bekv[1024 + j] = ebv[j]; break;
        default: ebq_s[j] = ebq[j] * SC; break;
    }
}

// ---------------- in-place bf16 add: dst += p1 ----------------
__global__ __launch_bounds__(256) void combine2(unsigned short* __restrict__ dst,
                                                const unsigned short* __restrict__ p1, int n8) {
    int i = blockIdx.x * 256 + threadIdx.x;
    if (i >= n8) return;
    short8 a = *(short8*)(dst + (size_t)i * 8);
    short8 b = *(const short8*)(p1 + (size_t)i * 8);
    short8 o;
#pragma unroll
    for (int j = 0; j < 8; j++)
        o[j] = f2bf(bf2f((unsigned short)a[j]) + bf2f((unsigned short)b[j]));
    *(short8*)(dst + (size_t)i * 8) = o;
}

// ---------------- per-head V transpose ----------------
__global__ __launch_bounds__(256) void transpose_v(const unsigned short* __restrict__ V, int ldv,
                                                   unsigned short* __restrict__ Vt) {
    __shared__ unsigned short t[64 * 64];
    const int bh = blockIdx.y, b = bh >> 4, h = bh & 15;
    const int s0 = blockIdx.x * 64;
    const int tid = threadIdx.x;
    const int r = tid >> 2, ch = tid & 3;
    const unsigned short* src = V + (size_t)(b * 1024 + s0 + r) * ldv + h * 64 + ch * 16;
    short8 v0 = *(const short8*)src;
    short8 v1 = *(const short8*)(src + 8);
    int pw_ = (ch ^ r ^ (r >> 4)) & 3;
    *(short8*)(t + r * 64 + pw_ * 16) = v0;
    *(short8*)(t + r * 64 + pw_ * 16 + 8) = v1;
    __syncthreads();
    const int dh = tid >> 2, sc = (tid & 3) * 16;
    short8 o0, o1;
#pragma unroll
    for (int j = 0; j < 8; j++) {
        int c0 = sc + j, c1 = sc + 8 + j;
        o0[j] = t[c0 * 64 + (((dh >> 4) ^ c0 ^ (c0 >> 4)) & 3) * 16 + (dh & 15)];
        o1[j] = t[c1 * 64 + (((dh >> 4) ^ c1 ^ (c1 >> 4)) & 3) * 16 + (dh & 15)];
    }
    unsigned short* dst = Vt + ((size_t)bh * 64 + dh) * 1024 + s0 + sc;
    *(short8*)dst = o0;
    *(short8*)(dst + 8) = o1;
}

// ---- block remap: chunked-XCD + group-major rasterization (bijective, nwg%8==0) ----
struct BlkMap { int m, n, z; };
__device__ __forceinline__ BlkMap remap_block() {
    const int gx = gridDim.x, gy = gridDim.y;
    const int nxy = gx * gy;
    const int nwg = nxy * gridDim.z;
    const int flat = (blockIdx.z * gy + blockIdx.y) * gx + blockIdx.x;
    const int id = (flat & 7) * (nwg >> 3) + (flat >> 3);
    const int pz = id / nxy;
    const int rz = id - pz * nxy;
    const int gwsh = (gx & 7) ? 2 : 3;       // group width 4 if gx%8!=0, else 8
    const int gw = 1 << gwsh;
    const int gsz = gw * gy;
    const int grp = rz / gsz;
    const int rem = rz - grp * gsz;
    BlkMap r;
    r.m = rem >> gwsh;
    r.n = (grp << gwsh) + (rem & (gw - 1));
    r.z = pz;
    return r;
}

// ================= GEMM 256x256, BK=64, 8 waves, 4-phase interleave (m201-style) ========
// EPI: 0 = bf16 out; 2 = relu+bf16 out; 3 = bf16 split-K partial to po.o[z] (bias only z==0).
template <int EPI>
__global__ __launch_bounds__(512, 2) void gemm256(const unsigned short* __restrict__ A,
                                                  const unsigned short* __restrict__ Bt,
                                                  const float* __restrict__ bias,
                                                  unsigned short* __restrict__ outB,
                                                  int N, int lda, int ldb, int nk, P8 po) {
    __shared__ unsigned short sm[4][16384];  // [0,1]=A dbuf, [2,3]=B dbuf; each 256 rows x 64 bf16
    const int tid = threadIdx.x;
    const int lane = tid & 63, wid = tid >> 6;
    const int l4 = lane & 15, g = lane >> 4;
    const int wr = wid >> 2, wc = wid & 3;   // 2 x 4 wave grid; per-wave out 128x64
    BlkMap bm = remap_block();
    const int m0 = bm.m * 256, n0 = bm.n * 256, z = bm.z;
    A += (size_t)z * (nk * 64);
    Bt += (size_t)z * (nk * 64);
    const int srow = tid >> 3;               // 0..63
    const int schunk = (tid & 7) ^ (srow & 7);
    const int sw = l4 & 7;

    auto stA = [&](int sb, int seg, int k0) {
        gload_lds16(A + (size_t)(m0 + seg * 64 + srow) * lda + k0 + schunk * 8,
                    (char*)sm[sb] + seg * 8192 + tid * 16);
    };
    auto stB = [&](int sb, int seg, int k0) {
        gload_lds16(Bt + (size_t)(n0 + seg * 64 + srow) * ldb + k0 + schunk * 8,
                    (char*)sm[2 + sb] + seg * 8192 + tid * 16);
    };

    f32x4 acc[8][4] = {};
    // prologue: stage tile 0 fully
#pragma unroll
    for (int s = 0; s < 4; s++) stB(0, s, 0);
#pragma unroll
    for (int s = 0; s < 4; s++) stA(0, s, 0);
    asm volatile("s_waitcnt vmcnt(0)" ::: "memory");
    __builtin_amdgcn_s_barrier();

    for (int t = 0; t < nk; ++t) {
        const int bufR = t & 1, bufW = bufR ^ 1;
        const int kn = (t + 1) * 64;
        const bool pf = (t + 1 < nk);
        const unsigned short* As_ = sm[bufR];
        const unsigned short* Bs_ = sm[2 + bufR];
        short8 a[4], b0[4], b1[4];
        // ---- P0: (mh=0, ks=0); stage B seg0,1 of t+1
        if (pf) { stB(bufW, 0, kn); stB(bufW, 1, kn); }
#pragma unroll
        for (int n = 0; n < 4; n++)
            b0[n] = *(const short8*)(Bs_ + (wc * 64 + n * 16 + l4) * 64 + (g ^ sw) * 8);
#pragma unroll
        for (int m = 0; m < 4; m++)
            a[m] = *(const short8*)(As_ + (wr * 128 + m * 16 + l4) * 64 + (g ^ sw) * 8);
        __builtin_amdgcn_s_barrier();
        __builtin_amdgcn_s_setprio(1);
#pragma unroll
        for (int m = 0; m < 4; m++)
#pragma unroll
            for (int n = 0; n < 4; n++)
                acc[m][n] = __builtin_amdgcn_mfma_f32_16x16x32_bf16(a[m], b0[n], acc[m][n], 0, 0, 0);
        __builtin_amdgcn_s_setprio(0);
        __builtin_amdgcn_s_barrier();
        // ---- P1: (mh=0, ks=1); stage B seg2,3
        if (pf) { stB(bufW, 2, kn); stB(bufW, 3, kn); }
#pragma unroll
        for (int n = 0; n < 4; n++)
            b1[n] = *(const short8*)(Bs_ + (wc * 64 + n * 16 + l4) * 64 + ((4 + g) ^ sw) * 8);
#pragma unroll
        for (int m = 0; m < 4; m++)
            a[m] = *(const short8*)(As_ + (wr * 128 + m * 16 + l4) * 64 + ((4 + g) ^ sw) * 8);
        __builtin_amdgcn_s_barrier();
        __builtin_amdgcn_s_setprio(1);
#pragma unroll
        for (int m = 0; m < 4; m++)
#pragma unroll
            for (int n = 0; n < 4; n++)
                acc[m][n] = __builtin_amdgcn_mfma_f32_16x16x32_bf16(a[m], b1[n], acc[m][n], 0, 0, 0);
        __builtin_amdgcn_s_setprio(0);
        // certify A seg1,3 of current tile are resident before P2 reads them
        if (pf) asm volatile("s_waitcnt vmcnt(4)" ::: "memory");
        else    asm volatile("s_waitcnt vmcnt(0)" ::: "memory");
        __builtin_amdgcn_s_barrier();
        // ---- P2: (mh=1, ks=0); stage A seg0,2 (needed first next tile)
        if (pf) { stA(bufW, 0, kn); stA(bufW, 2, kn); }
#pragma unroll
        for (int m = 0; m < 4; m++)
            a[m] = *(const short8*)(As_ + (wr * 128 + 64 + m * 16 + l4) * 64 + (g ^ sw) * 8);
        __builtin_amdgcn_s_barrier();
        __builtin_amdgcn_s_setprio(1);
#pragma unroll
        for (int m = 0; m < 4; m++)
#pragma unroll
            for (int n = 0; n < 4; n++)
                acc[4 + m][n] = __builtin_amdgcn_mfma_f32_16x16x32_bf16(a[m], b0[n], acc[4 + m][n], 0, 0, 0);
        __builtin_amdgcn_s_setprio(0);
        __builtin_amdgcn_s_barrier();
        // ---- P3: (mh=1, ks=1); stage A seg1,3
        if (pf) { stA(bufW, 1, kn); stA(bufW, 3, kn); }
#pragma unroll
        for (int m = 0; m < 4; m++)
            a[m] = *(const short8*)(As_ + (wr * 128 + 64 + m * 16 + l4) * 64 + ((4 + g) ^ sw) * 8);
        __builtin_amdgcn_s_barrier();
        __builtin_amdgcn_s_setprio(1);
#pragma unroll
        for (int m = 0; m < 4; m++)
#pragma unroll
            for (int n = 0; n < 4; n++)
                acc[4 + m][n] = __builtin_amdgcn_mfma_f32_16x16x32_bf16(a[m], b1[n], acc[4 + m][n], 0, 0, 0);
        __builtin_amdgcn_s_setprio(0);
        // certify B0-3 + A0,2 of t+1 (oldest 6 of 8 in flight) before next P0
        if (pf) asm volatile("s_waitcnt vmcnt(2)" ::: "memory");
        __builtin_amdgcn_s_barrier();
    }
    // ---- coalesced epilogue via LDS staging (half-tile at a time) ----
    unsigned short* eb = (unsigned short*)sm;   // 128KB scratch, free after K-loop
    unsigned short* oB = (EPI == 3) ? po.o[z] : outB;
    const int colL = wc * 64 + l4;              // local col (0..255), per-lane
#pragma unroll
    for (int h = 0; h < 2; ++h) {
        if (wr == h) {
#pragma unroll
            for (int mm = 0; mm < 8; mm++) {
                const int base_r = (mm < 4 ? mm * 16 : 64 + (mm - 4) * 16) + g * 4;
#pragma unroll
                for (int n = 0; n < 4; n++) {
                    float bv = (EPI == 3 && z != 0) ? 0.f : bias[n0 + colL + n * 16];
#pragma unroll
                    for (int r = 0; r < 4; r++) {
                        float v = acc[mm][n][r] + bv;
                        if (EPI == 2) v = fmaxf(v, 0.f);
                        eb[(base_r + r) * 260 + colL + n * 16] = f2bf(v);
                    }
                }
            }
        }
        __syncthreads();
        const int gr0 = m0 + h * 128;
#pragma unroll
        for (int j = 0; j < 8; j++) {
            const int f = j * 8192 + tid * 16;      // byte offset in [128][512B] image
            const int row = f >> 9;
            const int colb = f & 511;
            short8 v = *(const short8*)((const char*)eb + row * 520 + colb);
            *(short8*)(oB + (size_t)(gr0 + row) * N + n0 + (colb >> 1)) = v;
        }
        if (h == 0) __syncthreads();                // before overwriting LDS for half 2
    }
}

// ---------------- GEMM 64x128: 3-buffer depth-2, counted vmcnt, XCD-swizzled ----------------
template <int EPI>
__global__ __launch_bounds__(256) void gemm64_db(const unsigned short* __restrict__ A,
                                                 const unsigned short* __restrict__ Bt,
                                                 const float* __restrict__ bias,
                                                 float* __restrict__ outF,
                                                 unsigned short* __restrict__ outB,
                                                 int M, int N, int Kloop, int lda, int ldb) {
    __shared__ unsigned short As[3][64 * 32];
    __shared__ unsigned short Bs[3][128 * 32];
    const int tid = threadIdx.x;
    const int w = tid >> 6, lane = tid & 63, l4 = lane & 15, g = lane >> 4;
    BlkMap bm = remap_block();
    const int m0 = bm.m * 64, n0 = bm.n * 128;
    f32x4 acc[4][2] = {};
    const int r0 = tid >> 2;
    const int kk = ((tid & 3) ^ ((tid >> 3) & 3)) * 8;
    const int sk = (l4 >> 1) & 3;
    const unsigned short* Ar0 = A + (size_t)(m0 + r0) * lda + kk;
    const unsigned short* Br0 = Bt + (size_t)(n0 + r0) * ldb + kk;
    const unsigned short* Br1 = Bt + (size_t)(n0 + 64 + r0) * ldb + kk;
    auto stage = [&](int sb, int k0) {
        gload_lds16(Ar0 + k0, (char*)As[sb] + tid * 16);
        gload_lds16(Br0 + k0, (char*)Bs[sb] + tid * 16);
        gload_lds16(Br1 + k0, (char*)Bs[sb] + 4096 + tid * 16);
    };
    const int nk = Kloop >> 5;
    stage(0, 0);
    stage(1, 32);
    asm volatile("s_waitcnt vmcnt(3)" ::: "memory");
    __builtin_amdgcn_s_barrier();
    asm volatile("" ::: "memory");
    int buf = 0;
    for (int t = 0; t < nk; ++t) {
        if (t + 2 < nk) {
            int b2 = buf + 2; if (b2 >= 3) b2 -= 3;
            stage(b2, (t + 2) * 32);
        }
        short8 a[4], b[2];
#pragma unroll
        for (int m = 0; m < 4; m++)
            a[m] = *(const short8*)(As[buf] + (m * 16 + l4) * 32 + (g ^ sk) * 8);
#pragma unroll
        for (int n = 0; n < 2; n++)
            b[n] = *(const short8*)(Bs[buf] + (w * 32 + n * 16 + l4) * 32 + (g ^ sk) * 8);
#pragma unroll
        for (int m = 0; m < 4; m++)
#pragma unroll
            for (int n = 0; n < 2; n++)
                acc[m][n] = __builtin_amdgcn_mfma_f32_16x16x32_bf16(a[m], b[n], acc[m][n], 0, 0, 0);
        if (t + 1 < nk) {
            if (t + 2 < nk) asm volatile("s_waitcnt vmcnt(3)" ::: "memory");
            else            asm volatile("s_waitcnt vmcnt(0)" ::: "memory");
            __builtin_amdgcn_s_barrier();
            asm volatile("" ::: "memory");
        }
        buf = (buf + 1 == 3) ? 0 : buf + 1;
    }
    const int rowB = m0 + g * 4;
    const int colB = n0 + w * 32 + l4;
#pragma unroll
    for (int n = 0; n < 2; n++) {
        float bv = bias[colB + n * 16];
#pragma unroll
        for (int m = 0; m < 4; m++) {
#pragma unroll
            for (int r = 0; r < 4; r++) {
                float v = acc[m][n][r] + bv;
                if (EPI == 2) v = fmaxf(v, 0.f);
                size_t idx = (size_t)(rowB + m * 16 + r) * N + colB + n * 16;
                if (EPI == 1) outF[idx] = v;
                else outB[idx] = f2bf(v);
            }
        }
    }
}

// ---------------- flash attention v6: 8 waves / 128 q-rows per block ----------------
template <int CAUSAL>
__global__ __launch_bounds__(512) void attn6_kernel(const unsigned short* __restrict__ Q, int ldq,
                                                    const unsigned short* __restrict__ Kg, int ldk,
                                                    const unsigned short* __restrict__ Vt,
                                                    unsigned short* __restrict__ O) {
    __shared__ unsigned short Kl[2 * 64 * 64];
    __shared__ unsigned short Vl[2 * 64 * 64];
    __shared__ unsigned short Pl[8][16 * 72];
    const int bh = blockIdx.x;
    const int qb = CAUSAL ? (gridDim.y - 1 - blockIdx.y) : blockIdx.y;
    const int b = bh >> 4, h = bh & 15;
    const int tid = threadIdx.x, w = tid >> 6, lane = tid & 63;
    const int l4 = lane & 15, g = lane >> 4;
    const int q0 = qb * 128 + w * 16;
    const unsigned short* Qp = Q + (size_t)(b * Tc + q0 + l4) * ldq + h * DHc + g * 8;
    short8 qf0 = *(const short8*)Qp;
    short8 qf1 = *(const short8*)(Qp + 32);
    const unsigned short* Kbase = Kg + (size_t)(b * 1024) * ldk + h * DHc;
    const unsigned short* Vbase = Vt + (size_t)bh * DHc * 1024;
    f32x4 o[4] = {};
    float mrun = -1e30f, lrun = 0.f;
    const int nT = CAUSAL ? 2 * qb + 2 : 16;
    unsigned short* pw = &Pl[w][l4 * 72];
    const int qi = q0 + l4;

    short8 ones;
#pragma unroll
    for (int j = 0; j < 8; j++) ones[j] = (short)0x3F80;  // bf16 1.0

    const int sr = tid >> 3;                 // 0..63
    const int sc_ = (tid & 7) ^ (sr & 7);

    auto stage = [&](int s0, int buf) {
        char* kd = (char*)Kl + buf * 8192;
        char* vd = (char*)Vl + buf * 8192;
        gload_lds16(Kbase + (size_t)(s0 + sr) * ldk + sc_ * 8, kd + tid * 16);
        gload_lds16(Vbase + (size_t)sr * 1024 + s0 + sc_ * 8, vd + tid * 16);
    };

    stage(0, 0);
    __syncthreads();
    int buf = 0;
    const int sw = l4 & 7;

    for (int t = 0; t < nT; ++t) {
        const int s0 = t * 64;
        if (t + 1 < nT) stage(s0 + 64, buf ^ 1);
        if (!CAUSAL || s0 <= q0 + 15) {
            const unsigned short* Kb_ = Kl + buf * 4096;
            const unsigned short* Vb_ = Vl + buf * 4096;
            f32x4 st[4];
            f32x4 z = {0.f, 0.f, 0.f, 0.f};
            __builtin_amdgcn_s_setprio(1);
#pragma unroll
            for (int c = 0; c < 4; c++) {
                const unsigned short* kr = Kb_ + (c * 16 + l4) * 64;
                short8 ka0 = *(const short8*)(kr + ((g ^ sw) * 8));
                short8 ka1 = *(const short8*)(kr + (((g + 4) ^ sw) * 8));
                st[c] = __builtin_amdgcn_mfma_f32_16x16x32_bf16(ka0, qf0, z, 0, 0, 0);
                st[c] = __builtin_amdgcn_mfma_f32_16x16x32_bf16(ka1, qf1, st[c], 0, 0, 0);
            }
            __builtin_amdgcn_s_setprio(0);
            float p[16];
            const bool domask = CAUSAL && (s0 + 63 > q0);
#pragma unroll
            for (int c = 0; c < 4; c++)
#pragma unroll
                for (int r = 0; r < 4; r++) {
                    float v = st[c][r];
                    if (domask && (s0 + c * 16 + g * 4 + r) > qi) v = -1e9f;
                    p[c * 4 + r] = v;
                }
            float m1 = fmaxf(fmaxf(p[0], p[1]), p[2]);
            float m2 = fmaxf(fmaxf(p[3], p[4]), p[5]);
            float m3 = fmaxf(fmaxf(p[6], p[7]), p[8]);
            float m4 = fmaxf(fmaxf(p[9], p[10]), p[11]);
            float m5 = fmaxf(fmaxf(p[12], p[13]), p[14]);
            float tmax = fmaxf(fmaxf(fmaxf(m1, m2), fmaxf(m3, m4)), fmaxf(m5, p[15]));
            tmax = fmaxf(tmax, __shfl_xor(tmax, 16));
            tmax = fmaxf(tmax, __shfl_xor(tmax, 32));
            if (!__all(tmax <= mrun + 11.5f)) {
                float mnew = fmaxf(mrun, tmax);
                float al = fexp2(mrun - mnew);
                lrun *= al;
#pragma unroll
                for (int d = 0; d < 4; d++) o[d] *= al;
                mrun = mnew;
            }
#pragma unroll
            for (int i = 0; i < 16; i++) p[i] = fexp2(p[i] - mrun);
#pragma unroll
            for (int c = 0; c < 4; c++) {
                uint2 u;
                u.x = cvtpk(p[c * 4 + 0], p[c * 4 + 1]);
                u.y = cvtpk(p[c * 4 + 2], p[c * 4 + 3]);
                *(uint2*)(pw + c * 16 + g * 4) = u;
            }
            short8 pb_lo = *(const short8*)(pw + g * 8);
            short8 pb_hi = *(const short8*)(pw + 32 + g * 8);
            __builtin_amdgcn_s_setprio(1);
            f32x4 s4 = __builtin_amdgcn_mfma_f32_16x16x32_bf16(ones, pb_lo, z, 0, 0, 0);
            s4 = __builtin_amdgcn_mfma_f32_16x16x32_bf16(ones, pb_hi, s4, 0, 0, 0);
#pragma unroll
            for (int d = 0; d < 4; d++) {
                const unsigned short* vr = Vb_ + (d * 16 + l4) * 64;
                short8 va0 = *(const short8*)(vr + ((g ^ sw) * 8));
                short8 va1 = *(const short8*)(vr + (((g + 4) ^ sw) * 8));
                o[d] = __builtin_amdgcn_mfma_f32_16x16x32_bf16(va0, pb_lo, o[d], 0, 0, 0);
                o[d] = __builtin_amdgcn_mfma_f32_16x16x32_bf16(va1, pb_hi, o[d], 0, 0, 0);
            }
            __builtin_amdgcn_s_setprio(0);
            lrun += s4[0];
        }
        __syncthreads();
        buf ^= 1;
    }
    float inv = 1.f / lrun;
    unsigned short* Ob = O + (size_t)(b * Tc + q0 + l4) * Dc + h * DHc;
#pragma unroll
    for (int d = 0; d < 4; d++) {
#pragma unroll
        for (int r = 0; r < 4; r++) Ob[d * 16 + g * 4 + r] = f2bf(o[d][r] * inv);
    }
}

// ---------------- fused residual-add + LayerNorm (bf16 a + bf16 res) ----------------
__global__ __launch_bounds__(256) void ln_bf(const unsigned short* __restrict__ a,
                                             const unsigned short* __restrict__ res,
                                             const float* __restrict__ gam,
                                             const float* __restrict__ bet,
                                             unsigned short* __restrict__ outB,
                                             float* __restrict__ outF) {
    int row = blockIdx.x, t = threadIdx.x;
    size_t base = (size_t)row * Dc + t * 4;
    short4v av = *(const short4v*)(a + base);
    short4v rv = *(const short4v*)(res + base);
    float x0 = bf2f((unsigned short)av[0]) + bf2f((unsigned short)rv[0]);
    float x1 = bf2f((unsigned short)av[1]) + bf2f((unsigned short)rv[1]);
    float x2 = bf2f((unsigned short)av[2]) + bf2f((unsigned short)rv[2]);
    float x3 = bf2f((unsigned short)av[3]) + bf2f((unsigned short)rv[3]);
    float s = x0 + x1 + x2 + x3;
    float ss = x0 * x0 + x1 * x1 + x2 * x2 + x3 * x3;
    for (int o = 1; o < 64; o <<= 1) { s += __shfl_xor(s, o); ss += __shfl_xor(ss, o); }
    __shared__ float S1[4], S2[4];
    int w = t >> 6;
    if ((t & 63) == 0) { S1[w] = s; S2[w] = ss; }
    __syncthreads();
    s = S1[0] + S1[1] + S1[2] + S1[3];
    ss = S2[0] + S2[1] + S2[2] + S2[3];
    float mean = s * (1.f / Dc);
    float var = ss * (1.f / Dc) - mean * mean;
    float rstd = rsqrtf(var + 1e-5f);
    int c = t * 4;
    float4 g4 = *(const float4*)(gam + c);
    float4 b4 = *(const float4*)(bet + c);
    float y0 = (x0 - mean) * rstd * g4.x + b4.x;
    float y1 = (x1 - mean) * rstd * g4.y + b4.y;
    float y2 = (x2 - mean) * rstd * g4.z + b4.z;
    float y3 = (x3 - mean) * rstd * g4.w + b4.w;
    if (outB) {
        short4v ob;
        ob[0] = f2bf(y0); ob[1] = f2bf(y1); ob[2] = f2bf(y2); ob[3] = f2bf(y3);
        *(short4v*)(outB + base) = ob;
    }
    if (outF) { float4 ov = {y0, y1, y2, y3}; *(float4*)(outF + base) = ov; }
}

// ---------------- LN over 4 bf16 split-K partials + bf16 residual -> f32 out ----------------
__global__ __launch_bounds__(256) void ln_4b(const unsigned short* __restrict__ p,
                                             const unsigned short* __restrict__ res,
                                             const float* __restrict__ gam,
                                             const float* __restrict__ bet,
                                             float* __restrict__ outF) {
    const size_t PS = (size_t)4096 * 1024;   // partial stride (M*N)
    int row = blockIdx.x, t = threadIdx.x;
    size_t base = (size_t)row * Dc + t * 4;
    float x0, x1, x2, x3;
    {
        short4v rv = *(const short4v*)(res + base);
        x0 = bf2f((unsigned short)rv[0]); x1 = bf2f((unsigned short)rv[1]);
        x2 = bf2f((unsigned short)rv[2]); x3 = bf2f((unsigned short)rv[3]);
    }
#pragma unroll
    for (int j = 0; j < 4; j++) {
        short4v v = *(const short4v*)(p + j * PS + base);
        x0 += bf2f((unsigned short)v[0]); x1 += bf2f((unsigned short)v[1]);
        x2 += bf2f((unsigned short)v[2]); x3 += bf2f((unsigned short)v[3]);
    }
    float s = x0 + x1 + x2 + x3;
    float ss = x0 * x0 + x1 * x1 + x2 * x2 + x3 * x3;
    for (int o = 1; o < 64; o <<= 1) { s += __shfl_xor(s, o); ss += __shfl_xor(ss, o); }
    __shared__ float S1[4], S2[4];
    int w = t >> 6;
    if ((t & 63) == 0) { S1[w] = s; S2[w] = ss; }
    __syncthreads();
    s = S1[0] + S1[1] + S1[2] + S1[3];
    ss = S2[0] + S2[1] + S2[2] + S2[3];
    float mean = s * (1.f / Dc);
    float var = ss * (1.f / Dc) - mean * mean;
    float rstd = rsqrtf(var + 1e-5f);
    int c = t * 4;
    float4 g4 = *(const float4*)(gam + c);
    float4 b4 = *(const float4*)(bet + c);
    float4 ov;
    ov.x = (x0 - mean) * rstd * g4.x + b4.x;
    ov.y = (x1 - mean) * rstd * g4.y + b4.y;
    ov.z = (x2 - mean) * rstd * g4.z + b4.z;
    ov.w = (x3 - mean) * rstd * g4.w + b4.w;
    *(float4*)(outF + base) = ov;
}

// ---------------- launch ----------------
extern "C" void kernel_launch(void* const* d_in, const int* in_sizes, int n_in,
                              void* d_out, int out_size, void* d_ws, size_t ws_size,
                              hipStream_t stream) {
    const float* x   = (const float*)d_in[0];
    const float* enc = (const float*)d_in[1];
    const float* dWq = (const float*)d_in[4];  const float* dbq = (const float*)d_in[5];
    const float* dWk = (const float*)d_in[6];  const float* dbk = (const float*)d_in[7];
    const float* dWv = (const float*)d_in[8];  const float* dbv = (const float*)d_in[9];
    const float* dWo = (const float*)d_in[10]; const float* dbo = (const float*)d_in[11];
    const float* eWq = (const float*)d_in[12]; const float* ebq = (const float*)d_in[13];
    const float* eWk = (const float*)d_in[14]; const float* ebk = (const float*)d_in[15];
    const float* eWv = (const float*)d_in[16]; const float* ebv = (const float*)d_in[17];
    const float* eWo = (const float*)d_in[18]; const float* ebo = (const float*)d_in[19];
    const float* fW1 = (const float*)d_in[20]; const float* fb1 = (const float*)d_in[21];
    const float* fW2 = (const float*)d_in[22]; const float* fb2 = (const float*)d_in[23];
    const float* g1 = (const float*)d_in[24];  const float* be1 = (const float*)d_in[25];
    const float* g2 = (const float*)d_in[26];  const float* be2 = (const float*)d_in[27];
    const float* g3 = (const float*)d_in[28];  const float* be3 = (const float*)d_in[29];

    const float SC = 0.125f * 1.44269504f;   // softmax scale folded to exp2 domain

    char* ws = (char*)d_ws;
    size_t off = 0;
    auto alloc = [&](size_t bytes) -> void* {
        void* p = ws + off;
        off += (bytes + 255) & ~(size_t)255;
        return p;
    };
    const size_t A = (size_t)4096 * 1024;
    const size_t MB1 = (size_t)1024 * 1024;
    char* R1 = (char*)alloc(32 * 1024 * 1024);
    unsigned short* qkv = (unsigned short*)R1;                       // stride 3072
    unsigned short* kvx = (unsigned short*)R1;                       // stride 2048 (after qkv dead)
    unsigned short* qx  = (unsigned short*)(R1 + 16 * 1024 * 1024);  // stride 1024
    unsigned short* h1  = (unsigned short*)R1;                       // 4096x4096
    unsigned short* xb   = (unsigned short*)alloc(A * 2);
    unsigned short* encb = (unsigned short*)alloc(A * 2);
    unsigned short* wqkv = (unsigned short*)alloc(3 * MB1 * 2);
    unsigned short* wekv = (unsigned short*)alloc(2 * MB1 * 2);
    unsigned short* weq  = (unsigned short*)alloc(MB1 * 2);
    unsigned short* wdo  = (unsigned short*)alloc(MB1 * 2);
    unsigned short* weo  = (unsigned short*)alloc(MB1 * 2);
    unsigned short* wf1  = (unsigned short*)alloc(4 * MB1 * 2);
    unsigned short* wf2  = (unsigned short*)alloc(4 * MB1 * 2);
    float* bqkv = (float*)alloc(3072 * 4);
    float* bekv = (float*)alloc(2048 * 4);
    float* ebq_s = (float*)alloc(1024 * 4);
    unsigned short* VtB = (unsigned short*)alloc(A * 2);
    unsigned short* ab  = (unsigned short*)alloc(A * 2);
    unsigned short* tmpB = (unsigned short*)alloc(A * 2);
    unsigned short* dB = (unsigned short*)alloc(A * 2);
    unsigned short* fB = (unsigned short*)alloc(A * 2);
    // FFN2 split-K4 bf16 partials alias [VtB, ab, tmpB, dB] (free in FFN phase)
    unsigned short* pfb = VtB;
    (void)ws_size; (void)in_sizes; (void)n_in; (void)out_size;

    dim3 tb(32, 8);
    cast2_f32_bf16<<<dim3(2048, 2), 256, 0, stream>>>(x, enc, xb, encb, (int)(A / 8));
    TP8 tp;
    tp.s[0] = dWq; tp.d[0] = wqkv;           tp.scl[0] = SC;    // Q pre-scaled
    tp.s[1] = dWk; tp.d[1] = wqkv + MB1;     tp.scl[1] = 1.f;
    tp.s[2] = dWv; tp.d[2] = wqkv + 2 * MB1; tp.scl[2] = 1.f;
    tp.s[3] = eWk; tp.d[3] = wekv;           tp.scl[3] = 1.f;
    tp.s[4] = eWv; tp.d[4] = wekv + MB1;     tp.scl[4] = 1.f;
    tp.s[5] = eWq; tp.d[5] = weq;            tp.scl[5] = SC;    // cross Q pre-scaled
    tp.s[6] = dWo; tp.d[6] = wdo;            tp.scl[6] = 1.f;
    tp.s[7] = eWo; tp.d[7] = weo;            tp.scl[7] = 1.f;
    transpose_cast8<<<dim3(32, 32, 8), tb, 0, stream>>>(tp);
    transpose_cast<<<dim3(128, 32), tb, 0, stream>>>(fW1, wf1, 1024, 4096);
    transpose_cast<<<dim3(32, 128), tb, 0, stream>>>(fW2, wf2, 4096, 1024);
    prep_bias<<<24, 256, 0, stream>>>(dbq, dbk, dbv, ebk, ebv, ebq, bqkv, bekv, ebq_s, SC);

    P8 z8{};

    // ---- self-attention block ----
    gemm256<0><<<dim3(12, 16), 512, 0, stream>>>(xb, wqkv, bqkv, qkv, 3072, 1024, 1024, 16, z8);
    transpose_v<<<dim3(16, 64), 256, 0, stream>>>(qkv + 2048, 3072, VtB);
    attn6_kernel<1><<<dim3(64, 8), 512, 0, stream>>>(qkv, 3072, qkv + 1024, 3072, VtB, ab);
    gemm64_db<0><<<dim3(8, 64), 256, 0, stream>>>(ab, wdo, dbo, nullptr, tmpB, 4096, 1024, 1024, 1024, 1024);
    ln_bf<<<4096, 256, 0, stream>>>(tmpB, xb, g1, be1, dB, nullptr);

    // ---- cross-attention block ----
    // eKV split-K2: full 256-block grid; p0 = kvx (w/ bias), p1 = [VtB..ab] scratch
    {
        P8 pe{};
        pe.o[0] = kvx;
        pe.o[1] = VtB;
        gemm256<3><<<dim3(8, 16, 2), 512, 0, stream>>>(encb, wekv, bekv, nullptr, 2048, 1024, 1024, 8, pe);
        combine2<<<4096, 256, 0, stream>>>(kvx, VtB, (int)((size_t)4096 * 2048 / 8));
    }
    gemm64_db<0><<<dim3(8, 64), 256, 0, stream>>>(dB, weq, ebq_s, nullptr, qx, 4096, 1024, 1024, 1024, 1024);
    transpose_v<<<dim3(16, 64), 256, 0, stream>>>(kvx + 1024, 2048, VtB);
    attn6_kernel<0><<<dim3(64, 8), 512, 0, stream>>>(qx, 1024, kvx, 2048, VtB, ab);
    gemm64_db<0><<<dim3(8, 64), 256, 0, stream>>>(ab, weo, ebo, nullptr, tmpB, 4096, 1024, 1024, 1024, 1024);
    ln_bf<<<4096, 256, 0, stream>>>(tmpB, dB, g2, be2, fB, nullptr);

    // ---- FFN block ----
    gemm256<2><<<dim3(16, 16), 512, 0, stream>>>(fB, wf1, fb1, h1, 4096, 1024, 1024, 16, z8);
    {
        P8 pf{};
        pf.o[0] = pfb;
        pf.o[1] = pfb + A;
        pf.o[2] = pfb + 2 * A;
        pf.o[3] = pfb + 3 * A;
        gemm256<3><<<dim3(4, 16, 4), 512, 0, stream>>>(h1, wf2, fb2, nullptr, 1024, 4096, 4096, 16, pf);
    }
    ln_4b<<<4096, 256, 0, stream>>>(pfb, fB, g3, be3, (float*)d_out);
}

// Round 14
// 330.173 us; speedup vs baseline: 1.0196x; 1.0196x over previous
//
#include <hip/hip_runtime.h>

static constexpr int Bc = 4, Tc = 1024, Sc = 1024, Dc = 1024, Hc = 16, DHc = 64, FFc = 4096;

typedef __attribute__((ext_vector_type(8))) short short8;
typedef __attribute__((ext_vector_type(4))) short short4v;
typedef __attribute__((ext_vector_type(4))) float f32x4;

struct P8 { unsigned short* o[8]; };

__device__ __forceinline__ unsigned short f2bf(float f) {
    unsigned int u = __float_as_uint(f);
    unsigned int r = u + 0x7fffu + ((u >> 16) & 1u);
    return (unsigned short)(r >> 16);
}
__device__ __forceinline__ float bf2f(unsigned short u) {
    return __uint_as_float(((unsigned int)u) << 16);
}
__device__ __forceinline__ float fexp2(float x) {
    float r; asm("v_exp_f32 %0, %1" : "=v"(r) : "v"(x)); return r;
}
__device__ __forceinline__ unsigned int cvtpk(float a, float b) {
    unsigned int r;
    asm("v_cvt_pk_bf16_f32 %0, %1, %2" : "=v"(r) : "v"(a), "v"(b));
    return r;
}

__device__ __forceinline__ void gload_lds16(const void* g, void* l) {
    __builtin_amdgcn_global_load_lds((const __attribute__((address_space(1))) void*)g,
                                     (__attribute__((address_space(3))) void*)l, 16, 0, 0);
}

// ---------------- cast f32 -> bf16 (two tensors in one launch) ----------------
__global__ __launch_bounds__(256) void cast2_f32_bf16(const float* __restrict__ inA,
                                                      const float* __restrict__ inB,
                                                      unsigned short* __restrict__ outA,
                                                      unsigned short* __restrict__ outB, int n8) {
    int i = blockIdx.x * 256 + threadIdx.x;
    if (i >= n8) return;
    const float* in = blockIdx.y ? inB : inA;
    unsigned short* out = blockIdx.y ? outB : outA;
    const float4* p = (const float4*)in + (size_t)i * 2;
    float4 a = p[0], b = p[1];
    short8 o;
    o[0] = f2bf(a.x); o[1] = f2bf(a.y); o[2] = f2bf(a.z); o[3] = f2bf(a.w);
    o[4] = f2bf(b.x); o[5] = f2bf(b.y); o[6] = f2bf(b.z); o[7] = f2bf(b.w);
    *(short8*)(out + (size_t)i * 8) = o;
}

// ---------------- transpose + cast: W(K,N) f32 -> Wt(N,K) bf16 ----------------
__global__ __launch_bounds__(256) void transpose_cast(const float* __restrict__ W,
                                                      unsigned short* __restrict__ Wt,
                                                      int K, int N) {
    __shared__ float tile[32][33];
    int n0 = blockIdx.x * 32, k0 = blockIdx.y * 32;
    int tx = threadIdx.x, ty = threadIdx.y;  // (32,8)
#pragma unroll
    for (int i = 0; i < 4; i++)
        tile[ty + i * 8][tx] = W[(size_t)(k0 + ty + i * 8) * N + n0 + tx];
    __syncthreads();
#pragma unroll
    for (int i = 0; i < 4; i++)
        Wt[(size_t)(n0 + ty + i * 8) * K + k0 + tx] = f2bf(tile[tx][ty + i * 8]);
}

// batched version for 8 square 1024x1024 weights (per-matrix output scale)
struct TP8 { const float* s[8]; unsigned short* d[8]; float scl[8]; };
__global__ __launch_bounds__(256) void transpose_cast8(TP8 p) {
    __shared__ float tile[32][33];
    const float* W = p.s[blockIdx.z];
    unsigned short* Wt = p.d[blockIdx.z];
    const float sc = p.scl[blockIdx.z];
    int n0 = blockIdx.x * 32, k0 = blockIdx.y * 32;
    int tx = threadIdx.x, ty = threadIdx.y;
#pragma unroll
    for (int i = 0; i < 4; i++)
        tile[ty + i * 8][tx] = W[(size_t)(k0 + ty + i * 8) * 1024 + n0 + tx];
    __syncthreads();
#pragma unroll
    for (int i = 0; i < 4; i++)
        Wt[(size_t)(n0 + ty + i * 8) * 1024 + k0 + tx] = f2bf(tile[tx][ty + i * 8] * sc);
}

// ---------------- all bias prep in one launch (6144 elems) ----------------
__global__ void prep_bias(const float* dbq, const float* dbk, const float* dbv,
                          const float* ebk, const float* ebv, const float* ebq,
                          float* __restrict__ bqkv, float* __restrict__ bekv,
                          float* __restrict__ ebq_s, float SC) {
    int i = blockIdx.x * 256 + threadIdx.x;
    int seg = i >> 10, j = i & 1023;
    switch (seg) {
        case 0: bqkv[j] = dbq[j] * SC; break;
        case 1: bqkv[1024 + j] = dbk[j]; break;
        case 2: bqkv[2048 + j] = dbv[j]; break;
        case 3: bekv[j] = ebk[j]; break;
        case 4: bekv[1024 + j] = ebv[j]; break;
        default: ebq_s[j] = ebq[j] * SC; break;
    }
}

// ---------------- in-place bf16 add: dst += p1 ----------------
__global__ __launch_bounds__(256) void combine2(unsigned short* __restrict__ dst,
                                                const unsigned short* __restrict__ p1, int n8) {
    int i = blockIdx.x * 256 + threadIdx.x;
    if (i >= n8) return;
    short8 a = *(short8*)(dst + (size_t)i * 8);
    short8 b = *(const short8*)(p1 + (size_t)i * 8);
    short8 o;
#pragma unroll
    for (int j = 0; j < 8; j++)
        o[j] = f2bf(bf2f((unsigned short)a[j]) + bf2f((unsigned short)b[j]));
    *(short8*)(dst + (size_t)i * 8) = o;
}

// ---------------- per-head V transpose ----------------
__global__ __launch_bounds__(256) void transpose_v(const unsigned short* __restrict__ V, int ldv,
                                                   unsigned short* __restrict__ Vt) {
    __shared__ unsigned short t[64 * 64];
    const int bh = blockIdx.y, b = bh >> 4, h = bh & 15;
    const int s0 = blockIdx.x * 64;
    const int tid = threadIdx.x;
    const int r = tid >> 2, ch = tid & 3;
    const unsigned short* src = V + (size_t)(b * 1024 + s0 + r) * ldv + h * 64 + ch * 16;
    short8 v0 = *(const short8*)src;
    short8 v1 = *(const short8*)(src + 8);
    int pw_ = (ch ^ r ^ (r >> 4)) & 3;
    *(short8*)(t + r * 64 + pw_ * 16) = v0;
    *(short8*)(t + r * 64 + pw_ * 16 + 8) = v1;
    __syncthreads();
    const int dh = tid >> 2, sc = (tid & 3) * 16;
    short8 o0, o1;
#pragma unroll
    for (int j = 0; j < 8; j++) {
        int c0 = sc + j, c1 = sc + 8 + j;
        o0[j] = t[c0 * 64 + (((dh >> 4) ^ c0 ^ (c0 >> 4)) & 3) * 16 + (dh & 15)];
        o1[j] = t[c1 * 64 + (((dh >> 4) ^ c1 ^ (c1 >> 4)) & 3) * 16 + (dh & 15)];
    }
    unsigned short* dst = Vt + ((size_t)bh * 64 + dh) * 1024 + s0 + sc;
    *(short8*)dst = o0;
    *(short8*)(dst + 8) = o1;
}

// ---- block remap: chunked-XCD + group-major rasterization (bijective, nwg%8==0) ----
struct BlkMap { int m, n, z; };
__device__ __forceinline__ BlkMap remap_block() {
    const int gx = gridDim.x, gy = gridDim.y;
    const int nxy = gx * gy;
    const int nwg = nxy * gridDim.z;
    const int flat = (blockIdx.z * gy + blockIdx.y) * gx + blockIdx.x;
    const int id = (flat & 7) * (nwg >> 3) + (flat >> 3);
    const int pz = id / nxy;
    const int rz = id - pz * nxy;
    const int gwsh = (gx & 7) ? 2 : 3;       // group width 4 if gx%8!=0, else 8
    const int gw = 1 << gwsh;
    const int gsz = gw * gy;
    const int grp = rz / gsz;
    const int rem = rz - grp * gsz;
    BlkMap r;
    r.m = rem >> gwsh;
    r.n = (grp << gwsh) + (rem & (gw - 1));
    r.z = pz;
    return r;
}

// ================= GEMM 256x256, BK=64, 8 waves, single-barrier K-tile ==================
// EPI: 0 = bf16 out; 2 = relu+bf16 out; 3 = bf16 split-K partial to po.o[z] (bias only z==0).
// One vmcnt(0)+barrier per K-tile; all fragment reads + 64 MFMA in one region so the
// compiler's fine-grained lgkmcnt scheduling overlaps LDS reads with MFMA.
template <int EPI>
__global__ __launch_bounds__(512, 2) void gemm256(const unsigned short* __restrict__ A,
                                                  const unsigned short* __restrict__ Bt,
                                                  const float* __restrict__ bias,
                                                  unsigned short* __restrict__ outB,
                                                  int N, int lda, int ldb, int nk, P8 po) {
    __shared__ unsigned short sm[4][16384];  // [0,1]=A dbuf, [2,3]=B dbuf; each 256 rows x 64 bf16
    const int tid = threadIdx.x;
    const int lane = tid & 63, wid = tid >> 6;
    const int l4 = lane & 15, g = lane >> 4;
    const int wr = wid >> 2, wc = wid & 3;   // 2 x 4 wave grid; per-wave out 128x64
    BlkMap bm = remap_block();
    const int m0 = bm.m * 256, n0 = bm.n * 256, z = bm.z;
    A += (size_t)z * (nk * 64);
    Bt += (size_t)z * (nk * 64);
    const int srow = tid >> 3;               // 0..63
    const int schunk = (tid & 7) ^ (srow & 7);
    const int sw = l4 & 7;

    auto stA = [&](int sb, int seg, int k0) {
        gload_lds16(A + (size_t)(m0 + seg * 64 + srow) * lda + k0 + schunk * 8,
                    (char*)sm[sb] + seg * 8192 + tid * 16);
    };
    auto stB = [&](int sb, int seg, int k0) {
        gload_lds16(Bt + (size_t)(n0 + seg * 64 + srow) * ldb + k0 + schunk * 8,
                    (char*)sm[2 + sb] + seg * 8192 + tid * 16);
    };

    f32x4 acc[8][4] = {};
    // prologue: stage tile 0 fully
#pragma unroll
    for (int s = 0; s < 4; s++) stB(0, s, 0);
#pragma unroll
    for (int s = 0; s < 4; s++) stA(0, s, 0);
    asm volatile("s_waitcnt vmcnt(0)" ::: "memory");
    __builtin_amdgcn_s_barrier();

    for (int t = 0; t < nk; ++t) {
        const int bufR = t & 1, bufW = bufR ^ 1;
        const int kn = (t + 1) * 64;
        const bool pf = (t + 1 < nk);
        const unsigned short* As_ = sm[bufR];
        const unsigned short* Bs_ = sm[2 + bufR];
        // issue next tile's staging (completes during this tile's compute)
        if (pf) {
#pragma unroll
            for (int s = 0; s < 4; s++) stB(bufW, s, kn);
#pragma unroll
            for (int s = 0; s < 4; s++) stA(bufW, s, kn);
        }
        short8 a[4], b0[4], b1[4];
        __builtin_amdgcn_s_setprio(1);
        // ---- ks = 0 ----
#pragma unroll
        for (int n = 0; n < 4; n++)
            b0[n] = *(const short8*)(Bs_ + (wc * 64 + n * 16 + l4) * 64 + (g ^ sw) * 8);
#pragma unroll
        for (int m = 0; m < 4; m++)
            a[m] = *(const short8*)(As_ + (wr * 128 + m * 16 + l4) * 64 + (g ^ sw) * 8);
#pragma unroll
        for (int m = 0; m < 4; m++)
#pragma unroll
            for (int n = 0; n < 4; n++)
                acc[m][n] = __builtin_amdgcn_mfma_f32_16x16x32_bf16(a[m], b0[n], acc[m][n], 0, 0, 0);
#pragma unroll
        for (int m = 0; m < 4; m++)
            a[m] = *(const short8*)(As_ + (wr * 128 + 64 + m * 16 + l4) * 64 + (g ^ sw) * 8);
#pragma unroll
        for (int m = 0; m < 4; m++)
#pragma unroll
            for (int n = 0; n < 4; n++)
                acc[4 + m][n] = __builtin_amdgcn_mfma_f32_16x16x32_bf16(a[m], b0[n], acc[4 + m][n], 0, 0, 0);
        // ---- ks = 1 ----
#pragma unroll
        for (int n = 0; n < 4; n++)
            b1[n] = *(const short8*)(Bs_ + (wc * 64 + n * 16 + l4) * 64 + ((4 + g) ^ sw) * 8);
#pragma unroll
        for (int m = 0; m < 4; m++)
            a[m] = *(const short8*)(As_ + (wr * 128 + m * 16 + l4) * 64 + ((4 + g) ^ sw) * 8);
#pragma unroll
        for (int m = 0; m < 4; m++)
#pragma unroll
            for (int n = 0; n < 4; n++)
                acc[m][n] = __builtin_amdgcn_mfma_f32_16x16x32_bf16(a[m], b1[n], acc[m][n], 0, 0, 0);
#pragma unroll
        for (int m = 0; m < 4; m++)
            a[m] = *(const short8*)(As_ + (wr * 128 + 64 + m * 16 + l4) * 64 + ((4 + g) ^ sw) * 8);
#pragma unroll
        for (int m = 0; m < 4; m++)
#pragma unroll
            for (int n = 0; n < 4; n++)
                acc[4 + m][n] = __builtin_amdgcn_mfma_f32_16x16x32_bf16(a[m], b1[n], acc[4 + m][n], 0, 0, 0);
        __builtin_amdgcn_s_setprio(0);
        // one certify + one barrier per tile
        if (pf) asm volatile("s_waitcnt vmcnt(0)" ::: "memory");
        __builtin_amdgcn_s_barrier();
    }
    // ---- coalesced epilogue via LDS staging (half-tile at a time) ----
    unsigned short* eb = (unsigned short*)sm;   // 128KB scratch, free after K-loop
    unsigned short* oB = (EPI == 3) ? po.o[z] : outB;
    const int colL = wc * 64 + l4;              // local col (0..255), per-lane
#pragma unroll
    for (int h = 0; h < 2; ++h) {
        if (wr == h) {
#pragma unroll
            for (int mm = 0; mm < 8; mm++) {
                const int base_r = (mm < 4 ? mm * 16 : 64 + (mm - 4) * 16) + g * 4;
#pragma unroll
                for (int n = 0; n < 4; n++) {
                    float bv = (EPI == 3 && z != 0) ? 0.f : bias[n0 + colL + n * 16];
#pragma unroll
                    for (int r = 0; r < 4; r++) {
                        float v = acc[mm][n][r] + bv;
                        if (EPI == 2) v = fmaxf(v, 0.f);
                        eb[(base_r + r) * 260 + colL + n * 16] = f2bf(v);
                    }
                }
            }
        }
        __syncthreads();
        const int gr0 = m0 + h * 128;
#pragma unroll
        for (int j = 0; j < 8; j++) {
            const int f = j * 8192 + tid * 16;      // byte offset in [128][512B] image
            const int row = f >> 9;
            const int colb = f & 511;
            short8 v = *(const short8*)((const char*)eb + row * 520 + colb);
            *(short8*)(oB + (size_t)(gr0 + row) * N + n0 + (colb >> 1)) = v;
        }
        if (h == 0) __syncthreads();                // before overwriting LDS for half 2
    }
}

// ---------------- GEMM 64x128: 3-buffer depth-2, counted vmcnt, XCD-swizzled ----------------
template <int EPI>
__global__ __launch_bounds__(256) void gemm64_db(const unsigned short* __restrict__ A,
                                                 const unsigned short* __restrict__ Bt,
                                                 const float* __restrict__ bias,
                                                 float* __restrict__ outF,
                                                 unsigned short* __restrict__ outB,
                                                 int M, int N, int Kloop, int lda, int ldb) {
    __shared__ unsigned short As[3][64 * 32];
    __shared__ unsigned short Bs[3][128 * 32];
    const int tid = threadIdx.x;
    const int w = tid >> 6, lane = tid & 63, l4 = lane & 15, g = lane >> 4;
    BlkMap bm = remap_block();
    const int m0 = bm.m * 64, n0 = bm.n * 128;
    f32x4 acc[4][2] = {};
    const int r0 = tid >> 2;
    const int kk = ((tid & 3) ^ ((tid >> 3) & 3)) * 8;
    const int sk = (l4 >> 1) & 3;
    const unsigned short* Ar0 = A + (size_t)(m0 + r0) * lda + kk;
    const unsigned short* Br0 = Bt + (size_t)(n0 + r0) * ldb + kk;
    const unsigned short* Br1 = Bt + (size_t)(n0 + 64 + r0) * ldb + kk;
    auto stage = [&](int sb, int k0) {
        gload_lds16(Ar0 + k0, (char*)As[sb] + tid * 16);
        gload_lds16(Br0 + k0, (char*)Bs[sb] + tid * 16);
        gload_lds16(Br1 + k0, (char*)Bs[sb] + 4096 + tid * 16);
    };
    const int nk = Kloop >> 5;
    stage(0, 0);
    stage(1, 32);
    asm volatile("s_waitcnt vmcnt(3)" ::: "memory");
    __builtin_amdgcn_s_barrier();
    asm volatile("" ::: "memory");
    int buf = 0;
    for (int t = 0; t < nk; ++t) {
        if (t + 2 < nk) {
            int b2 = buf + 2; if (b2 >= 3) b2 -= 3;
            stage(b2, (t + 2) * 32);
        }
        short8 a[4], b[2];
#pragma unroll
        for (int m = 0; m < 4; m++)
            a[m] = *(const short8*)(As[buf] + (m * 16 + l4) * 32 + (g ^ sk) * 8);
#pragma unroll
        for (int n = 0; n < 2; n++)
            b[n] = *(const short8*)(Bs[buf] + (w * 32 + n * 16 + l4) * 32 + (g ^ sk) * 8);
#pragma unroll
        for (int m = 0; m < 4; m++)
#pragma unroll
            for (int n = 0; n < 2; n++)
                acc[m][n] = __builtin_amdgcn_mfma_f32_16x16x32_bf16(a[m], b[n], acc[m][n], 0, 0, 0);
        if (t + 1 < nk) {
            if (t + 2 < nk) asm volatile("s_waitcnt vmcnt(3)" ::: "memory");
            else            asm volatile("s_waitcnt vmcnt(0)" ::: "memory");
            __builtin_amdgcn_s_barrier();
            asm volatile("" ::: "memory");
        }
        buf = (buf + 1 == 3) ? 0 : buf + 1;
    }
    const int rowB = m0 + g * 4;
    const int colB = n0 + w * 32 + l4;
#pragma unroll
    for (int n = 0; n < 2; n++) {
        float bv = bias[colB + n * 16];
#pragma unroll
        for (int m = 0; m < 4; m++) {
#pragma unroll
            for (int r = 0; r < 4; r++) {
                float v = acc[m][n][r] + bv;
                if (EPI == 2) v = fmaxf(v, 0.f);
                size_t idx = (size_t)(rowB + m * 16 + r) * N + colB + n * 16;
                if (EPI == 1) outF[idx] = v;
                else outB[idx] = f2bf(v);
            }
        }
    }
}

// ---------------- flash attention v6: 8 waves / 128 q-rows per block ----------------
template <int CAUSAL>
__global__ __launch_bounds__(512) void attn6_kernel(const unsigned short* __restrict__ Q, int ldq,
                                                    const unsigned short* __restrict__ Kg, int ldk,
                                                    const unsigned short* __restrict__ Vt,
                                                    unsigned short* __restrict__ O) {
    __shared__ unsigned short Kl[2 * 64 * 64];
    __shared__ unsigned short Vl[2 * 64 * 64];
    __shared__ unsigned short Pl[8][16 * 72];
    const int bh = blockIdx.x;
    const int qb = CAUSAL ? (gridDim.y - 1 - blockIdx.y) : blockIdx.y;
    const int b = bh >> 4, h = bh & 15;
    const int tid = threadIdx.x, w = tid >> 6, lane = tid & 63;
    const int l4 = lane & 15, g = lane >> 4;
    const int q0 = qb * 128 + w * 16;
    const unsigned short* Qp = Q + (size_t)(b * Tc + q0 + l4) * ldq + h * DHc + g * 8;
    short8 qf0 = *(const short8*)Qp;
    short8 qf1 = *(const short8*)(Qp + 32);
    const unsigned short* Kbase = Kg + (size_t)(b * 1024) * ldk + h * DHc;
    const unsigned short* Vbase = Vt + (size_t)bh * DHc * 1024;
    f32x4 o[4] = {};
    float mrun = -1e30f, lrun = 0.f;
    const int nT = CAUSAL ? 2 * qb + 2 : 16;
    unsigned short* pw = &Pl[w][l4 * 72];
    const int qi = q0 + l4;

    short8 ones;
#pragma unroll
    for (int j = 0; j < 8; j++) ones[j] = (short)0x3F80;  // bf16 1.0

    const int sr = tid >> 3;                 // 0..63
    const int sc_ = (tid & 7) ^ (sr & 7);

    auto stage = [&](int s0, int buf) {
        char* kd = (char*)Kl + buf * 8192;
        char* vd = (char*)Vl + buf * 8192;
        gload_lds16(Kbase + (size_t)(s0 + sr) * ldk + sc_ * 8, kd + tid * 16);
        gload_lds16(Vbase + (size_t)sr * 1024 + s0 + sc_ * 8, vd + tid * 16);
    };

    stage(0, 0);
    __syncthreads();
    int buf = 0;
    const int sw = l4 & 7;

    for (int t = 0; t < nT; ++t) {
        const int s0 = t * 64;
        if (t + 1 < nT) stage(s0 + 64, buf ^ 1);
        if (!CAUSAL || s0 <= q0 + 15) {
            const unsigned short* Kb_ = Kl + buf * 4096;
            const unsigned short* Vb_ = Vl + buf * 4096;
            f32x4 st[4];
            f32x4 z = {0.f, 0.f, 0.f, 0.f};
            __builtin_amdgcn_s_setprio(1);
#pragma unroll
            for (int c = 0; c < 4; c++) {
                const unsigned short* kr = Kb_ + (c * 16 + l4) * 64;
                short8 ka0 = *(const short8*)(kr + ((g ^ sw) * 8));
                short8 ka1 = *(const short8*)(kr + (((g + 4) ^ sw) * 8));
                st[c] = __builtin_amdgcn_mfma_f32_16x16x32_bf16(ka0, qf0, z, 0, 0, 0);
                st[c] = __builtin_amdgcn_mfma_f32_16x16x32_bf16(ka1, qf1, st[c], 0, 0, 0);
            }
            __builtin_amdgcn_s_setprio(0);
            float p[16];
            const bool domask = CAUSAL && (s0 + 63 > q0);
#pragma unroll
            for (int c = 0; c < 4; c++)
#pragma unroll
                for (int r = 0; r < 4; r++) {
                    float v = st[c][r];
                    if (domask && (s0 + c * 16 + g * 4 + r) > qi) v = -1e9f;
                    p[c * 4 + r] = v;
                }
            float m1 = fmaxf(fmaxf(p[0], p[1]), p[2]);
            float m2 = fmaxf(fmaxf(p[3], p[4]), p[5]);
            float m3 = fmaxf(fmaxf(p[6], p[7]), p[8]);
            float m4 = fmaxf(fmaxf(p[9], p[10]), p[11]);
            float m5 = fmaxf(fmaxf(p[12], p[13]), p[14]);
            float tmax = fmaxf(fmaxf(fmaxf(m1, m2), fmaxf(m3, m4)), fmaxf(m5, p[15]));
            tmax = fmaxf(tmax, __shfl_xor(tmax, 16));
            tmax = fmaxf(tmax, __shfl_xor(tmax, 32));
            if (!__all(tmax <= mrun + 11.5f)) {
                float mnew = fmaxf(mrun, tmax);
                float al = fexp2(mrun - mnew);
                lrun *= al;
#pragma unroll
                for (int d = 0; d < 4; d++) o[d] *= al;
                mrun = mnew;
            }
#pragma unroll
            for (int i = 0; i < 16; i++) p[i] = fexp2(p[i] - mrun);
#pragma unroll
            for (int c = 0; c < 4; c++) {
                uint2 u;
                u.x = cvtpk(p[c * 4 + 0], p[c * 4 + 1]);
                u.y = cvtpk(p[c * 4 + 2], p[c * 4 + 3]);
                *(uint2*)(pw + c * 16 + g * 4) = u;
            }
            short8 pb_lo = *(const short8*)(pw + g * 8);
            short8 pb_hi = *(const short8*)(pw + 32 + g * 8);
            __builtin_amdgcn_s_setprio(1);
            f32x4 s4 = __builtin_amdgcn_mfma_f32_16x16x32_bf16(ones, pb_lo, z, 0, 0, 0);
            s4 = __builtin_amdgcn_mfma_f32_16x16x32_bf16(ones, pb_hi, s4, 0, 0, 0);
#pragma unroll
            for (int d = 0; d < 4; d++) {
                const unsigned short* vr = Vb_ + (d * 16 + l4) * 64;
                short8 va0 = *(const short8*)(vr + ((g ^ sw) * 8));
                short8 va1 = *(const short8*)(vr + (((g + 4) ^ sw) * 8));
                o[d] = __builtin_amdgcn_mfma_f32_16x16x32_bf16(va0, pb_lo, o[d], 0, 0, 0);
                o[d] = __builtin_amdgcn_mfma_f32_16x16x32_bf16(va1, pb_hi, o[d], 0, 0, 0);
            }
            __builtin_amdgcn_s_setprio(0);
            lrun += s4[0];
        }
        __syncthreads();
        buf ^= 1;
    }
    float inv = 1.f / lrun;
    unsigned short* Ob = O + (size_t)(b * Tc + q0 + l4) * Dc + h * DHc;
#pragma unroll
    for (int d = 0; d < 4; d++) {
#pragma unroll
        for (int r = 0; r < 4; r++) Ob[d * 16 + g * 4 + r] = f2bf(o[d][r] * inv);
    }
}

// ---------------- fused residual-add + LayerNorm (bf16 a + bf16 res) ----------------
__global__ __launch_bounds__(256) void ln_bf(const unsigned short* __restrict__ a,
                                             const unsigned short* __restrict__ res,
                                             const float* __restrict__ gam,
                                             const float* __restrict__ bet,
                                             unsigned short* __restrict__ outB,
                                             float* __restrict__ outF) {
    int row = blockIdx.x, t = threadIdx.x;
    size_t base = (size_t)row * Dc + t * 4;
    short4v av = *(const short4v*)(a + base);
    short4v rv = *(const short4v*)(res + base);
    float x0 = bf2f((unsigned short)av[0]) + bf2f((unsigned short)rv[0]);
    float x1 = bf2f((unsigned short)av[1]) + bf2f((unsigned short)rv[1]);
    float x2 = bf2f((unsigned short)av[2]) + bf2f((unsigned short)rv[2]);
    float x3 = bf2f((unsigned short)av[3]) + bf2f((unsigned short)rv[3]);
    float s = x0 + x1 + x2 + x3;
    float ss = x0 * x0 + x1 * x1 + x2 * x2 + x3 * x3;
    for (int o = 1; o < 64; o <<= 1) { s += __shfl_xor(s, o); ss += __shfl_xor(ss, o); }
    __shared__ float S1[4], S2[4];
    int w = t >> 6;
    if ((t & 63) == 0) { S1[w] = s; S2[w] = ss; }
    __syncthreads();
    s = S1[0] + S1[1] + S1[2] + S1[3];
    ss = S2[0] + S2[1] + S2[2] + S2[3];
    float mean = s * (1.f / Dc);
    float var = ss * (1.f / Dc) - mean * mean;
    float rstd = rsqrtf(var + 1e-5f);
    int c = t * 4;
    float4 g4 = *(const float4*)(gam + c);
    float4 b4 = *(const float4*)(bet + c);
    float y0 = (x0 - mean) * rstd * g4.x + b4.x;
    float y1 = (x1 - mean) * rstd * g4.y + b4.y;
    float y2 = (x2 - mean) * rstd * g4.z + b4.z;
    float y3 = (x3 - mean) * rstd * g4.w + b4.w;
    if (outB) {
        short4v ob;
        ob[0] = f2bf(y0); ob[1] = f2bf(y1); ob[2] = f2bf(y2); ob[3] = f2bf(y3);
        *(short4v*)(outB + base) = ob;
    }
    if (outF) { float4 ov = {y0, y1, y2, y3}; *(float4*)(outF + base) = ov; }
}

// ---------------- LN over 4 bf16 split-K partials + bf16 residual -> f32 out ----------------
__global__ __launch_bounds__(256) void ln_4b(const unsigned short* __restrict__ p,
                                             const unsigned short* __restrict__ res,
                                             const float* __restrict__ gam,
                                             const float* __restrict__ bet,
                                             float* __restrict__ outF) {
    const size_t PS = (size_t)4096 * 1024;   // partial stride (M*N)
    int row = blockIdx.x, t = threadIdx.x;
    size_t base = (size_t)row * Dc + t * 4;
    float x0, x1, x2, x3;
    {
        short4v rv = *(const short4v*)(res + base);
        x0 = bf2f((unsigned short)rv[0]); x1 = bf2f((unsigned short)rv[1]);
        x2 = bf2f((unsigned short)rv[2]); x3 = bf2f((unsigned short)rv[3]);
    }
#pragma unroll
    for (int j = 0; j < 4; j++) {
        short4v v = *(const short4v*)(p + j * PS + base);
        x0 += bf2f((unsigned short)v[0]); x1 += bf2f((unsigned short)v[1]);
        x2 += bf2f((unsigned short)v[2]); x3 += bf2f((unsigned short)v[3]);
    }
    float s = x0 + x1 + x2 + x3;
    float ss = x0 * x0 + x1 * x1 + x2 * x2 + x3 * x3;
    for (int o = 1; o < 64; o <<= 1) { s += __shfl_xor(s, o); ss += __shfl_xor(ss, o); }
    __shared__ float S1[4], S2[4];
    int w = t >> 6;
    if ((t & 63) == 0) { S1[w] = s; S2[w] = ss; }
    __syncthreads();
    s = S1[0] + S1[1] + S1[2] + S1[3];
    ss = S2[0] + S2[1] + S2[2] + S2[3];
    float mean = s * (1.f / Dc);
    float var = ss * (1.f / Dc) - mean * mean;
    float rstd = rsqrtf(var + 1e-5f);
    int c = t * 4;
    float4 g4 = *(const float4*)(gam + c);
    float4 b4 = *(const float4*)(bet + c);
    float4 ov;
    ov.x = (x0 - mean) * rstd * g4.x + b4.x;
    ov.y = (x1 - mean) * rstd * g4.y + b4.y;
    ov.z = (x2 - mean) * rstd * g4.z + b4.z;
    ov.w = (x3 - mean) * rstd * g4.w + b4.w;
    *(float4*)(outF + base) = ov;
}

// ---------------- launch ----------------
extern "C" void kernel_launch(void* const* d_in, const int* in_sizes, int n_in,
                              void* d_out, int out_size, void* d_ws, size_t ws_size,
                              hipStream_t stream) {
    const float* x   = (const float*)d_in[0];
    const float* enc = (const float*)d_in[1];
    const float* dWq = (const float*)d_in[4];  const float* dbq = (const float*)d_in[5];
    const float* dWk = (const float*)d_in[6];  const float* dbk = (const float*)d_in[7];
    const float* dWv = (const float*)d_in[8];  const float* dbv = (const float*)d_in[9];
    const float* dWo = (const float*)d_in[10]; const float* dbo = (const float*)d_in[11];
    const float* eWq = (const float*)d_in[12]; const float* ebq = (const float*)d_in[13];
    const float* eWk = (const float*)d_in[14]; const float* ebk = (const float*)d_in[15];
    const float* eWv = (const float*)d_in[16]; const float* ebv = (const float*)d_in[17];
    const float* eWo = (const float*)d_in[18]; const float* ebo = (const float*)d_in[19];
    const float* fW1 = (const float*)d_in[20]; const float* fb1 = (const float*)d_in[21];
    const float* fW2 = (const float*)d_in[22]; const float* fb2 = (const float*)d_in[23];
    const float* g1 = (const float*)d_in[24];  const float* be1 = (const float*)d_in[25];
    const float* g2 = (const float*)d_in[26];  const float* be2 = (const float*)d_in[27];
    const float* g3 = (const float*)d_in[28];  const float* be3 = (const float*)d_in[29];

    const float SC = 0.125f * 1.44269504f;   // softmax scale folded to exp2 domain

    char* ws = (char*)d_ws;
    size_t off = 0;
    auto alloc = [&](size_t bytes) -> void* {
        void* p = ws + off;
        off += (bytes + 255) & ~(size_t)255;
        return p;
    };
    const size_t A = (size_t)4096 * 1024;
    const size_t MB1 = (size_t)1024 * 1024;
    char* R1 = (char*)alloc(32 * 1024 * 1024);
    unsigned short* qkv = (unsigned short*)R1;                       // stride 3072
    unsigned short* kvx = (unsigned short*)R1;                       // stride 2048 (after qkv dead)
    unsigned short* qx  = (unsigned short*)(R1 + 16 * 1024 * 1024);  // stride 1024
    unsigned short* h1  = (unsigned short*)R1;                       // 4096x4096
    unsigned short* xb   = (unsigned short*)alloc(A * 2);
    unsigned short* encb = (unsigned short*)alloc(A * 2);
    unsigned short* wqkv = (unsigned short*)alloc(3 * MB1 * 2);
    unsigned short* wekv = (unsigned short*)alloc(2 * MB1 * 2);
    unsigned short* weq  = (unsigned short*)alloc(MB1 * 2);
    unsigned short* wdo  = (unsigned short*)alloc(MB1 * 2);
    unsigned short* weo  = (unsigned short*)alloc(MB1 * 2);
    unsigned short* wf1  = (unsigned short*)alloc(4 * MB1 * 2);
    unsigned short* wf2  = (unsigned short*)alloc(4 * MB1 * 2);
    float* bqkv = (float*)alloc(3072 * 4);
    float* bekv = (float*)alloc(2048 * 4);
    float* ebq_s = (float*)alloc(1024 * 4);
    unsigned short* VtB = (unsigned short*)alloc(A * 2);
    unsigned short* ab  = (unsigned short*)alloc(A * 2);
    unsigned short* tmpB = (unsigned short*)alloc(A * 2);
    unsigned short* dB = (unsigned short*)alloc(A * 2);
    unsigned short* fB = (unsigned short*)alloc(A * 2);
    // FFN2 split-K4 bf16 partials alias [VtB, ab, tmpB, dB] (free in FFN phase)
    unsigned short* pfb = VtB;
    (void)ws_size; (void)in_sizes; (void)n_in; (void)out_size;

    dim3 tb(32, 8);
    cast2_f32_bf16<<<dim3(2048, 2), 256, 0, stream>>>(x, enc, xb, encb, (int)(A / 8));
    TP8 tp;
    tp.s[0] = dWq; tp.d[0] = wqkv;           tp.scl[0] = SC;    // Q pre-scaled
    tp.s[1] = dWk; tp.d[1] = wqkv + MB1;     tp.scl[1] = 1.f;
    tp.s[2] = dWv; tp.d[2] = wqkv + 2 * MB1; tp.scl[2] = 1.f;
    tp.s[3] = eWk; tp.d[3] = wekv;           tp.scl[3] = 1.f;
    tp.s[4] = eWv; tp.d[4] = wekv + MB1;     tp.scl[4] = 1.f;
    tp.s[5] = eWq; tp.d[5] = weq;            tp.scl[5] = SC;    // cross Q pre-scaled
    tp.s[6] = dWo; tp.d[6] = wdo;            tp.scl[6] = 1.f;
    tp.s[7] = eWo; tp.d[7] = weo;            tp.scl[7] = 1.f;
    transpose_cast8<<<dim3(32, 32, 8), tb, 0, stream>>>(tp);
    transpose_cast<<<dim3(128, 32), tb, 0, stream>>>(fW1, wf1, 1024, 4096);
    transpose_cast<<<dim3(32, 128), tb, 0, stream>>>(fW2, wf2, 4096, 1024);
    prep_bias<<<24, 256, 0, stream>>>(dbq, dbk, dbv, ebk, ebv, ebq, bqkv, bekv, ebq_s, SC);

    P8 z8{};

    // ---- self-attention block ----
    gemm256<0><<<dim3(12, 16), 512, 0, stream>>>(xb, wqkv, bqkv, qkv, 3072, 1024, 1024, 16, z8);
    transpose_v<<<dim3(16, 64), 256, 0, stream>>>(qkv + 2048, 3072, VtB);
    attn6_kernel<1><<<dim3(64, 8), 512, 0, stream>>>(qkv, 3072, qkv + 1024, 3072, VtB, ab);
    gemm64_db<0><<<dim3(8, 64), 256, 0, stream>>>(ab, wdo, dbo, nullptr, tmpB, 4096, 1024, 1024, 1024, 1024);
    ln_bf<<<4096, 256, 0, stream>>>(tmpB, xb, g1, be1, dB, nullptr);

    // ---- cross-attention block ----
    {
        P8 pe{};
        pe.o[0] = kvx;
        pe.o[1] = VtB;
        gemm256<3><<<dim3(8, 16, 2), 512, 0, stream>>>(encb, wekv, bekv, nullptr, 2048, 1024, 1024, 8, pe);
        combine2<<<4096, 256, 0, stream>>>(kvx, VtB, (int)((size_t)4096 * 2048 / 8));
    }
    gemm64_db<0><<<dim3(8, 64), 256, 0, stream>>>(dB, weq, ebq_s, nullptr, qx, 4096, 1024, 1024, 1024, 1024);
    transpose_v<<<dim3(16, 64), 256, 0, stream>>>(kvx + 1024, 2048, VtB);
    attn6_kernel<0><<<dim3(64, 8), 512, 0, stream>>>(qx, 1024, kvx, 2048, VtB, ab);
    gemm64_db<0><<<dim3(8, 64), 256, 0, stream>>>(ab, weo, ebo, nullptr, tmpB, 4096, 1024, 1024, 1024, 1024);
    ln_bf<<<4096, 256, 0, stream>>>(tmpB, dB, g2, be2, fB, nullptr);

    // ---- FFN block ----
    gemm256<2><<<dim3(16, 16), 512, 0, stream>>>(fB, wf1, fb1, h1, 4096, 1024, 1024, 16, z8);
    {
        P8 pf{};
        pf.o[0] = pfb;
        pf.o[1] = pfb + A;
        pf.o[2] = pfb + 2 * A;
        pf.o[3] = pfb + 3 * A;
        gemm256<3><<<dim3(4, 16, 4), 512, 0, stream>>>(h1, wf2, fb2, nullptr, 1024, 4096, 4096, 16, pf);
    }
    ln_4b<<<4096, 256, 0, stream>>>(pfb, fB, g3, be3, (float*)d_out);
}

// Round 15
// 325.864 us; speedup vs baseline: 1.0331x; 1.0132x over previous
//
#include <hip/hip_runtime.h>

static constexpr int Bc = 4, Tc = 1024, Sc = 1024, Dc = 1024, Hc = 16, DHc = 64, FFc = 4096;

typedef __attribute__((ext_vector_type(8))) short short8;
typedef __attribute__((ext_vector_type(4))) short short4v;
typedef __attribute__((ext_vector_type(4))) float f32x4;

struct P8 { unsigned short* o[8]; };

__device__ __forceinline__ unsigned short f2bf(float f) {
    unsigned int u = __float_as_uint(f);
    unsigned int r = u + 0x7fffu + ((u >> 16) & 1u);
    return (unsigned short)(r >> 16);
}
__device__ __forceinline__ float bf2f(unsigned short u) {
    return __uint_as_float(((unsigned int)u) << 16);
}
__device__ __forceinline__ float fexp2(float x) {
    float r; asm("v_exp_f32 %0, %1" : "=v"(r) : "v"(x)); return r;
}
__device__ __forceinline__ unsigned int cvtpk(float a, float b) {
    unsigned int r;
    asm("v_cvt_pk_bf16_f32 %0, %1, %2" : "=v"(r) : "v"(a), "v"(b));
    return r;
}

__device__ __forceinline__ void gload_lds16(const void* g, void* l) {
    __builtin_amdgcn_global_load_lds((const __attribute__((address_space(1))) void*)g,
                                     (__attribute__((address_space(3))) void*)l, 16, 0, 0);
}

// ---------------- cast f32 -> bf16 (two tensors in one launch) ----------------
__global__ __launch_bounds__(256) void cast2_f32_bf16(const float* __restrict__ inA,
                                                      const float* __restrict__ inB,
                                                      unsigned short* __restrict__ outA,
                                                      unsigned short* __restrict__ outB, int n8) {
    int i = blockIdx.x * 256 + threadIdx.x;
    if (i >= n8) return;
    const float* in = blockIdx.y ? inB : inA;
    unsigned short* out = blockIdx.y ? outB : outA;
    const float4* p = (const float4*)in + (size_t)i * 2;
    float4 a = p[0], b = p[1];
    short8 o;
    o[0] = f2bf(a.x); o[1] = f2bf(a.y); o[2] = f2bf(a.z); o[3] = f2bf(a.w);
    o[4] = f2bf(b.x); o[5] = f2bf(b.y); o[6] = f2bf(b.z); o[7] = f2bf(b.w);
    *(short8*)(out + (size_t)i * 8) = o;
}

// ---------------- transpose + cast: W(K,N) f32 -> Wt(N,K) bf16 ----------------
__global__ __launch_bounds__(256) void transpose_cast(const float* __restrict__ W,
                                                      unsigned short* __restrict__ Wt,
                                                      int K, int N) {
    __shared__ float tile[32][33];
    int n0 = blockIdx.x * 32, k0 = blockIdx.y * 32;
    int tx = threadIdx.x, ty = threadIdx.y;  // (32,8)
#pragma unroll
    for (int i = 0; i < 4; i++)
        tile[ty + i * 8][tx] = W[(size_t)(k0 + ty + i * 8) * N + n0 + tx];
    __syncthreads();
#pragma unroll
    for (int i = 0; i < 4; i++)
        Wt[(size_t)(n0 + ty + i * 8) * K + k0 + tx] = f2bf(tile[tx][ty + i * 8]);
}

// batched version for 8 square 1024x1024 weights (per-matrix output scale)
struct TP8 { const float* s[8]; unsigned short* d[8]; float scl[8]; };
__global__ __launch_bounds__(256) void transpose_cast8(TP8 p) {
    __shared__ float tile[32][33];
    const float* W = p.s[blockIdx.z];
    unsigned short* Wt = p.d[blockIdx.z];
    const float sc = p.scl[blockIdx.z];
    int n0 = blockIdx.x * 32, k0 = blockIdx.y * 32;
    int tx = threadIdx.x, ty = threadIdx.y;
#pragma unroll
    for (int i = 0; i < 4; i++)
        tile[ty + i * 8][tx] = W[(size_t)(k0 + ty + i * 8) * 1024 + n0 + tx];
    __syncthreads();
#pragma unroll
    for (int i = 0; i < 4; i++)
        Wt[(size_t)(n0 + ty + i * 8) * 1024 + k0 + tx] = f2bf(tile[tx][ty + i * 8] * sc);
}

// ---------------- all bias prep in one launch (6144 elems) ----------------
__global__ void prep_bias(const float* dbq, const float* dbk, const float* dbv,
                          const float* ebk, const float* ebv, const float* ebq,
                          float* __restrict__ bqkv, float* __restrict__ bekv,
                          float* __restrict__ ebq_s, float SC) {
    int i = blockIdx.x * 256 + threadIdx.x;
    int seg = i >> 10, j = i & 1023;
    switch (seg) {
        case 0: bqkv[j] = dbq[j] * SC; break;
        case 1: bqkv[1024 + j] = dbk[j]; break;
        case 2: bqkv[2048 + j] = dbv[j]; break;
        case 3: bekv[j] = ebk[j]; break;
        case 4: bekv[1024 + j] = ebv[j]; break;
        default: ebq_s[j] = ebq[j] * SC; break;
    }
}

// ---------------- in-place bf16 add: dst += p1 ----------------
__global__ __launch_bounds__(256) void combine2(unsigned short* __restrict__ dst,
                                                const unsigned short* __restrict__ p1, int n8) {
    int i = blockIdx.x * 256 + threadIdx.x;
    if (i >= n8) return;
    short8 a = *(short8*)(dst + (size_t)i * 8);
    short8 b = *(const short8*)(p1 + (size_t)i * 8);
    short8 o;
#pragma unroll
    for (int j = 0; j < 8; j++)
        o[j] = f2bf(bf2f((unsigned short)a[j]) + bf2f((unsigned short)b[j]));
    *(short8*)(dst + (size_t)i * 8) = o;
}

// ---------------- per-head V transpose ----------------
__global__ __launch_bounds__(256) void transpose_v(const unsigned short* __restrict__ V, int ldv,
                                                   unsigned short* __restrict__ Vt) {
    __shared__ unsigned short t[64 * 64];
    const int bh = blockIdx.y, b = bh >> 4, h = bh & 15;
    const int s0 = blockIdx.x * 64;
    const int tid = threadIdx.x;
    const int r = tid >> 2, ch = tid & 3;
    const unsigned short* src = V + (size_t)(b * 1024 + s0 + r) * ldv + h * 64 + ch * 16;
    short8 v0 = *(const short8*)src;
    short8 v1 = *(const short8*)(src + 8);
    int pw_ = (ch ^ r ^ (r >> 4)) & 3;
    *(short8*)(t + r * 64 + pw_ * 16) = v0;
    *(short8*)(t + r * 64 + pw_ * 16 + 8) = v1;
    __syncthreads();
    const int dh = tid >> 2, sc = (tid & 3) * 16;
    short8 o0, o1;
#pragma unroll
    for (int j = 0; j < 8; j++) {
        int c0 = sc + j, c1 = sc + 8 + j;
        o0[j] = t[c0 * 64 + (((dh >> 4) ^ c0 ^ (c0 >> 4)) & 3) * 16 + (dh & 15)];
        o1[j] = t[c1 * 64 + (((dh >> 4) ^ c1 ^ (c1 >> 4)) & 3) * 16 + (dh & 15)];
    }
    unsigned short* dst = Vt + ((size_t)bh * 64 + dh) * 1024 + s0 + sc;
    *(short8*)dst = o0;
    *(short8*)(dst + 8) = o1;
}

// ---- block remap: chunked-XCD + group-major rasterization (bijective, nwg%8==0) ----
struct BlkMap { int m, n, z; };
__device__ __forceinline__ BlkMap remap_block() {
    const int gx = gridDim.x, gy = gridDim.y;
    const int nxy = gx * gy;
    const int nwg = nxy * gridDim.z;
    const int flat = (blockIdx.z * gy + blockIdx.y) * gx + blockIdx.x;
    const int id = (flat & 7) * (nwg >> 3) + (flat >> 3);
    const int pz = id / nxy;
    const int rz = id - pz * nxy;
    const int gwsh = (gx & 7) ? 2 : 3;       // group width 4 if gx%8!=0, else 8
    const int gw = 1 << gwsh;
    const int gsz = gw * gy;
    const int grp = rz / gsz;
    const int rem = rz - grp * gsz;
    BlkMap r;
    r.m = rem >> gwsh;
    r.n = (grp << gwsh) + (rem & (gw - 1));
    r.z = pz;
    return r;
}

// ================= GEMM 256x256, BK=64, 8 waves, m201 8-phase counted-vmcnt ============
// EPI: 0 = bf16 out; 2 = relu+bf16 out; 3 = bf16 split-K partial to po.o[z] (bias only z==0).
// LDS: [A|B][dbuf][half][16KB]. A halves split by m (stripe-folded), B halves by k (row-folded).
// 1 half-tile staged per phase; vmcnt(6) only at P3/P7 (3 half-tiles always in flight).
template <int EPI>
__global__ __launch_bounds__(512, 2) void gemm256(const unsigned short* __restrict__ A,
                                                  const unsigned short* __restrict__ Bt,
                                                  const float* __restrict__ bias,
                                                  unsigned short* __restrict__ outB,
                                                  int N, int lda, int ldb, int nk, P8 po) {
    __shared__ unsigned short SM[2][2][2][8192];   // 128 KiB
    const int tid = threadIdx.x;
    const int lane = tid & 63, wid = tid >> 6;
    const int l4 = lane & 15, g = lane >> 4;
    const int wr = wid >> 2, wc = wid & 3;         // 2 x 4 wave grid; per-wave out 128x64
    BlkMap bm = remap_block();
    const int m0 = bm.m * 256, n0 = bm.n * 256, z = bm.z;
    A += (size_t)z * (nk * 64);
    Bt += (size_t)z * (nk * 64);
    const int sw = l4 & 7;

    // staging coords: 2 loads/thread/half-tile; linear LDS dest, inverse-swizzled source
    const int fl0 = tid, fl1 = 512 + tid;
    const int lr0 = fl0 >> 3, ch0 = (fl0 & 7) ^ (lr0 & 7);
    const int lr1 = fl1 >> 3, ch1 = (fl1 & 7) ^ (lr1 & 7);
    const size_t A64 = (size_t)64 * lda;
    const unsigned short* pA0 = A + (size_t)(m0 + (lr0 >> 6) * 128 + (lr0 & 63)) * lda + ch0 * 8;
    const unsigned short* pA1 = A + (size_t)(m0 + (lr1 >> 6) * 128 + (lr1 & 63)) * lda + ch1 * 8;
    const unsigned short* pB0 = Bt + (size_t)(n0 + (ch0 >> 2) * 128 + lr0) * ldb + (ch0 & 3) * 8;
    const unsigned short* pB1 = Bt + (size_t)(n0 + (ch1 >> 2) * 128 + lr1) * ldb + (ch1 & 3) * 8;

    auto stA = [&](int d, int mh, int kofs) {
        char* base = (char*)&SM[0][d][mh][0];
        gload_lds16(pA0 + (size_t)mh * A64 + kofs, base + fl0 * 16);
        gload_lds16(pA1 + (size_t)mh * A64 + kofs, base + fl1 * 16);
    };
    auto stB = [&](int d, int ks, int kofs) {
        char* base = (char*)&SM[1][d][ks][0];
        gload_lds16(pB0 + ks * 32 + kofs, base + fl0 * 16);
        gload_lds16(pB1 + ks * 32 + kofs, base + fl1 * 16);
    };

    f32x4 acc[8][4] = {};
    short8 aF[4], aH[4], b0[4], b1[4];

    auto ldA = [&](int d, int mh, short8* d0, short8* d1) {   // full row: both k-halves
#pragma unroll
        for (int m = 0; m < 4; m++) {
            const char* rp = (const char*)&SM[0][d][mh][0] + (wr * 64 + m * 16 + l4) * 128;
            d0[m] = *(const short8*)(rp + ((g ^ sw) * 16));
            d1[m] = *(const short8*)(rp + (((4 + g) ^ sw) * 16));
        }
    };
    auto ldB = [&](int d, int ks, short8* dst) {
#pragma unroll
        for (int n = 0; n < 4; n++) {
            const char* rp = (const char*)&SM[1][d][ks][0] + ((wc & 1) * 64 + n * 16 + l4) * 128;
            dst[n] = *(const short8*)(rp + ((((wc >> 1) * 4 + g) ^ sw) * 16));
        }
    };

#define MFMA16(aa, bb, base)                                                                  \
    _Pragma("unroll") for (int m_ = 0; m_ < 4; m_++)                                          \
        _Pragma("unroll") for (int n_ = 0; n_ < 4; n_++)                                      \
            acc[(base) + m_][n_] = __builtin_amdgcn_mfma_f32_16x16x32_bf16(                   \
                (aa)[m_], (bb)[n_], acc[(base) + m_][n_], 0, 0, 0);

    // prologue: tile0 full {B0,A0,B1,A1} + tile1 {B0,A0,B1}; vmcnt(6) => tile0 resident
    stB(0, 0, 0); stA(0, 0, 0); stB(0, 1, 0); stA(0, 1, 0);
    stB(1, 0, 64); stA(1, 0, 64); stB(1, 1, 64);
    asm volatile("s_waitcnt vmcnt(6)" ::: "memory");
    __builtin_amdgcn_s_barrier();

    const int nIter = nk >> 1;
    for (int it = 0; it < nIter; ++it) {
        const int t = 2 * it, u = t + 1;
        const int ku = u * 64;
        const int kv = ((t + 2 < nk) ? t + 2 : t) * 64;   // dummy re-stage on tail (same bytes)
        const int kw = ((u + 2 < nk) ? u + 2 : u) * 64;
        // ---- P0 (t: mh0,ks0) — 12 ds_reads; stage u.A1 ----
        ldB(0, 0, b0); ldA(0, 0, aF, aH);
        stA(1, 1, ku);
        asm volatile("s_waitcnt lgkmcnt(8)" ::: "memory");
        __builtin_amdgcn_s_barrier();
        asm volatile("s_waitcnt lgkmcnt(0)" ::: "memory");
        __builtin_amdgcn_s_setprio(1); MFMA16(aF, b0, 0); __builtin_amdgcn_s_setprio(0);
        __builtin_amdgcn_s_barrier();
        // ---- P1 (t: mh0,ks1) — 4 reads; stage v.B0 ----
        ldB(0, 1, b1);
        stB(0, 0, kv);
        __builtin_amdgcn_s_barrier();
        asm volatile("s_waitcnt lgkmcnt(0)" ::: "memory");
        __builtin_amdgcn_s_setprio(1); MFMA16(aH, b1, 0); __builtin_amdgcn_s_setprio(0);
        __builtin_amdgcn_s_barrier();
        // ---- P2 (t: mh1,ks1) — 8 reads; stage v.A0 ----
        ldA(0, 1, aF, aH);
        stA(0, 0, kv);
        __builtin_amdgcn_s_barrier();
        asm volatile("s_waitcnt lgkmcnt(0)" ::: "memory");
        __builtin_amdgcn_s_setprio(1); MFMA16(aH, b1, 4); __builtin_amdgcn_s_setprio(0);
        __builtin_amdgcn_s_barrier();
        // ---- P3 (t: mh1,ks0) — 0 reads; stage v.B1; vmcnt(6) ----
        stB(0, 1, kv);
        __builtin_amdgcn_s_barrier();
        __builtin_amdgcn_s_setprio(1); MFMA16(aF, b0, 4); __builtin_amdgcn_s_setprio(0);
        asm volatile("s_waitcnt vmcnt(6)" ::: "memory");
        __builtin_amdgcn_s_barrier();
        // ---- P4 (u: mh0,ks0) — 12 reads; stage v.A1 ----
        ldB(1, 0, b0); ldA(1, 0, aF, aH);
        stA(0, 1, kv);
        asm volatile("s_waitcnt lgkmcnt(8)" ::: "memory");
        __builtin_amdgcn_s_barrier();
        asm volatile("s_waitcnt lgkmcnt(0)" ::: "memory");
        __builtin_amdgcn_s_setprio(1); MFMA16(aF, b0, 0); __builtin_amdgcn_s_setprio(0);
        __builtin_amdgcn_s_barrier();
        // ---- P5 (u: mh0,ks1) — 4 reads; stage w.B0 ----
        ldB(1, 1, b1);
        stB(1, 0, kw);
        __builtin_amdgcn_s_barrier();
        asm volatile("s_waitcnt lgkmcnt(0)" ::: "memory");
        __builtin_amdgcn_s_setprio(1); MFMA16(aH, b1, 0); __builtin_amdgcn_s_setprio(0);
        __builtin_amdgcn_s_barrier();
        // ---- P6 (u: mh1,ks1) — 8 reads; stage w.A0 ----
        ldA(1, 1, aF, aH);
        stA(1, 0, kw);
        __builtin_amdgcn_s_barrier();
        asm volatile("s_waitcnt lgkmcnt(0)" ::: "memory");
        __builtin_amdgcn_s_setprio(1); MFMA16(aH, b1, 4); __builtin_amdgcn_s_setprio(0);
        __builtin_amdgcn_s_barrier();
        // ---- P7 (u: mh1,ks0) — 0 reads; stage w.B1; vmcnt(6) ----
        stB(1, 1, kw);
        __builtin_amdgcn_s_barrier();
        __builtin_amdgcn_s_setprio(1); MFMA16(aF, b0, 4); __builtin_amdgcn_s_setprio(0);
        asm volatile("s_waitcnt vmcnt(6)" ::: "memory");
        __builtin_amdgcn_s_barrier();
    }
    // drain dummy stages before reusing LDS
    asm volatile("s_waitcnt vmcnt(0)" ::: "memory");
    __syncthreads();

    // ---- coalesced epilogue via LDS staging (half-tile at a time) ----
    unsigned short* eb = (unsigned short*)SM;
    unsigned short* oB = (EPI == 3) ? po.o[z] : outB;
    const int colL = wc * 64 + l4;
#pragma unroll
    for (int h = 0; h < 2; ++h) {
        if (wr == h) {
#pragma unroll
            for (int mm = 0; mm < 8; mm++) {
                const int base_r = (mm < 4 ? mm * 16 : 64 + (mm - 4) * 16) + g * 4;
#pragma unroll
                for (int n = 0; n < 4; n++) {
                    float bv = (EPI == 3 && z != 0) ? 0.f : bias[n0 + colL + n * 16];
#pragma unroll
                    for (int r = 0; r < 4; r++) {
                        float v = acc[mm][n][r] + bv;
                        if (EPI == 2) v = fmaxf(v, 0.f);
                        eb[(base_r + r) * 260 + colL + n * 16] = f2bf(v);
                    }
                }
            }
        }
        __syncthreads();
        const int gr0 = m0 + h * 128;
#pragma unroll
        for (int j = 0; j < 8; j++) {
            const int f = j * 8192 + tid * 16;
            const int row = f >> 9;
            const int colb = f & 511;
            short8 v = *(const short8*)((const char*)eb + row * 520 + colb);
            *(short8*)(oB + (size_t)(gr0 + row) * N + n0 + (colb >> 1)) = v;
        }
        if (h == 0) __syncthreads();
    }
#undef MFMA16
}

// ---------------- GEMM 64x128: 3-buffer depth-2, counted vmcnt, XCD-swizzled ----------------
template <int EPI>
__global__ __launch_bounds__(256) void gemm64_db(const unsigned short* __restrict__ A,
                                                 const unsigned short* __restrict__ Bt,
                                                 const float* __restrict__ bias,
                                                 float* __restrict__ outF,
                                                 unsigned short* __restrict__ outB,
                                                 int M, int N, int Kloop, int lda, int ldb) {
    __shared__ unsigned short As[3][64 * 32];
    __shared__ unsigned short Bs[3][128 * 32];
    const int tid = threadIdx.x;
    const int w = tid >> 6, lane = tid & 63, l4 = lane & 15, g = lane >> 4;
    BlkMap bm = remap_block();
    const int m0 = bm.m * 64, n0 = bm.n * 128;
    f32x4 acc[4][2] = {};
    const int r0 = tid >> 2;
    const int kk = ((tid & 3) ^ ((tid >> 3) & 3)) * 8;
    const int sk = (l4 >> 1) & 3;
    const unsigned short* Ar0 = A + (size_t)(m0 + r0) * lda + kk;
    const unsigned short* Br0 = Bt + (size_t)(n0 + r0) * ldb + kk;
    const unsigned short* Br1 = Bt + (size_t)(n0 + 64 + r0) * ldb + kk;
    auto stage = [&](int sb, int k0) {
        gload_lds16(Ar0 + k0, (char*)As[sb] + tid * 16);
        gload_lds16(Br0 + k0, (char*)Bs[sb] + tid * 16);
        gload_lds16(Br1 + k0, (char*)Bs[sb] + 4096 + tid * 16);
    };
    const int nk = Kloop >> 5;
    stage(0, 0);
    stage(1, 32);
    asm volatile("s_waitcnt vmcnt(3)" ::: "memory");
    __builtin_amdgcn_s_barrier();
    asm volatile("" ::: "memory");
    int buf = 0;
    for (int t = 0; t < nk; ++t) {
        if (t + 2 < nk) {
            int b2 = buf + 2; if (b2 >= 3) b2 -= 3;
            stage(b2, (t + 2) * 32);
        }
        short8 a[4], b[2];
#pragma unroll
        for (int m = 0; m < 4; m++)
            a[m] = *(const short8*)(As[buf] + (m * 16 + l4) * 32 + (g ^ sk) * 8);
#pragma unroll
        for (int n = 0; n < 2; n++)
            b[n] = *(const short8*)(Bs[buf] + (w * 32 + n * 16 + l4) * 32 + (g ^ sk) * 8);
#pragma unroll
        for (int m = 0; m < 4; m++)
#pragma unroll
            for (int n = 0; n < 2; n++)
                acc[m][n] = __builtin_amdgcn_mfma_f32_16x16x32_bf16(a[m], b[n], acc[m][n], 0, 0, 0);
        if (t + 1 < nk) {
            if (t + 2 < nk) asm volatile("s_waitcnt vmcnt(3)" ::: "memory");
            else            asm volatile("s_waitcnt vmcnt(0)" ::: "memory");
            __builtin_amdgcn_s_barrier();
            asm volatile("" ::: "memory");
        }
        buf = (buf + 1 == 3) ? 0 : buf + 1;
    }
    const int rowB = m0 + g * 4;
    const int colB = n0 + w * 32 + l4;
#pragma unroll
    for (int n = 0; n < 2; n++) {
        float bv = bias[colB + n * 16];
#pragma unroll
        for (int m = 0; m < 4; m++) {
#pragma unroll
            for (int r = 0; r < 4; r++) {
                float v = acc[m][n][r] + bv;
                if (EPI == 2) v = fmaxf(v, 0.f);
                size_t idx = (size_t)(rowB + m * 16 + r) * N + colB + n * 16;
                if (EPI == 1) outF[idx] = v;
                else outB[idx] = f2bf(v);
            }
        }
    }
}

// ---------------- flash attention v6: 8 waves / 128 q-rows per block ----------------
template <int CAUSAL>
__global__ __launch_bounds__(512) void attn6_kernel(const unsigned short* __restrict__ Q, int ldq,
                                                    const unsigned short* __restrict__ Kg, int ldk,
                                                    const unsigned short* __restrict__ Vt,
                                                    unsigned short* __restrict__ O) {
    __shared__ unsigned short Kl[2 * 64 * 64];
    __shared__ unsigned short Vl[2 * 64 * 64];
    __shared__ unsigned short Pl[8][16 * 72];
    const int bh = blockIdx.x;
    const int qb = CAUSAL ? (gridDim.y - 1 - blockIdx.y) : blockIdx.y;
    const int b = bh >> 4, h = bh & 15;
    const int tid = threadIdx.x, w = tid >> 6, lane = tid & 63;
    const int l4 = lane & 15, g = lane >> 4;
    const int q0 = qb * 128 + w * 16;
    const unsigned short* Qp = Q + (size_t)(b * Tc + q0 + l4) * ldq + h * DHc + g * 8;
    short8 qf0 = *(const short8*)Qp;
    short8 qf1 = *(const short8*)(Qp + 32);
    const unsigned short* Kbase = Kg + (size_t)(b * 1024) * ldk + h * DHc;
    const unsigned short* Vbase = Vt + (size_t)bh * DHc * 1024;
    f32x4 o[4] = {};
    float mrun = -1e30f, lrun = 0.f;
    const int nT = CAUSAL ? 2 * qb + 2 : 16;
    unsigned short* pw = &Pl[w][l4 * 72];
    const int qi = q0 + l4;

    short8 ones;
#pragma unroll
    for (int j = 0; j < 8; j++) ones[j] = (short)0x3F80;  // bf16 1.0

    const int sr = tid >> 3;
    const int sc_ = (tid & 7) ^ (sr & 7);

    auto stage = [&](int s0, int buf) {
        char* kd = (char*)Kl + buf * 8192;
        char* vd = (char*)Vl + buf * 8192;
        gload_lds16(Kbase + (size_t)(s0 + sr) * ldk + sc_ * 8, kd + tid * 16);
        gload_lds16(Vbase + (size_t)sr * 1024 + s0 + sc_ * 8, vd + tid * 16);
    };

    stage(0, 0);
    __syncthreads();
    int buf = 0;
    const int sw = l4 & 7;

    for (int t = 0; t < nT; ++t) {
        const int s0 = t * 64;
        if (t + 1 < nT) stage(s0 + 64, buf ^ 1);
        if (!CAUSAL || s0 <= q0 + 15) {
            const unsigned short* Kb_ = Kl + buf * 4096;
            const unsigned short* Vb_ = Vl + buf * 4096;
            f32x4 st[4];
            f32x4 z = {0.f, 0.f, 0.f, 0.f};
            __builtin_amdgcn_s_setprio(1);
#pragma unroll
            for (int c = 0; c < 4; c++) {
                const unsigned short* kr = Kb_ + (c * 16 + l4) * 64;
                short8 ka0 = *(const short8*)(kr + ((g ^ sw) * 8));
                short8 ka1 = *(const short8*)(kr + (((g + 4) ^ sw) * 8));
                st[c] = __builtin_amdgcn_mfma_f32_16x16x32_bf16(ka0, qf0, z, 0, 0, 0);
                st[c] = __builtin_amdgcn_mfma_f32_16x16x32_bf16(ka1, qf1, st[c], 0, 0, 0);
            }
            __builtin_amdgcn_s_setprio(0);
            float p[16];
            const bool domask = CAUSAL && (s0 + 63 > q0);
#pragma unroll
            for (int c = 0; c < 4; c++)
#pragma unroll
                for (int r = 0; r < 4; r++) {
                    float v = st[c][r];
                    if (domask && (s0 + c * 16 + g * 4 + r) > qi) v = -1e9f;
                    p[c * 4 + r] = v;
                }
            float m1 = fmaxf(fmaxf(p[0], p[1]), p[2]);
            float m2 = fmaxf(fmaxf(p[3], p[4]), p[5]);
            float m3 = fmaxf(fmaxf(p[6], p[7]), p[8]);
            float m4 = fmaxf(fmaxf(p[9], p[10]), p[11]);
            float m5 = fmaxf(fmaxf(p[12], p[13]), p[14]);
            float tmax = fmaxf(fmaxf(fmaxf(m1, m2), fmaxf(m3, m4)), fmaxf(m5, p[15]));
            tmax = fmaxf(tmax, __shfl_xor(tmax, 16));
            tmax = fmaxf(tmax, __shfl_xor(tmax, 32));
            if (!__all(tmax <= mrun + 11.5f)) {
                float mnew = fmaxf(mrun, tmax);
                float al = fexp2(mrun - mnew);
                lrun *= al;
#pragma unroll
                for (int d = 0; d < 4; d++) o[d] *= al;
                mrun = mnew;
            }
#pragma unroll
            for (int i = 0; i < 16; i++) p[i] = fexp2(p[i] - mrun);
#pragma unroll
            for (int c = 0; c < 4; c++) {
                uint2 u;
                u.x = cvtpk(p[c * 4 + 0], p[c * 4 + 1]);
                u.y = cvtpk(p[c * 4 + 2], p[c * 4 + 3]);
                *(uint2*)(pw + c * 16 + g * 4) = u;
            }
            short8 pb_lo = *(const short8*)(pw + g * 8);
            short8 pb_hi = *(const short8*)(pw + 32 + g * 8);
            __builtin_amdgcn_s_setprio(1);
            f32x4 s4 = __builtin_amdgcn_mfma_f32_16x16x32_bf16(ones, pb_lo, z, 0, 0, 0);
            s4 = __builtin_amdgcn_mfma_f32_16x16x32_bf16(ones, pb_hi, s4, 0, 0, 0);
#pragma unroll
            for (int d = 0; d < 4; d++) {
                const unsigned short* vr = Vb_ + (d * 16 + l4) * 64;
                short8 va0 = *(const short8*)(vr + ((g ^ sw) * 8));
                short8 va1 = *(const short8*)(vr + (((g + 4) ^ sw) * 8));
                o[d] = __builtin_amdgcn_mfma_f32_16x16x32_bf16(va0, pb_lo, o[d], 0, 0, 0);
                o[d] = __builtin_amdgcn_mfma_f32_16x16x32_bf16(va1, pb_hi, o[d], 0, 0, 0);
            }
            __builtin_amdgcn_s_setprio(0);
            lrun += s4[0];
        }
        __syncthreads();
        buf ^= 1;
    }
    float inv = 1.f / lrun;
    unsigned short* Ob = O + (size_t)(b * Tc + q0 + l4) * Dc + h * DHc;
#pragma unroll
    for (int d = 0; d < 4; d++) {
#pragma unroll
        for (int r = 0; r < 4; r++) Ob[d * 16 + g * 4 + r] = f2bf(o[d][r] * inv);
    }
}

// ---------------- fused residual-add + LayerNorm (bf16 a + bf16 res) ----------------
__global__ __launch_bounds__(256) void ln_bf(const unsigned short* __restrict__ a,
                                             const unsigned short* __restrict__ res,
                                             const float* __restrict__ gam,
                                             const float* __restrict__ bet,
                                             unsigned short* __restrict__ outB,
                                             float* __restrict__ outF) {
    int row = blockIdx.x, t = threadIdx.x;
    size_t base = (size_t)row * Dc + t * 4;
    short4v av = *(const short4v*)(a + base);
    short4v rv = *(const short4v*)(res + base);
    float x0 = bf2f((unsigned short)av[0]) + bf2f((unsigned short)rv[0]);
    float x1 = bf2f((unsigned short)av[1]) + bf2f((unsigned short)rv[1]);
    float x2 = bf2f((unsigned short)av[2]) + bf2f((unsigned short)rv[2]);
    float x3 = bf2f((unsigned short)av[3]) + bf2f((unsigned short)rv[3]);
    float s = x0 + x1 + x2 + x3;
    float ss = x0 * x0 + x1 * x1 + x2 * x2 + x3 * x3;
    for (int o = 1; o < 64; o <<= 1) { s += __shfl_xor(s, o); ss += __shfl_xor(ss, o); }
    __shared__ float S1[4], S2[4];
    int w = t >> 6;
    if ((t & 63) == 0) { S1[w] = s; S2[w] = ss; }
    __syncthreads();
    s = S1[0] + S1[1] + S1[2] + S1[3];
    ss = S2[0] + S2[1] + S2[2] + S2[3];
    float mean = s * (1.f / Dc);
    float var = ss * (1.f / Dc) - mean * mean;
    float rstd = rsqrtf(var + 1e-5f);
    int c = t * 4;
    float4 g4 = *(const float4*)(gam + c);
    float4 b4 = *(const float4*)(bet + c);
    float y0 = (x0 - mean) * rstd * g4.x + b4.x;
    float y1 = (x1 - mean) * rstd * g4.y + b4.y;
    float y2 = (x2 - mean) * rstd * g4.z + b4.z;
    float y3 = (x3 - mean) * rstd * g4.w + b4.w;
    if (outB) {
        short4v ob;
        ob[0] = f2bf(y0); ob[1] = f2bf(y1); ob[2] = f2bf(y2); ob[3] = f2bf(y3);
        *(short4v*)(outB + base) = ob;
    }
    if (outF) { float4 ov = {y0, y1, y2, y3}; *(float4*)(outF + base) = ov; }
}

// ---------------- LN over 4 bf16 split-K partials + bf16 residual -> f32 out ----------------
__global__ __launch_bounds__(256) void ln_4b(const unsigned short* __restrict__ p,
                                             const unsigned short* __restrict__ res,
                                             const float* __restrict__ gam,
                                             const float* __restrict__ bet,
                                             float* __restrict__ outF) {
    const size_t PS = (size_t)4096 * 1024;
    int row = blockIdx.x, t = threadIdx.x;
    size_t base = (size_t)row * Dc + t * 4;
    float x0, x1, x2, x3;
    {
        short4v rv = *(const short4v*)(res + base);
        x0 = bf2f((unsigned short)rv[0]); x1 = bf2f((unsigned short)rv[1]);
        x2 = bf2f((unsigned short)rv[2]); x3 = bf2f((unsigned short)rv[3]);
    }
#pragma unroll
    for (int j = 0; j < 4; j++) {
        short4v v = *(const short4v*)(p + j * PS + base);
        x0 += bf2f((unsigned short)v[0]); x1 += bf2f((unsigned short)v[1]);
        x2 += bf2f((unsigned short)v[2]); x3 += bf2f((unsigned short)v[3]);
    }
    float s = x0 + x1 + x2 + x3;
    float ss = x0 * x0 + x1 * x1 + x2 * x2 + x3 * x3;
    for (int o = 1; o < 64; o <<= 1) { s += __shfl_xor(s, o); ss += __shfl_xor(ss, o); }
    __shared__ float S1[4], S2[4];
    int w = t >> 6;
    if ((t & 63) == 0) { S1[w] = s; S2[w] = ss; }
    __syncthreads();
    s = S1[0] + S1[1] + S1[2] + S1[3];
    ss = S2[0] + S2[1] + S2[2] + S2[3];
    float mean = s * (1.f / Dc);
    float var = ss * (1.f / Dc) - mean * mean;
    float rstd = rsqrtf(var + 1e-5f);
    int c = t * 4;
    float4 g4 = *(const float4*)(gam + c);
    float4 b4 = *(const float4*)(bet + c);
    float4 ov;
    ov.x = (x0 - mean) * rstd * g4.x + b4.x;
    ov.y = (x1 - mean) * rstd * g4.y + b4.y;
    ov.z = (x2 - mean) * rstd * g4.z + b4.z;
    ov.w = (x3 - mean) * rstd * g4.w + b4.w;
    *(float4*)(outF + base) = ov;
}

// ---------------- launch ----------------
extern "C" void kernel_launch(void* const* d_in, const int* in_sizes, int n_in,
                              void* d_out, int out_size, void* d_ws, size_t ws_size,
                              hipStream_t stream) {
    const float* x   = (const float*)d_in[0];
    const float* enc = (const float*)d_in[1];
    const float* dWq = (const float*)d_in[4];  const float* dbq = (const float*)d_in[5];
    const float* dWk = (const float*)d_in[6];  const float* dbk = (const float*)d_in[7];
    const float* dWv = (const float*)d_in[8];  const float* dbv = (const float*)d_in[9];
    const float* dWo = (const float*)d_in[10]; const float* dbo = (const float*)d_in[11];
    const float* eWq = (const float*)d_in[12]; const float* ebq = (const float*)d_in[13];
    const float* eWk = (const float*)d_in[14]; const float* ebk = (const float*)d_in[15];
    const float* eWv = (const float*)d_in[16]; const float* ebv = (const float*)d_in[17];
    const float* eWo = (const float*)d_in[18]; const float* ebo = (const float*)d_in[19];
    const float* fW1 = (const float*)d_in[20]; const float* fb1 = (const float*)d_in[21];
    const float* fW2 = (const float*)d_in[22]; const float* fb2 = (const float*)d_in[23];
    const float* g1 = (const float*)d_in[24];  const float* be1 = (const float*)d_in[25];
    const float* g2 = (const float*)d_in[26];  const float* be2 = (const float*)d_in[27];
    const float* g3 = (const float*)d_in[28];  const float* be3 = (const float*)d_in[29];

    const float SC = 0.125f * 1.44269504f;

    char* ws = (char*)d_ws;
    size_t off = 0;
    auto alloc = [&](size_t bytes) -> void* {
        void* p = ws + off;
        off += (bytes + 255) & ~(size_t)255;
        return p;
    };
    const size_t A = (size_t)4096 * 1024;
    const size_t MB1 = (size_t)1024 * 1024;
    char* R1 = (char*)alloc(32 * 1024 * 1024);
    unsigned short* qkv = (unsigned short*)R1;                       // stride 3072
    unsigned short* kvx = (unsigned short*)R1;                       // stride 2048
    unsigned short* qx  = (unsigned short*)(R1 + 16 * 1024 * 1024);  // stride 1024
    unsigned short* h1  = (unsigned short*)R1;                       // 4096x4096
    unsigned short* xb   = (unsigned short*)alloc(A * 2);
    unsigned short* encb = (unsigned short*)alloc(A * 2);
    unsigned short* wqkv = (unsigned short*)alloc(3 * MB1 * 2);
    unsigned short* wekv = (unsigned short*)alloc(2 * MB1 * 2);
    unsigned short* weq  = (unsigned short*)alloc(MB1 * 2);
    unsigned short* wdo  = (unsigned short*)alloc(MB1 * 2);
    unsigned short* weo  = (unsigned short*)alloc(MB1 * 2);
    unsigned short* wf1  = (unsigned short*)alloc(4 * MB1 * 2);
    unsigned short* wf2  = (unsigned short*)alloc(4 * MB1 * 2);
    float* bqkv = (float*)alloc(3072 * 4);
    float* bekv = (float*)alloc(2048 * 4);
    float* ebq_s = (float*)alloc(1024 * 4);
    unsigned short* VtB = (unsigned short*)alloc(A * 2);
    unsigned short* ab  = (unsigned short*)alloc(A * 2);
    unsigned short* tmpB = (unsigned short*)alloc(A * 2);
    unsigned short* dB = (unsigned short*)alloc(A * 2);
    unsigned short* fB = (unsigned short*)alloc(A * 2);
    unsigned short* pfb = VtB;
    (void)ws_size; (void)in_sizes; (void)n_in; (void)out_size;

    dim3 tb(32, 8);
    cast2_f32_bf16<<<dim3(2048, 2), 256, 0, stream>>>(x, enc, xb, encb, (int)(A / 8));
    TP8 tp;
    tp.s[0] = dWq; tp.d[0] = wqkv;           tp.scl[0] = SC;
    tp.s[1] = dWk; tp.d[1] = wqkv + MB1;     tp.scl[1] = 1.f;
    tp.s[2] = dWv; tp.d[2] = wqkv + 2 * MB1; tp.scl[2] = 1.f;
    tp.s[3] = eWk; tp.d[3] = wekv;           tp.scl[3] = 1.f;
    tp.s[4] = eWv; tp.d[4] = wekv + MB1;     tp.scl[4] = 1.f;
    tp.s[5] = eWq; tp.d[5] = weq;            tp.scl[5] = SC;
    tp.s[6] = dWo; tp.d[6] = wdo;            tp.scl[6] = 1.f;
    tp.s[7] = eWo; tp.d[7] = weo;            tp.scl[7] = 1.f;
    transpose_cast8<<<dim3(32, 32, 8), tb, 0, stream>>>(tp);
    transpose_cast<<<dim3(128, 32), tb, 0, stream>>>(fW1, wf1, 1024, 4096);
    transpose_cast<<<dim3(32, 128), tb, 0, stream>>>(fW2, wf2, 4096, 1024);
    prep_bias<<<24, 256, 0, stream>>>(dbq, dbk, dbv, ebk, ebv, ebq, bqkv, bekv, ebq_s, SC);

    P8 z8{};

    // ---- self-attention block ----
    gemm256<0><<<dim3(12, 16), 512, 0, stream>>>(xb, wqkv, bqkv, qkv, 3072, 1024, 1024, 16, z8);
    transpose_v<<<dim3(16, 64), 256, 0, stream>>>(qkv + 2048, 3072, VtB);
    attn6_kernel<1><<<dim3(64, 8), 512, 0, stream>>>(qkv, 3072, qkv + 1024, 3072, VtB, ab);
    gemm64_db<0><<<dim3(8, 64), 256, 0, stream>>>(ab, wdo, dbo, nullptr, tmpB, 4096, 1024, 1024, 1024, 1024);
    ln_bf<<<4096, 256, 0, stream>>>(tmpB, xb, g1, be1, dB, nullptr);

    // ---- cross-attention block ----
    {
        P8 pe{};
        pe.o[0] = kvx;
        pe.o[1] = VtB;
        gemm256<3><<<dim3(8, 16, 2), 512, 0, stream>>>(encb, wekv, bekv, nullptr, 2048, 1024, 1024, 8, pe);
        combine2<<<4096, 256, 0, stream>>>(kvx, VtB, (int)((size_t)4096 * 2048 / 8));
    }
    gemm64_db<0><<<dim3(8, 64), 256, 0, stream>>>(dB, weq, ebq_s, nullptr, qx, 4096, 1024, 1024, 1024, 1024);
    transpose_v<<<dim3(16, 64), 256, 0, stream>>>(kvx + 1024, 2048, VtB);
    attn6_kernel<0><<<dim3(64, 8), 512, 0, stream>>>(qx, 1024, kvx, 2048, VtB, ab);
    gemm64_db<0><<<dim3(8, 64), 256, 0, stream>>>(ab, weo, ebo, nullptr, tmpB, 4096, 1024, 1024, 1024, 1024);
    ln_bf<<<4096, 256, 0, stream>>>(tmpB, dB, g2, be2, fB, nullptr);

    // ---- FFN block ----
    gemm256<2><<<dim3(16, 16), 512, 0, stream>>>(fB, wf1, fb1, h1, 4096, 1024, 1024, 16, z8);
    {
        P8 pf{};
        pf.o[0] = pfb;
        pf.o[1] = pfb + A;
        pf.o[2] = pfb + 2 * A;
        pf.o[3] = pfb + 3 * A;
        gemm256<3><<<dim3(4, 16, 4), 512, 0, stream>>>(h1, wf2, fb2, nullptr, 1024, 4096, 4096, 16, pf);
    }
    ln_4b<<<4096, 256, 0, stream>>>(pfb, fB, g3, be3, (float*)d_out);
}

// Round 16
// 321.261 us; speedup vs baseline: 1.0479x; 1.0143x over previous
//
#include <hip/hip_runtime.h>

static constexpr int Bc = 4, Tc = 1024, Sc = 1024, Dc = 1024, Hc = 16, DHc = 64, FFc = 4096;

typedef __attribute__((ext_vector_type(8))) short short8;
typedef __attribute__((ext_vector_type(4))) short short4v;
typedef __attribute__((ext_vector_type(4))) float f32x4;

struct P8 { unsigned short* o[8]; };

__device__ __forceinline__ unsigned short f2bf(float f) {
    unsigned int u = __float_as_uint(f);
    unsigned int r = u + 0x7fffu + ((u >> 16) & 1u);
    return (unsigned short)(r >> 16);
}
__device__ __forceinline__ float bf2f(unsigned short u) {
    return __uint_as_float(((unsigned int)u) << 16);
}
__device__ __forceinline__ float fexp2(float x) {
    float r; asm("v_exp_f32 %0, %1" : "=v"(r) : "v"(x)); return r;
}
__device__ __forceinline__ unsigned int cvtpk(float a, float b) {
    unsigned int r;
    asm("v_cvt_pk_bf16_f32 %0, %1, %2" : "=v"(r) : "v"(a), "v"(b));
    return r;
}

__device__ __forceinline__ void gload_lds16(const void* g, void* l) {
    __builtin_amdgcn_global_load_lds((const __attribute__((address_space(1))) void*)g,
                                     (__attribute__((address_space(3))) void*)l, 16, 0, 0);
}

// ---------------- cast f32 -> bf16 (two tensors in one launch) ----------------
__global__ __launch_bounds__(256) void cast2_f32_bf16(const float* __restrict__ inA,
                                                      const float* __restrict__ inB,
                                                      unsigned short* __restrict__ outA,
                                                      unsigned short* __restrict__ outB, int n8) {
    int i = blockIdx.x * 256 + threadIdx.x;
    if (i >= n8) return;
    const float* in = blockIdx.y ? inB : inA;
    unsigned short* out = blockIdx.y ? outB : outA;
    const float4* p = (const float4*)in + (size_t)i * 2;
    float4 a = p[0], b = p[1];
    short8 o;
    o[0] = f2bf(a.x); o[1] = f2bf(a.y); o[2] = f2bf(a.z); o[3] = f2bf(a.w);
    o[4] = f2bf(b.x); o[5] = f2bf(b.y); o[6] = f2bf(b.z); o[7] = f2bf(b.w);
    *(short8*)(out + (size_t)i * 8) = o;
}

// ---------------- unified weight transpose+cast: 16 jobs of 1024x1024 views ----------------
// out[n][k] = scl * in[k][n]; 64x64 tiles, float4 reads, short8 coalesced writes.
struct TJ { const float* s; unsigned short* d; int ss, ds; float scl; };
struct TJ16 { TJ j[16]; };
__global__ __launch_bounds__(256) void transpose_cast16(TJ16 p) {
    __shared__ float t[64][65];
    const TJ jb = p.j[blockIdx.z];
    const int c0 = blockIdx.x * 64, r0 = blockIdx.y * 64;   // src col / src row tile origin
    const int tid = threadIdx.x;
    const int rr = tid >> 2, cc = (tid & 3) * 16;
    const float* src = jb.s + (size_t)(r0 + rr) * jb.ss + c0 + cc;
#pragma unroll
    for (int i = 0; i < 4; i++) {
        float4 v = *(const float4*)(src + i * 4);
        t[rr][cc + i * 4 + 0] = v.x;
        t[rr][cc + i * 4 + 1] = v.y;
        t[rr][cc + i * 4 + 2] = v.z;
        t[rr][cc + i * 4 + 3] = v.w;
    }
    __syncthreads();
#pragma unroll
    for (int half = 0; half < 2; half++) {
        const int id = half * 256 + tid;
        const int a = id >> 3, b0 = id & 7;     // out-row (src col) a; 8-elem chunk b0
        short8 o;
#pragma unroll
        for (int e = 0; e < 8; e++) o[e] = f2bf(t[b0 * 8 + e][a] * jb.scl);
        *(short8*)(jb.d + (size_t)(c0 + a) * jb.ds + r0 + b0 * 8) = o;
    }
}

// ---------------- all bias prep in one launch (6144 elems) ----------------
__global__ void prep_bias(const float* dbq, const float* dbk, const float* dbv,
                          const float* ebk, const float* ebv, const float* ebq,
                          float* __restrict__ bqkv, float* __restrict__ bekv,
                          float* __restrict__ ebq_s, float SC) {
    int i = blockIdx.x * 256 + threadIdx.x;
    int seg = i >> 10, j = i & 1023;
    switch (seg) {
        case 0: bqkv[j] = dbq[j] * SC; break;
        case 1: bqkv[1024 + j] = dbk[j]; break;
        case 2: bqkv[2048 + j] = dbv[j]; break;
        case 3: bekv[j] = ebk[j]; break;
        case 4: bekv[1024 + j] = ebv[j]; break;
        default: ebq_s[j] = ebq[j] * SC; break;
    }
}

// ---------------- in-place bf16 add: dst += p1 ----------------
__global__ __launch_bounds__(256) void combine2(unsigned short* __restrict__ dst,
                                                const unsigned short* __restrict__ p1, int n8) {
    int i = blockIdx.x * 256 + threadIdx.x;
    if (i >= n8) return;
    short8 a = *(short8*)(dst + (size_t)i * 8);
    short8 b = *(const short8*)(p1 + (size_t)i * 8);
    short8 o;
#pragma unroll
    for (int j = 0; j < 8; j++)
        o[j] = f2bf(bf2f((unsigned short)a[j]) + bf2f((unsigned short)b[j]));
    *(short8*)(dst + (size_t)i * 8) = o;
}

// ---------------- per-head V transpose ----------------
__global__ __launch_bounds__(256) void transpose_v(const unsigned short* __restrict__ V, int ldv,
                                                   unsigned short* __restrict__ Vt) {
    __shared__ unsigned short t[64 * 64];
    const int bh = blockIdx.y, b = bh >> 4, h = bh & 15;
    const int s0 = blockIdx.x * 64;
    const int tid = threadIdx.x;
    const int r = tid >> 2, ch = tid & 3;
    const unsigned short* src = V + (size_t)(b * 1024 + s0 + r) * ldv + h * 64 + ch * 16;
    short8 v0 = *(const short8*)src;
    short8 v1 = *(const short8*)(src + 8);
    int pw_ = (ch ^ r ^ (r >> 4)) & 3;
    *(short8*)(t + r * 64 + pw_ * 16) = v0;
    *(short8*)(t + r * 64 + pw_ * 16 + 8) = v1;
    __syncthreads();
    const int dh = tid >> 2, sc = (tid & 3) * 16;
    short8 o0, o1;
#pragma unroll
    for (int j = 0; j < 8; j++) {
        int c0 = sc + j, c1 = sc + 8 + j;
        o0[j] = t[c0 * 64 + (((dh >> 4) ^ c0 ^ (c0 >> 4)) & 3) * 16 + (dh & 15)];
        o1[j] = t[c1 * 64 + (((dh >> 4) ^ c1 ^ (c1 >> 4)) & 3) * 16 + (dh & 15)];
    }
    unsigned short* dst = Vt + ((size_t)bh * 64 + dh) * 1024 + s0 + sc;
    *(short8*)dst = o0;
    *(short8*)(dst + 8) = o1;
}

// ---- block remap: chunked-XCD + group-major rasterization (bijective, nwg%8==0) ----
struct BlkMap { int m, n, z; };
__device__ __forceinline__ BlkMap remap_block() {
    const int gx = gridDim.x, gy = gridDim.y;
    const int nxy = gx * gy;
    const int nwg = nxy * gridDim.z;
    const int flat = (blockIdx.z * gy + blockIdx.y) * gx + blockIdx.x;
    const int id = (flat & 7) * (nwg >> 3) + (flat >> 3);
    const int pz = id / nxy;
    const int rz = id - pz * nxy;
    const int gwsh = (gx & 7) ? 2 : 3;
    const int gw = 1 << gwsh;
    const int gsz = gw * gy;
    const int grp = rz / gsz;
    const int rem = rz - grp * gsz;
    BlkMap r;
    r.m = rem >> gwsh;
    r.n = (grp << gwsh) + (rem & (gw - 1));
    r.z = pz;
    return r;
}

// ================= GEMM 256x256, BK=64, 8 waves, m201 8-phase counted-vmcnt ============
template <int EPI>
__global__ __launch_bounds__(512, 2) void gemm256(const unsigned short* __restrict__ A,
                                                  const unsigned short* __restrict__ Bt,
                                                  const float* __restrict__ bias,
                                                  unsigned short* __restrict__ outB,
                                                  int N, int lda, int ldb, int nk, P8 po) {
    __shared__ unsigned short SM[2][2][2][8192];   // 128 KiB
    const int tid = threadIdx.x;
    const int lane = tid & 63, wid = tid >> 6;
    const int l4 = lane & 15, g = lane >> 4;
    const int wr = wid >> 2, wc = wid & 3;
    BlkMap bm = remap_block();
    const int m0 = bm.m * 256, n0 = bm.n * 256, z = bm.z;
    A += (size_t)z * (nk * 64);
    Bt += (size_t)z * (nk * 64);
    const int sw = l4 & 7;

    const int fl0 = tid, fl1 = 512 + tid;
    const int lr0 = fl0 >> 3, ch0 = (fl0 & 7) ^ (lr0 & 7);
    const int lr1 = fl1 >> 3, ch1 = (fl1 & 7) ^ (lr1 & 7);
    const size_t A64 = (size_t)64 * lda;
    const unsigned short* pA0 = A + (size_t)(m0 + (lr0 >> 6) * 128 + (lr0 & 63)) * lda + ch0 * 8;
    const unsigned short* pA1 = A + (size_t)(m0 + (lr1 >> 6) * 128 + (lr1 & 63)) * lda + ch1 * 8;
    const unsigned short* pB0 = Bt + (size_t)(n0 + (ch0 >> 2) * 128 + lr0) * ldb + (ch0 & 3) * 8;
    const unsigned short* pB1 = Bt + (size_t)(n0 + (ch1 >> 2) * 128 + lr1) * ldb + (ch1 & 3) * 8;

    auto stA = [&](int d, int mh, int kofs) {
        char* base = (char*)&SM[0][d][mh][0];
        gload_lds16(pA0 + (size_t)mh * A64 + kofs, base + fl0 * 16);
        gload_lds16(pA1 + (size_t)mh * A64 + kofs, base + fl1 * 16);
    };
    auto stB = [&](int d, int ks, int kofs) {
        char* base = (char*)&SM[1][d][ks][0];
        gload_lds16(pB0 + ks * 32 + kofs, base + fl0 * 16);
        gload_lds16(pB1 + ks * 32 + kofs, base + fl1 * 16);
    };

    f32x4 acc[8][4] = {};
    short8 aF[4], aH[4], b0[4], b1[4];

    auto ldA = [&](int d, int mh, short8* d0, short8* d1) {
#pragma unroll
        for (int m = 0; m < 4; m++) {
            const char* rp = (const char*)&SM[0][d][mh][0] + (wr * 64 + m * 16 + l4) * 128;
            d0[m] = *(const short8*)(rp + ((g ^ sw) * 16));
            d1[m] = *(const short8*)(rp + (((4 + g) ^ sw) * 16));
        }
    };
    auto ldB = [&](int d, int ks, short8* dst) {
#pragma unroll
        for (int n = 0; n < 4; n++) {
            const char* rp = (const char*)&SM[1][d][ks][0] + ((wc & 1) * 64 + n * 16 + l4) * 128;
            dst[n] = *(const short8*)(rp + ((((wc >> 1) * 4 + g) ^ sw) * 16));
        }
    };

#define MFMA16(aa, bb, base)                                                                  \
    _Pragma("unroll") for (int m_ = 0; m_ < 4; m_++)                                          \
        _Pragma("unroll") for (int n_ = 0; n_ < 4; n_++)                                      \
            acc[(base) + m_][n_] = __builtin_amdgcn_mfma_f32_16x16x32_bf16(                   \
                (aa)[m_], (bb)[n_], acc[(base) + m_][n_], 0, 0, 0);

    stB(0, 0, 0); stA(0, 0, 0); stB(0, 1, 0); stA(0, 1, 0);
    stB(1, 0, 64); stA(1, 0, 64); stB(1, 1, 64);
    asm volatile("s_waitcnt vmcnt(6)" ::: "memory");
    __builtin_amdgcn_s_barrier();

    const int nIter = nk >> 1;
    for (int it = 0; it < nIter; ++it) {
        const int t = 2 * it, u = t + 1;
        const int ku = u * 64;
        const int kv = ((t + 2 < nk) ? t + 2 : t) * 64;
        const int kw = ((u + 2 < nk) ? u + 2 : u) * 64;
        // ---- P0 (t: mh0,ks0) ----
        ldB(0, 0, b0); ldA(0, 0, aF, aH);
        stA(1, 1, ku);
        asm volatile("s_waitcnt lgkmcnt(8)" ::: "memory");
        __builtin_amdgcn_s_barrier();
        asm volatile("s_waitcnt lgkmcnt(0)" ::: "memory");
        __builtin_amdgcn_s_setprio(1); MFMA16(aF, b0, 0); __builtin_amdgcn_s_setprio(0);
        __builtin_amdgcn_s_barrier();
        // ---- P1 (t: mh0,ks1) ----
        ldB(0, 1, b1);
        stB(0, 0, kv);
        __builtin_amdgcn_s_barrier();
        asm volatile("s_waitcnt lgkmcnt(0)" ::: "memory");
        __builtin_amdgcn_s_setprio(1); MFMA16(aH, b1, 0); __builtin_amdgcn_s_setprio(0);
        __builtin_amdgcn_s_barrier();
        // ---- P2 (t: mh1,ks1) ----
        ldA(0, 1, aF, aH);
        stA(0, 0, kv);
        __builtin_amdgcn_s_barrier();
        asm volatile("s_waitcnt lgkmcnt(0)" ::: "memory");
        __builtin_amdgcn_s_setprio(1); MFMA16(aH, b1, 4); __builtin_amdgcn_s_setprio(0);
        __builtin_amdgcn_s_barrier();
        // ---- P3 (t: mh1,ks0) ----
        stB(0, 1, kv);
        __builtin_amdgcn_s_barrier();
        __builtin_amdgcn_s_setprio(1); MFMA16(aF, b0, 4); __builtin_amdgcn_s_setprio(0);
        asm volatile("s_waitcnt vmcnt(6)" ::: "memory");
        __builtin_amdgcn_s_barrier();
        // ---- P4 (u: mh0,ks0) ----
        ldB(1, 0, b0); ldA(1, 0, aF, aH);
        stA(0, 1, kv);
        asm volatile("s_waitcnt lgkmcnt(8)" ::: "memory");
        __builtin_amdgcn_s_barrier();
        asm volatile("s_waitcnt lgkmcnt(0)" ::: "memory");
        __builtin_amdgcn_s_setprio(1); MFMA16(aF, b0, 0); __builtin_amdgcn_s_setprio(0);
        __builtin_amdgcn_s_barrier();
        // ---- P5 (u: mh0,ks1) ----
        ldB(1, 1, b1);
        stB(1, 0, kw);
        __builtin_amdgcn_s_barrier();
        asm volatile("s_waitcnt lgkmcnt(0)" ::: "memory");
        __builtin_amdgcn_s_setprio(1); MFMA16(aH, b1, 0); __builtin_amdgcn_s_setprio(0);
        __builtin_amdgcn_s_barrier();
        // ---- P6 (u: mh1,ks1) ----
        ldA(1, 1, aF, aH);
        stA(1, 0, kw);
        __builtin_amdgcn_s_barrier();
        asm volatile("s_waitcnt lgkmcnt(0)" ::: "memory");
        __builtin_amdgcn_s_setprio(1); MFMA16(aH, b1, 4); __builtin_amdgcn_s_setprio(0);
        __builtin_amdgcn_s_barrier();
        // ---- P7 (u: mh1,ks0) ----
        stB(1, 1, kw);
        __builtin_amdgcn_s_barrier();
        __builtin_amdgcn_s_setprio(1); MFMA16(aF, b0, 4); __builtin_amdgcn_s_setprio(0);
        asm volatile("s_waitcnt vmcnt(6)" ::: "memory");
        __builtin_amdgcn_s_barrier();
    }
    asm volatile("s_waitcnt vmcnt(0)" ::: "memory");
    __syncthreads();

    // ---- coalesced epilogue via LDS staging (half-tile at a time) ----
    unsigned short* eb = (unsigned short*)SM;
    unsigned short* oB = (EPI == 3) ? po.o[z] : outB;
    const int colL = wc * 64 + l4;
#pragma unroll
    for (int h = 0; h < 2; ++h) {
        if (wr == h) {
#pragma unroll
            for (int mm = 0; mm < 8; mm++) {
                const int base_r = (mm < 4 ? mm * 16 : 64 + (mm - 4) * 16) + g * 4;
#pragma unroll
                for (int n = 0; n < 4; n++) {
                    float bv = (EPI == 3 && z != 0) ? 0.f : bias[n0 + colL + n * 16];
#pragma unroll
                    for (int r = 0; r < 4; r++) {
                        float v = acc[mm][n][r] + bv;
                        if (EPI == 2) v = fmaxf(v, 0.f);
                        eb[(base_r + r) * 260 + colL + n * 16] = f2bf(v);
                    }
                }
            }
        }
        __syncthreads();
        const int gr0 = m0 + h * 128;
#pragma unroll
        for (int j = 0; j < 8; j++) {
            const int f = j * 8192 + tid * 16;
            const int row = f >> 9;
            const int colb = f & 511;
            short8 v = *(const short8*)((const char*)eb + row * 520 + colb);
            *(short8*)(oB + (size_t)(gr0 + row) * N + n0 + (colb >> 1)) = v;
        }
        if (h == 0) __syncthreads();
    }
#undef MFMA16
}

// ---------------- GEMM 64x128: 3-buffer depth-2, counted vmcnt, XCD-swizzled ----------------
template <int EPI>
__global__ __launch_bounds__(256) void gemm64_db(const unsigned short* __restrict__ A,
                                                 const unsigned short* __restrict__ Bt,
                                                 const float* __restrict__ bias,
                                                 float* __restrict__ outF,
                                                 unsigned short* __restrict__ outB,
                                                 int M, int N, int Kloop, int lda, int ldb) {
    __shared__ unsigned short As[3][64 * 32];
    __shared__ unsigned short Bs[3][128 * 32];
    const int tid = threadIdx.x;
    const int w = tid >> 6, lane = tid & 63, l4 = lane & 15, g = lane >> 4;
    BlkMap bm = remap_block();
    const int m0 = bm.m * 64, n0 = bm.n * 128;
    f32x4 acc[4][2] = {};
    const int r0 = tid >> 2;
    const int kk = ((tid & 3) ^ ((tid >> 3) & 3)) * 8;
    const int sk = (l4 >> 1) & 3;
    const unsigned short* Ar0 = A + (size_t)(m0 + r0) * lda + kk;
    const unsigned short* Br0 = Bt + (size_t)(n0 + r0) * ldb + kk;
    const unsigned short* Br1 = Bt + (size_t)(n0 + 64 + r0) * ldb + kk;
    auto stage = [&](int sb, int k0) {
        gload_lds16(Ar0 + k0, (char*)As[sb] + tid * 16);
        gload_lds16(Br0 + k0, (char*)Bs[sb] + tid * 16);
        gload_lds16(Br1 + k0, (char*)Bs[sb] + 4096 + tid * 16);
    };
    const int nk = Kloop >> 5;
    stage(0, 0);
    stage(1, 32);
    asm volatile("s_waitcnt vmcnt(3)" ::: "memory");
    __builtin_amdgcn_s_barrier();
    asm volatile("" ::: "memory");
    int buf = 0;
    for (int t = 0; t < nk; ++t) {
        if (t + 2 < nk) {
            int b2 = buf + 2; if (b2 >= 3) b2 -= 3;
            stage(b2, (t + 2) * 32);
        }
        short8 a[4], b[2];
#pragma unroll
        for (int m = 0; m < 4; m++)
            a[m] = *(const short8*)(As[buf] + (m * 16 + l4) * 32 + (g ^ sk) * 8);
#pragma unroll
        for (int n = 0; n < 2; n++)
            b[n] = *(const short8*)(Bs[buf] + (w * 32 + n * 16 + l4) * 32 + (g ^ sk) * 8);
#pragma unroll
        for (int m = 0; m < 4; m++)
#pragma unroll
            for (int n = 0; n < 2; n++)
                acc[m][n] = __builtin_amdgcn_mfma_f32_16x16x32_bf16(a[m], b[n], acc[m][n], 0, 0, 0);
        if (t + 1 < nk) {
            if (t + 2 < nk) asm volatile("s_waitcnt vmcnt(3)" ::: "memory");
            else            asm volatile("s_waitcnt vmcnt(0)" ::: "memory");
            __builtin_amdgcn_s_barrier();
            asm volatile("" ::: "memory");
        }
        buf = (buf + 1 == 3) ? 0 : buf + 1;
    }
    const int rowB = m0 + g * 4;
    const int colB = n0 + w * 32 + l4;
#pragma unroll
    for (int n = 0; n < 2; n++) {
        float bv = bias[colB + n * 16];
#pragma unroll
        for (int m = 0; m < 4; m++) {
#pragma unroll
            for (int r = 0; r < 4; r++) {
                float v = acc[m][n][r] + bv;
                if (EPI == 2) v = fmaxf(v, 0.f);
                size_t idx = (size_t)(rowB + m * 16 + r) * N + colB + n * 16;
                if (EPI == 1) outF[idx] = v;
                else outB[idx] = f2bf(v);
            }
        }
    }
}

// ---------------- flash attention v6: 8 waves / 128 q-rows per block ----------------
template <int CAUSAL>
__global__ __launch_bounds__(512) void attn6_kernel(const unsigned short* __restrict__ Q, int ldq,
                                                    const unsigned short* __restrict__ Kg, int ldk,
                                                    const unsigned short* __restrict__ Vt,
                                                    unsigned short* __restrict__ O) {
    __shared__ unsigned short Kl[2 * 64 * 64];
    __shared__ unsigned short Vl[2 * 64 * 64];
    __shared__ unsigned short Pl[8][16 * 72];
    const int bh = blockIdx.x;
    const int qb = CAUSAL ? (gridDim.y - 1 - blockIdx.y) : blockIdx.y;
    const int b = bh >> 4, h = bh & 15;
    const int tid = threadIdx.x, w = tid >> 6, lane = tid & 63;
    const int l4 = lane & 15, g = lane >> 4;
    const int q0 = qb * 128 + w * 16;
    const unsigned short* Qp = Q + (size_t)(b * Tc + q0 + l4) * ldq + h * DHc + g * 8;
    short8 qf0 = *(const short8*)Qp;
    short8 qf1 = *(const short8*)(Qp + 32);
    const unsigned short* Kbase = Kg + (size_t)(b * 1024) * ldk + h * DHc;
    const unsigned short* Vbase = Vt + (size_t)bh * DHc * 1024;
    f32x4 o[4] = {};
    float mrun = -1e30f, lrun = 0.f;
    const int nT = CAUSAL ? 2 * qb + 2 : 16;
    unsigned short* pw = &Pl[w][l4 * 72];
    const int qi = q0 + l4;

    short8 ones;
#pragma unroll
    for (int j = 0; j < 8; j++) ones[j] = (short)0x3F80;

    const int sr = tid >> 3;
    const int sc_ = (tid & 7) ^ (sr & 7);

    auto stage = [&](int s0, int buf) {
        char* kd = (char*)Kl + buf * 8192;
        char* vd = (char*)Vl + buf * 8192;
        gload_lds16(Kbase + (size_t)(s0 + sr) * ldk + sc_ * 8, kd + tid * 16);
        gload_lds16(Vbase + (size_t)sr * 1024 + s0 + sc_ * 8, vd + tid * 16);
    };

    stage(0, 0);
    __syncthreads();
    int buf = 0;
    const int sw = l4 & 7;

    for (int t = 0; t < nT; ++t) {
        const int s0 = t * 64;
        if (t + 1 < nT) stage(s0 + 64, buf ^ 1);
        if (!CAUSAL || s0 <= q0 + 15) {
            const unsigned short* Kb_ = Kl + buf * 4096;
            const unsigned short* Vb_ = Vl + buf * 4096;
            f32x4 st[4];
            f32x4 z = {0.f, 0.f, 0.f, 0.f};
            __builtin_amdgcn_s_setprio(1);
#pragma unroll
            for (int c = 0; c < 4; c++) {
                const unsigned short* kr = Kb_ + (c * 16 + l4) * 64;
                short8 ka0 = *(const short8*)(kr + ((g ^ sw) * 8));
                short8 ka1 = *(const short8*)(kr + (((g + 4) ^ sw) * 8));
                st[c] = __builtin_amdgcn_mfma_f32_16x16x32_bf16(ka0, qf0, z, 0, 0, 0);
                st[c] = __builtin_amdgcn_mfma_f32_16x16x32_bf16(ka1, qf1, st[c], 0, 0, 0);
            }
            __builtin_amdgcn_s_setprio(0);
            float p[16];
            const bool domask = CAUSAL && (s0 + 63 > q0);
#pragma unroll
            for (int c = 0; c < 4; c++)
#pragma unroll
                for (int r = 0; r < 4; r++) {
                    float v = st[c][r];
                    if (domask && (s0 + c * 16 + g * 4 + r) > qi) v = -1e9f;
                    p[c * 4 + r] = v;
                }
            float m1 = fmaxf(fmaxf(p[0], p[1]), p[2]);
            float m2 = fmaxf(fmaxf(p[3], p[4]), p[5]);
            float m3 = fmaxf(fmaxf(p[6], p[7]), p[8]);
            float m4 = fmaxf(fmaxf(p[9], p[10]), p[11]);
            float m5 = fmaxf(fmaxf(p[12], p[13]), p[14]);
            float tmax = fmaxf(fmaxf(fmaxf(m1, m2), fmaxf(m3, m4)), fmaxf(m5, p[15]));
            tmax = fmaxf(tmax, __shfl_xor(tmax, 16));
            tmax = fmaxf(tmax, __shfl_xor(tmax, 32));
            if (!__all(tmax <= mrun + 11.5f)) {
                float mnew = fmaxf(mrun, tmax);
                float al = fexp2(mrun - mnew);
                lrun *= al;
#pragma unroll
                for (int d = 0; d < 4; d++) o[d] *= al;
                mrun = mnew;
            }
#pragma unroll
            for (int i = 0; i < 16; i++) p[i] = fexp2(p[i] - mrun);
#pragma unroll
            for (int c = 0; c < 4; c++) {
                uint2 u;
                u.x = cvtpk(p[c * 4 + 0], p[c * 4 + 1]);
                u.y = cvtpk(p[c * 4 + 2], p[c * 4 + 3]);
                *(uint2*)(pw + c * 16 + g * 4) = u;
            }
            short8 pb_lo = *(const short8*)(pw + g * 8);
            short8 pb_hi = *(const short8*)(pw + 32 + g * 8);
            __builtin_amdgcn_s_setprio(1);
            f32x4 s4 = __builtin_amdgcn_mfma_f32_16x16x32_bf16(ones, pb_lo, z, 0, 0, 0);
            s4 = __builtin_amdgcn_mfma_f32_16x16x32_bf16(ones, pb_hi, s4, 0, 0, 0);
#pragma unroll
            for (int d = 0; d < 4; d++) {
                const unsigned short* vr = Vb_ + (d * 16 + l4) * 64;
                short8 va0 = *(const short8*)(vr + ((g ^ sw) * 8));
                short8 va1 = *(const short8*)(vr + (((g + 4) ^ sw) * 8));
                o[d] = __builtin_amdgcn_mfma_f32_16x16x32_bf16(va0, pb_lo, o[d], 0, 0, 0);
                o[d] = __builtin_amdgcn_mfma_f32_16x16x32_bf16(va1, pb_hi, o[d], 0, 0, 0);
            }
            __builtin_amdgcn_s_setprio(0);
            lrun += s4[0];
        }
        __syncthreads();
        buf ^= 1;
    }
    float inv = 1.f / lrun;
    unsigned short* Ob = O + (size_t)(b * Tc + q0 + l4) * Dc + h * DHc;
#pragma unroll
    for (int d = 0; d < 4; d++) {
#pragma unroll
        for (int r = 0; r < 4; r++) Ob[d * 16 + g * 4 + r] = f2bf(o[d][r] * inv);
    }
}

// ---------------- fused residual-add + LayerNorm (bf16 a + bf16 res) ----------------
__global__ __launch_bounds__(256) void ln_bf(const unsigned short* __restrict__ a,
                                             const unsigned short* __restrict__ res,
                                             const float* __restrict__ gam,
                                             const float* __restrict__ bet,
                                             unsigned short* __restrict__ outB,
                                             float* __restrict__ outF) {
    int row = blockIdx.x, t = threadIdx.x;
    size_t base = (size_t)row * Dc + t * 4;
    short4v av = *(const short4v*)(a + base);
    short4v rv = *(const short4v*)(res + base);
    float x0 = bf2f((unsigned short)av[0]) + bf2f((unsigned short)rv[0]);
    float x1 = bf2f((unsigned short)av[1]) + bf2f((unsigned short)rv[1]);
    float x2 = bf2f((unsigned short)av[2]) + bf2f((unsigned short)rv[2]);
    float x3 = bf2f((unsigned short)av[3]) + bf2f((unsigned short)rv[3]);
    float s = x0 + x1 + x2 + x3;
    float ss = x0 * x0 + x1 * x1 + x2 * x2 + x3 * x3;
    for (int o = 1; o < 64; o <<= 1) { s += __shfl_xor(s, o); ss += __shfl_xor(ss, o); }
    __shared__ float S1[4], S2[4];
    int w = t >> 6;
    if ((t & 63) == 0) { S1[w] = s; S2[w] = ss; }
    __syncthreads();
    s = S1[0] + S1[1] + S1[2] + S1[3];
    ss = S2[0] + S2[1] + S2[2] + S2[3];
    float mean = s * (1.f / Dc);
    float var = ss * (1.f / Dc) - mean * mean;
    float rstd = rsqrtf(var + 1e-5f);
    int c = t * 4;
    float4 g4 = *(const float4*)(gam + c);
    float4 b4 = *(const float4*)(bet + c);
    float y0 = (x0 - mean) * rstd * g4.x + b4.x;
    float y1 = (x1 - mean) * rstd * g4.y + b4.y;
    float y2 = (x2 - mean) * rstd * g4.z + b4.z;
    float y3 = (x3 - mean) * rstd * g4.w + b4.w;
    if (outB) {
        short4v ob;
        ob[0] = f2bf(y0); ob[1] = f2bf(y1); ob[2] = f2bf(y2); ob[3] = f2bf(y3);
        *(short4v*)(outB + base) = ob;
    }
    if (outF) { float4 ov = {y0, y1, y2, y3}; *(float4*)(outF + base) = ov; }
}

// ---------------- LN over 4 bf16 split-K partials + bf16 residual -> f32 out ----------------
__global__ __launch_bounds__(256) void ln_4b(const unsigned short* __restrict__ p,
                                             const unsigned short* __restrict__ res,
                                             const float* __restrict__ gam,
                                             const float* __restrict__ bet,
                                             float* __restrict__ outF) {
    const size_t PS = (size_t)4096 * 1024;
    int row = blockIdx.x, t = threadIdx.x;
    size_t base = (size_t)row * Dc + t * 4;
    float x0, x1, x2, x3;
    {
        short4v rv = *(const short4v*)(res + base);
        x0 = bf2f((unsigned short)rv[0]); x1 = bf2f((unsigned short)rv[1]);
        x2 = bf2f((unsigned short)rv[2]); x3 = bf2f((unsigned short)rv[3]);
    }
#pragma unroll
    for (int j = 0; j < 4; j++) {
        short4v v = *(const short4v*)(p + j * PS + base);
        x0 += bf2f((unsigned short)v[0]); x1 += bf2f((unsigned short)v[1]);
        x2 += bf2f((unsigned short)v[2]); x3 += bf2f((unsigned short)v[3]);
    }
    float s = x0 + x1 + x2 + x3;
    float ss = x0 * x0 + x1 * x1 + x2 * x2 + x3 * x3;
    for (int o = 1; o < 64; o <<= 1) { s += __shfl_xor(s, o); ss += __shfl_xor(ss, o); }
    __shared__ float S1[4], S2[4];
    int w = t >> 6;
    if ((t & 63) == 0) { S1[w] = s; S2[w] = ss; }
    __syncthreads();
    s = S1[0] + S1[1] + S1[2] + S1[3];
    ss = S2[0] + S2[1] + S2[2] + S2[3];
    float mean = s * (1.f / Dc);
    float var = ss * (1.f / Dc) - mean * mean;
    float rstd = rsqrtf(var + 1e-5f);
    int c = t * 4;
    float4 g4 = *(const float4*)(gam + c);
    float4 b4 = *(const float4*)(bet + c);
    float4 ov;
    ov.x = (x0 - mean) * rstd * g4.x + b4.x;
    ov.y = (x1 - mean) * rstd * g4.y + b4.y;
    ov.z = (x2 - mean) * rstd * g4.z + b4.z;
    ov.w = (x3 - mean) * rstd * g4.w + b4.w;
    *(float4*)(outF + base) = ov;
}

// ---------------- launch ----------------
extern "C" void kernel_launch(void* const* d_in, const int* in_sizes, int n_in,
                              void* d_out, int out_size, void* d_ws, size_t ws_size,
                              hipStream_t stream) {
    const float* x   = (const float*)d_in[0];
    const float* enc = (const float*)d_in[1];
    const float* dWq = (const float*)d_in[4];  const float* dbq = (const float*)d_in[5];
    const float* dWk = (const float*)d_in[6];  const float* dbk = (const float*)d_in[7];
    const float* dWv = (const float*)d_in[8];  const float* dbv = (const float*)d_in[9];
    const float* dWo = (const float*)d_in[10]; const float* dbo = (const float*)d_in[11];
    const float* eWq = (const float*)d_in[12]; const float* ebq = (const float*)d_in[13];
    const float* eWk = (const float*)d_in[14]; const float* ebk = (const float*)d_in[15];
    const float* eWv = (const float*)d_in[16]; const float* ebv = (const float*)d_in[17];
    const float* eWo = (const float*)d_in[18]; const float* ebo = (const float*)d_in[19];
    const float* fW1 = (const float*)d_in[20]; const float* fb1 = (const float*)d_in[21];
    const float* fW2 = (const float*)d_in[22]; const float* fb2 = (const float*)d_in[23];
    const float* g1 = (const float*)d_in[24];  const float* be1 = (const float*)d_in[25];
    const float* g2 = (const float*)d_in[26];  const float* be2 = (const float*)d_in[27];
    const float* g3 = (const float*)d_in[28];  const float* be3 = (const float*)d_in[29];

    const float SC = 0.125f * 1.44269504f;

    char* ws = (char*)d_ws;
    size_t off = 0;
    auto alloc = [&](size_t bytes) -> void* {
        void* p = ws + off;
        off += (bytes + 255) & ~(size_t)255;
        return p;
    };
    const size_t A = (size_t)4096 * 1024;
    const size_t MB1 = (size_t)1024 * 1024;
    char* R1 = (char*)alloc(32 * 1024 * 1024);
    unsigned short* qkv = (unsigned short*)R1;                       // stride 3072
    unsigned short* kvx = (unsigned short*)R1;                       // stride 2048
    unsigned short* qx  = (unsigned short*)(R1 + 16 * 1024 * 1024);  // stride 1024
    unsigned short* h1  = (unsigned short*)R1;                       // 4096x4096
    unsigned short* xb   = (unsigned short*)alloc(A * 2);
    unsigned short* encb = (unsigned short*)alloc(A * 2);
    unsigned short* wqkv = (unsigned short*)alloc(3 * MB1 * 2);
    unsigned short* wekv = (unsigned short*)alloc(2 * MB1 * 2);
    unsigned short* weq  = (unsigned short*)alloc(MB1 * 2);
    unsigned short* wdo  = (unsigned short*)alloc(MB1 * 2);
    unsigned short* weo  = (unsigned short*)alloc(MB1 * 2);
    unsigned short* wf1  = (unsigned short*)alloc(4 * MB1 * 2);
    unsigned short* wf2  = (unsigned short*)alloc(4 * MB1 * 2);
    float* bqkv = (float*)alloc(3072 * 4);
    float* bekv = (float*)alloc(2048 * 4);
    float* ebq_s = (float*)alloc(1024 * 4);
    unsigned short* VtB = (unsigned short*)alloc(A * 2);
    unsigned short* ab  = (unsigned short*)alloc(A * 2);
    unsigned short* tmpB = (unsigned short*)alloc(A * 2);
    unsigned short* dB = (unsigned short*)alloc(A * 2);
    unsigned short* fB = (unsigned short*)alloc(A * 2);
    unsigned short* pfb = VtB;
    (void)ws_size; (void)in_sizes; (void)n_in; (void)out_size;

    cast2_f32_bf16<<<dim3(2048, 2), 256, 0, stream>>>(x, enc, xb, encb, (int)(A / 8));

    // unified 16-job weight transpose (8 squares + fW1 as 4 + fW2 as 4)
    TJ16 tj;
    tj.j[0] = {dWq, wqkv,           1024, 1024, SC};
    tj.j[1] = {dWk, wqkv + MB1,     1024, 1024, 1.f};
    tj.j[2] = {dWv, wqkv + 2 * MB1, 1024, 1024, 1.f};
    tj.j[3] = {eWk, wekv,           1024, 1024, 1.f};
    tj.j[4] = {eWv, wekv + MB1,     1024, 1024, 1.f};
    tj.j[5] = {eWq, weq,            1024, 1024, SC};
    tj.j[6] = {dWo, wdo,            1024, 1024, 1.f};
    tj.j[7] = {eWo, weo,            1024, 1024, 1.f};
    for (int jj = 0; jj < 4; jj++) {
        tj.j[8 + jj]  = {fW1 + 1024 * jj, wf1 + (size_t)1024 * jj * 1024, 4096, 1024, 1.f};
        tj.j[12 + jj] = {fW2 + (size_t)1024 * jj * 1024, wf2 + 1024 * jj, 1024, 4096, 1.f};
    }
    transpose_cast16<<<dim3(16, 16, 16), 256, 0, stream>>>(tj);
    prep_bias<<<24, 256, 0, stream>>>(dbq, dbk, dbv, ebk, ebv, ebq, bqkv, bekv, ebq_s, SC);

    P8 z8{};

    // ---- self-attention block ----
    gemm256<0><<<dim3(12, 16), 512, 0, stream>>>(xb, wqkv, bqkv, qkv, 3072, 1024, 1024, 16, z8);
    transpose_v<<<dim3(16, 64), 256, 0, stream>>>(qkv + 2048, 3072, VtB);
    attn6_kernel<1><<<dim3(64, 8), 512, 0, stream>>>(qkv, 3072, qkv + 1024, 3072, VtB, ab);
    gemm64_db<0><<<dim3(8, 64), 256, 0, stream>>>(ab, wdo, dbo, nullptr, tmpB, 4096, 1024, 1024, 1024, 1024);
    ln_bf<<<4096, 256, 0, stream>>>(tmpB, xb, g1, be1, dB, nullptr);

    // ---- cross-attention block ----
    {
        P8 pe{};
        pe.o[0] = kvx;
        pe.o[1] = VtB;
        gemm256<3><<<dim3(8, 16, 2), 512, 0, stream>>>(encb, wekv, bekv, nullptr, 2048, 1024, 1024, 8, pe);
        combine2<<<4096, 256, 0, stream>>>(kvx, VtB, (int)((size_t)4096 * 2048 / 8));
    }
    gemm64_db<0><<<dim3(8, 64), 256, 0, stream>>>(dB, weq, ebq_s, nullptr, qx, 4096, 1024, 1024, 1024, 1024);
    transpose_v<<<dim3(16, 64), 256, 0, stream>>>(kvx + 1024, 2048, VtB);
    attn6_kernel<0><<<dim3(64, 8), 512, 0, stream>>>(qx, 1024, kvx, 2048, VtB, ab);
    gemm64_db<0><<<dim3(8, 64), 256, 0, stream>>>(ab, weo, ebo, nullptr, tmpB, 4096, 1024, 1024, 1024, 1024);
    ln_bf<<<4096, 256, 0, stream>>>(tmpB, dB, g2, be2, fB, nullptr);

    // ---- FFN block ----
    gemm256<2><<<dim3(16, 16), 512, 0, stream>>>(fB, wf1, fb1, h1, 4096, 1024, 1024, 16, z8);
    {
        P8 pf{};
        pf.o[0] = pfb;
        pf.o[1] = pfb + A;
        pf.o[2] = pfb + 2 * A;
        pf.o[3] = pfb + 3 * A;
        gemm256<3><<<dim3(4, 16, 4), 512, 0, stream>>>(h1, wf2, fb2, nullptr, 1024, 4096, 4096, 16, pf);
    }
    ln_4b<<<4096, 256, 0, stream>>>(pfb, fB, g3, be3, (float*)d_out);
}

// Round 17
// 320.117 us; speedup vs baseline: 1.0516x; 1.0036x over previous
//
#include <hip/hip_runtime.h>

static constexpr int Bc = 4, Tc = 1024, Sc = 1024, Dc = 1024, Hc = 16, DHc = 64, FFc = 4096;

typedef __attribute__((ext_vector_type(8))) short short8;
typedef __attribute__((ext_vector_type(4))) short short4v;
typedef __attribute__((ext_vector_type(4))) float f32x4;

struct P8 { unsigned short* o[8]; };

__device__ __forceinline__ unsigned short f2bf(float f) {
    unsigned int u = __float_as_uint(f);
    unsigned int r = u + 0x7fffu + ((u >> 16) & 1u);
    return (unsigned short)(r >> 16);
}
__device__ __forceinline__ float bf2f(unsigned short u) {
    return __uint_as_float(((unsigned int)u) << 16);
}
__device__ __forceinline__ float fexp2(float x) {
    float r; asm("v_exp_f32 %0, %1" : "=v"(r) : "v"(x)); return r;
}
__device__ __forceinline__ unsigned int cvtpk(float a, float b) {
    unsigned int r;
    asm("v_cvt_pk_bf16_f32 %0, %1, %2" : "=v"(r) : "v"(a), "v"(b));
    return r;
}

__device__ __forceinline__ void gload_lds16(const void* g, void* l) {
    __builtin_amdgcn_global_load_lds((const __attribute__((address_space(1))) void*)g,
                                     (__attribute__((address_space(3))) void*)l, 16, 0, 0);
}

// ---------------- cast f32 -> bf16 (two tensors in one launch) ----------------
__global__ __launch_bounds__(256) void cast2_f32_bf16(const float* __restrict__ inA,
                                                      const float* __restrict__ inB,
                                                      unsigned short* __restrict__ outA,
                                                      unsigned short* __restrict__ outB, int n8) {
    int i = blockIdx.x * 256 + threadIdx.x;
    if (i >= n8) return;
    const float* in = blockIdx.y ? inB : inA;
    unsigned short* out = blockIdx.y ? outB : outA;
    const float4* p = (const float4*)in + (size_t)i * 2;
    float4 a = p[0], b = p[1];
    short8 o;
    o[0] = f2bf(a.x); o[1] = f2bf(a.y); o[2] = f2bf(a.z); o[3] = f2bf(a.w);
    o[4] = f2bf(b.x); o[5] = f2bf(b.y); o[6] = f2bf(b.z); o[7] = f2bf(b.w);
    *(short8*)(out + (size_t)i * 8) = o;
}

// ---------------- unified weight transpose+cast: 16 jobs of 1024x1024 views ----------------
struct TJ { const float* s; unsigned short* d; int ss, ds; float scl; };
struct TJ16 { TJ j[16]; };
__global__ __launch_bounds__(256) void transpose_cast16(TJ16 p) {
    __shared__ float t[64][65];
    const TJ jb = p.j[blockIdx.z];
    const int c0 = blockIdx.x * 64, r0 = blockIdx.y * 64;
    const int tid = threadIdx.x;
    const int rr = tid >> 2, cc = (tid & 3) * 16;
    const float* src = jb.s + (size_t)(r0 + rr) * jb.ss + c0 + cc;
#pragma unroll
    for (int i = 0; i < 4; i++) {
        float4 v = *(const float4*)(src + i * 4);
        t[rr][cc + i * 4 + 0] = v.x;
        t[rr][cc + i * 4 + 1] = v.y;
        t[rr][cc + i * 4 + 2] = v.z;
        t[rr][cc + i * 4 + 3] = v.w;
    }
    __syncthreads();
#pragma unroll
    for (int half = 0; half < 2; half++) {
        const int id = half * 256 + tid;
        const int a = id >> 3, b0 = id & 7;
        short8 o;
#pragma unroll
        for (int e = 0; e < 8; e++) o[e] = f2bf(t[b0 * 8 + e][a] * jb.scl);
        *(short8*)(jb.d + (size_t)(c0 + a) * jb.ds + r0 + b0 * 8) = o;
    }
}

// ---------------- all bias prep in one launch (6144 elems) ----------------
__global__ void prep_bias(const float* dbq, const float* dbk, const float* dbv,
                          const float* ebk, const float* ebv, const float* ebq,
                          float* __restrict__ bqkv, float* __restrict__ bekv,
                          float* __restrict__ ebq_s, float SC) {
    int i = blockIdx.x * 256 + threadIdx.x;
    int seg = i >> 10, j = i & 1023;
    switch (seg) {
        case 0: bqkv[j] = dbq[j] * SC; break;
        case 1: bqkv[1024 + j] = dbk[j]; break;
        case 2: bqkv[2048 + j] = dbv[j]; break;
        case 3: bekv[j] = ebk[j]; break;
        case 4: bekv[1024 + j] = ebv[j]; break;
        default: ebq_s[j] = ebq[j] * SC; break;
    }
}

// ---------------- fused eKV combine: K summed in place; V summed + per-head transposed ----
// kv = partial0 (stride 2048, K cols [0,1024), V cols [1024,2048)); p1 = partial1.
// blocks [0,2048): K region; blocks [2048,3072): V transpose-combine -> Vt.
__global__ __launch_bounds__(256) void combineKV(unsigned short* __restrict__ kv,
                                                 const unsigned short* __restrict__ p1,
                                                 unsigned short* __restrict__ Vt) {
    __shared__ unsigned short t[64 * 64];
    const int bx = blockIdx.x;
    const int tid = threadIdx.x;
    if (bx < 2048) {
        const int cid = bx * 256 + tid;
        const int row = cid >> 7, col8 = (cid & 127) * 8;
        const size_t a = (size_t)row * 2048 + col8;
        short8 x = *(short8*)(kv + a);
        short8 y = *(const short8*)(p1 + a);
        short8 o;
#pragma unroll
        for (int j = 0; j < 8; j++)
            o[j] = f2bf(bf2f((unsigned short)x[j]) + bf2f((unsigned short)y[j]));
        *(short8*)(kv + a) = o;
        return;
    }
    const int vb = bx - 2048;
    const int bh = vb & 63, b = bh >> 4, h = bh & 15;
    const int s0 = (vb >> 6) * 64;
    const int r = tid >> 2, ch = tid & 3;
    const size_t off = (size_t)(b * 1024 + s0 + r) * 2048 + 1024 + h * 64 + ch * 16;
    short8 x0 = *(const short8*)(kv + off);
    short8 x1 = *(const short8*)(kv + off + 8);
    short8 y0 = *(const short8*)(p1 + off);
    short8 y1 = *(const short8*)(p1 + off + 8);
    short8 v0, v1;
#pragma unroll
    for (int j = 0; j < 8; j++) {
        v0[j] = f2bf(bf2f((unsigned short)x0[j]) + bf2f((unsigned short)y0[j]));
        v1[j] = f2bf(bf2f((unsigned short)x1[j]) + bf2f((unsigned short)y1[j]));
    }
    int pw_ = (ch ^ r ^ (r >> 4)) & 3;
    *(short8*)(t + r * 64 + pw_ * 16) = v0;
    *(short8*)(t + r * 64 + pw_ * 16 + 8) = v1;
    __syncthreads();
    const int dh = tid >> 2, sc = (tid & 3) * 16;
    short8 o0, o1;
#pragma unroll
    for (int j = 0; j < 8; j++) {
        int c0 = sc + j, c1 = sc + 8 + j;
        o0[j] = t[c0 * 64 + (((dh >> 4) ^ c0 ^ (c0 >> 4)) & 3) * 16 + (dh & 15)];
        o1[j] = t[c1 * 64 + (((dh >> 4) ^ c1 ^ (c1 >> 4)) & 3) * 16 + (dh & 15)];
    }
    unsigned short* dst = Vt + ((size_t)bh * 64 + dh) * 1024 + s0 + sc;
    *(short8*)dst = o0;
    *(short8*)(dst + 8) = o1;
}

// ---- block remap: chunked-XCD + group-major rasterization (bijective, nwg%8==0) ----
struct BlkMap { int m, n, z; };
__device__ __forceinline__ BlkMap remap_block() {
    const int gx = gridDim.x, gy = gridDim.y;
    const int nxy = gx * gy;
    const int nwg = nxy * gridDim.z;
    const int flat = (blockIdx.z * gy + blockIdx.y) * gx + blockIdx.x;
    const int id = (flat & 7) * (nwg >> 3) + (flat >> 3);
    const int pz = id / nxy;
    const int rz = id - pz * nxy;
    const int gwsh = (gx & 7) ? 2 : 3;
    const int gw = 1 << gwsh;
    const int gsz = gw * gy;
    const int grp = rz / gsz;
    const int rem = rz - grp * gsz;
    BlkMap r;
    r.m = rem >> gwsh;
    r.n = (grp << gwsh) + (rem & (gw - 1));
    r.z = pz;
    return r;
}

// ================= GEMM 256x256, BK=64, 8 waves, m201 8-phase counted-vmcnt ============
// EPI: 0 = bf16 out; 2 = relu+bf16 out; 3 = bf16 split-K partial to po.o[z] (bias z==0);
//      4 = QKV mode: cols <2048 row-major to outB; cols >=2048 per-head V^T to po.o[0].
template <int EPI>
__global__ __launch_bounds__(512, 2) void gemm256(const unsigned short* __restrict__ A,
                                                  const unsigned short* __restrict__ Bt,
                                                  const float* __restrict__ bias,
                                                  unsigned short* __restrict__ outB,
                                                  int N, int lda, int ldb, int nk, P8 po) {
    __shared__ unsigned short SM[2][2][2][8192];   // 128 KiB
    const int tid = threadIdx.x;
    const int lane = tid & 63, wid = tid >> 6;
    const int l4 = lane & 15, g = lane >> 4;
    const int wr = wid >> 2, wc = wid & 3;
    BlkMap bm = remap_block();
    const int m0 = bm.m * 256, n0 = bm.n * 256, z = bm.z;
    A += (size_t)z * (nk * 64);
    Bt += (size_t)z * (nk * 64);
    const int sw = l4 & 7;

    const int fl0 = tid, fl1 = 512 + tid;
    const int lr0 = fl0 >> 3, ch0 = (fl0 & 7) ^ (lr0 & 7);
    const int lr1 = fl1 >> 3, ch1 = (fl1 & 7) ^ (lr1 & 7);
    const size_t A64 = (size_t)64 * lda;
    const unsigned short* pA0 = A + (size_t)(m0 + (lr0 >> 6) * 128 + (lr0 & 63)) * lda + ch0 * 8;
    const unsigned short* pA1 = A + (size_t)(m0 + (lr1 >> 6) * 128 + (lr1 & 63)) * lda + ch1 * 8;
    const unsigned short* pB0 = Bt + (size_t)(n0 + (ch0 >> 2) * 128 + lr0) * ldb + (ch0 & 3) * 8;
    const unsigned short* pB1 = Bt + (size_t)(n0 + (ch1 >> 2) * 128 + lr1) * ldb + (ch1 & 3) * 8;

    auto stA = [&](int d, int mh, int kofs) {
        char* base = (char*)&SM[0][d][mh][0];
        gload_lds16(pA0 + (size_t)mh * A64 + kofs, base + fl0 * 16);
        gload_lds16(pA1 + (size_t)mh * A64 + kofs, base + fl1 * 16);
    };
    auto stB = [&](int d, int ks, int kofs) {
        char* base = (char*)&SM[1][d][ks][0];
        gload_lds16(pB0 + ks * 32 + kofs, base + fl0 * 16);
        gload_lds16(pB1 + ks * 32 + kofs, base + fl1 * 16);
    };

    f32x4 acc[8][4] = {};
    short8 aF[4], aH[4], b0[4], b1[4];

    auto ldA = [&](int d, int mh, short8* d0, short8* d1) {
#pragma unroll
        for (int m = 0; m < 4; m++) {
            const char* rp = (const char*)&SM[0][d][mh][0] + (wr * 64 + m * 16 + l4) * 128;
            d0[m] = *(const short8*)(rp + ((g ^ sw) * 16));
            d1[m] = *(const short8*)(rp + (((4 + g) ^ sw) * 16));
        }
    };
    auto ldB = [&](int d, int ks, short8* dst) {
#pragma unroll
        for (int n = 0; n < 4; n++) {
            const char* rp = (const char*)&SM[1][d][ks][0] + ((wc & 1) * 64 + n * 16 + l4) * 128;
            dst[n] = *(const short8*)(rp + ((((wc >> 1) * 4 + g) ^ sw) * 16));
        }
    };

#define MFMA16(aa, bb, base)                                                                  \
    _Pragma("unroll") for (int m_ = 0; m_ < 4; m_++)                                          \
        _Pragma("unroll") for (int n_ = 0; n_ < 4; n_++)                                      \
            acc[(base) + m_][n_] = __builtin_amdgcn_mfma_f32_16x16x32_bf16(                   \
                (aa)[m_], (bb)[n_], acc[(base) + m_][n_], 0, 0, 0);

    stB(0, 0, 0); stA(0, 0, 0); stB(0, 1, 0); stA(0, 1, 0);
    stB(1, 0, 64); stA(1, 0, 64); stB(1, 1, 64);
    asm volatile("s_waitcnt vmcnt(6)" ::: "memory");
    __builtin_amdgcn_s_barrier();

    const int nIter = nk >> 1;
    for (int it = 0; it < nIter; ++it) {
        const int t = 2 * it, u = t + 1;
        const int ku = u * 64;
        const int kv = ((t + 2 < nk) ? t + 2 : t) * 64;
        const int kw = ((u + 2 < nk) ? u + 2 : u) * 64;
        // ---- P0 (t: mh0,ks0) ----
        ldB(0, 0, b0); ldA(0, 0, aF, aH);
        stA(1, 1, ku);
        asm volatile("s_waitcnt lgkmcnt(8)" ::: "memory");
        __builtin_amdgcn_s_barrier();
        asm volatile("s_waitcnt lgkmcnt(0)" ::: "memory");
        __builtin_amdgcn_s_setprio(1); MFMA16(aF, b0, 0); __builtin_amdgcn_s_setprio(0);
        __builtin_amdgcn_s_barrier();
        // ---- P1 (t: mh0,ks1) ----
        ldB(0, 1, b1);
        stB(0, 0, kv);
        __builtin_amdgcn_s_barrier();
        asm volatile("s_waitcnt lgkmcnt(0)" ::: "memory");
        __builtin_amdgcn_s_setprio(1); MFMA16(aH, b1, 0); __builtin_amdgcn_s_setprio(0);
        __builtin_amdgcn_s_barrier();
        // ---- P2 (t: mh1,ks1) ----
        ldA(0, 1, aF, aH);
        stA(0, 0, kv);
        __builtin_amdgcn_s_barrier();
        asm volatile("s_waitcnt lgkmcnt(0)" ::: "memory");
        __builtin_amdgcn_s_setprio(1); MFMA16(aH, b1, 4); __builtin_amdgcn_s_setprio(0);
        __builtin_amdgcn_s_barrier();
        // ---- P3 (t: mh1,ks0) ----
        stB(0, 1, kv);
        __builtin_amdgcn_s_barrier();
        __builtin_amdgcn_s_setprio(1); MFMA16(aF, b0, 4); __builtin_amdgcn_s_setprio(0);
        asm volatile("s_waitcnt vmcnt(6)" ::: "memory");
        __builtin_amdgcn_s_barrier();
        // ---- P4 (u: mh0,ks0) ----
        ldB(1, 0, b0); ldA(1, 0, aF, aH);
        stA(0, 1, kv);
        asm volatile("s_waitcnt lgkmcnt(8)" ::: "memory");
        __builtin_amdgcn_s_barrier();
        asm volatile("s_waitcnt lgkmcnt(0)" ::: "memory");
        __builtin_amdgcn_s_setprio(1); MFMA16(aF, b0, 0); __builtin_amdgcn_s_setprio(0);
        __builtin_amdgcn_s_barrier();
        // ---- P5 (u: mh0,ks1) ----
        ldB(1, 1, b1);
        stB(1, 0, kw);
        __builtin_amdgcn_s_barrier();
        asm volatile("s_waitcnt lgkmcnt(0)" ::: "memory");
        __builtin_amdgcn_s_setprio(1); MFMA16(aH, b1, 0); __builtin_amdgcn_s_setprio(0);
        __builtin_amdgcn_s_barrier();
        // ---- P6 (u: mh1,ks1) ----
        ldA(1, 1, aF, aH);
        stA(1, 0, kw);
        __builtin_amdgcn_s_barrier();
        asm volatile("s_waitcnt lgkmcnt(0)" ::: "memory");
        __builtin_amdgcn_s_setprio(1); MFMA16(aH, b1, 4); __builtin_amdgcn_s_setprio(0);
        __builtin_amdgcn_s_barrier();
        // ---- P7 (u: mh1,ks0) ----
        stB(1, 1, kw);
        __builtin_amdgcn_s_barrier();
        __builtin_amdgcn_s_setprio(1); MFMA16(aF, b0, 4); __builtin_amdgcn_s_setprio(0);
        asm volatile("s_waitcnt vmcnt(6)" ::: "memory");
        __builtin_amdgcn_s_barrier();
    }
    asm volatile("s_waitcnt vmcnt(0)" ::: "memory");
    __syncthreads();

    // ---- coalesced epilogue via LDS staging (half-tile at a time) ----
    unsigned short* eb = (unsigned short*)SM;
    unsigned short* oB = (EPI == 3) ? po.o[z] : outB;
    const int colL = wc * 64 + l4;
#pragma unroll
    for (int h = 0; h < 2; ++h) {
        if (wr == h) {
#pragma unroll
            for (int mm = 0; mm < 8; mm++) {
                const int base_r = (mm < 4 ? mm * 16 : 64 + (mm - 4) * 16) + g * 4;
#pragma unroll
                for (int n = 0; n < 4; n++) {
                    float bv = (EPI == 3 && z != 0) ? 0.f : bias[n0 + colL + n * 16];
#pragma unroll
                    for (int r = 0; r < 4; r++) {
                        float v = acc[mm][n][r] + bv;
                        if (EPI == 2) v = fmaxf(v, 0.f);
                        eb[(base_r + r) * 260 + colL + n * 16] = f2bf(v);
                    }
                }
            }
        }
        __syncthreads();
        const int gr0 = m0 + h * 128;
        if (EPI == 4 && n0 >= 2048) {
            // V segment: write per-head transposed [bh][dh][s] (s-contiguous 16B chunks)
            const int b_ = gr0 >> 10, sb = gr0 & 1023;
#pragma unroll
            for (int j = 0; j < 4; j++) {
                const int id = j * 512 + tid;
                const int col = id & 255, rseg = id >> 8;      // col 0..255, rseg 0..7
                const int rel = n0 - 2048 + col;
                const int hh = rel >> 6, dh = rel & 63;
                short8 v0, v1;
#pragma unroll
                for (int e = 0; e < 8; e++) {
                    v0[e] = eb[(rseg * 16 + e) * 260 + col];
                    v1[e] = eb[(rseg * 16 + 8 + e) * 260 + col];
                }
                unsigned short* dp = po.o[0] +
                    ((size_t)(b_ * 16 + hh) * 64 + dh) * 1024 + sb + rseg * 16;
                *(short8*)dp = v0;
                *(short8*)(dp + 8) = v1;
            }
        } else {
#pragma unroll
            for (int j = 0; j < 8; j++) {
                const int f = j * 8192 + tid * 16;
                const int row = f >> 9;
                const int colb = f & 511;
                short8 v = *(const short8*)((const char*)eb + row * 520 + colb);
                *(short8*)(oB + (size_t)(gr0 + row) * N + n0 + (colb >> 1)) = v;
            }
        }
        if (h == 0) __syncthreads();
    }
#undef MFMA16
}

// ---------------- GEMM 64x128: 3-buffer depth-2, counted vmcnt, XCD-swizzled ----------------
template <int EPI>
__global__ __launch_bounds__(256) void gemm64_db(const unsigned short* __restrict__ A,
                                                 const unsigned short* __restrict__ Bt,
                                                 const float* __restrict__ bias,
                                                 float* __restrict__ outF,
                                                 unsigned short* __restrict__ outB,
                                                 int M, int N, int Kloop, int lda, int ldb) {
    __shared__ unsigned short As[3][64 * 32];
    __shared__ unsigned short Bs[3][128 * 32];
    const int tid = threadIdx.x;
    const int w = tid >> 6, lane = tid & 63, l4 = lane & 15, g = lane >> 4;
    BlkMap bm = remap_block();
    const int m0 = bm.m * 64, n0 = bm.n * 128;
    f32x4 acc[4][2] = {};
    const int r0 = tid >> 2;
    const int kk = ((tid & 3) ^ ((tid >> 3) & 3)) * 8;
    const int sk = (l4 >> 1) & 3;
    const unsigned short* Ar0 = A + (size_t)(m0 + r0) * lda + kk;
    const unsigned short* Br0 = Bt + (size_t)(n0 + r0) * ldb + kk;
    const unsigned short* Br1 = Bt + (size_t)(n0 + 64 + r0) * ldb + kk;
    auto stage = [&](int sb, int k0) {
        gload_lds16(Ar0 + k0, (char*)As[sb] + tid * 16);
        gload_lds16(Br0 + k0, (char*)Bs[sb] + tid * 16);
        gload_lds16(Br1 + k0, (char*)Bs[sb] + 4096 + tid * 16);
    };
    const int nk = Kloop >> 5;
    stage(0, 0);
    stage(1, 32);
    asm volatile("s_waitcnt vmcnt(3)" ::: "memory");
    __builtin_amdgcn_s_barrier();
    asm volatile("" ::: "memory");
    int buf = 0;
    for (int t = 0; t < nk; ++t) {
        if (t + 2 < nk) {
            int b2 = buf + 2; if (b2 >= 3) b2 -= 3;
            stage(b2, (t + 2) * 32);
        }
        short8 a[4], b[2];
#pragma unroll
        for (int m = 0; m < 4; m++)
            a[m] = *(const short8*)(As[buf] + (m * 16 + l4) * 32 + (g ^ sk) * 8);
#pragma unroll
        for (int n = 0; n < 2; n++)
            b[n] = *(const short8*)(Bs[buf] + (w * 32 + n * 16 + l4) * 32 + (g ^ sk) * 8);
#pragma unroll
        for (int m = 0; m < 4; m++)
#pragma unroll
            for (int n = 0; n < 2; n++)
                acc[m][n] = __builtin_amdgcn_mfma_f32_16x16x32_bf16(a[m], b[n], acc[m][n], 0, 0, 0);
        if (t + 1 < nk) {
            if (t + 2 < nk) asm volatile("s_waitcnt vmcnt(3)" ::: "memory");
            else            asm volatile("s_waitcnt vmcnt(0)" ::: "memory");
            __builtin_amdgcn_s_barrier();
            asm volatile("" ::: "memory");
        }
        buf = (buf + 1 == 3) ? 0 : buf + 1;
    }
    const int rowB = m0 + g * 4;
    const int colB = n0 + w * 32 + l4;
#pragma unroll
    for (int n = 0; n < 2; n++) {
        float bv = bias[colB + n * 16];
#pragma unroll
        for (int m = 0; m < 4; m++) {
#pragma unroll
            for (int r = 0; r < 4; r++) {
                float v = acc[m][n][r] + bv;
                if (EPI == 2) v = fmaxf(v, 0.f);
                size_t idx = (size_t)(rowB + m * 16 + r) * N + colB + n * 16;
                if (EPI == 1) outF[idx] = v;
                else outB[idx] = f2bf(v);
            }
        }
    }
}

// ---------------- flash attention v6: 8 waves / 128 q-rows per block ----------------
template <int CAUSAL>
__global__ __launch_bounds__(512) void attn6_kernel(const unsigned short* __restrict__ Q, int ldq,
                                                    const unsigned short* __restrict__ Kg, int ldk,
                                                    const unsigned short* __restrict__ Vt,
                                                    unsigned short* __restrict__ O) {
    __shared__ unsigned short Kl[2 * 64 * 64];
    __shared__ unsigned short Vl[2 * 64 * 64];
    __shared__ unsigned short Pl[8][16 * 72];
    const int bh = blockIdx.x;
    const int qb = CAUSAL ? (gridDim.y - 1 - blockIdx.y) : blockIdx.y;
    const int b = bh >> 4, h = bh & 15;
    const int tid = threadIdx.x, w = tid >> 6, lane = tid & 63;
    const int l4 = lane & 15, g = lane >> 4;
    const int q0 = qb * 128 + w * 16;
    const unsigned short* Qp = Q + (size_t)(b * Tc + q0 + l4) * ldq + h * DHc + g * 8;
    short8 qf0 = *(const short8*)Qp;
    short8 qf1 = *(const short8*)(Qp + 32);
    const unsigned short* Kbase = Kg + (size_t)(b * 1024) * ldk + h * DHc;
    const unsigned short* Vbase = Vt + (size_t)bh * DHc * 1024;
    f32x4 o[4] = {};
    float mrun = -1e30f, lrun = 0.f;
    const int nT = CAUSAL ? 2 * qb + 2 : 16;
    unsigned short* pw = &Pl[w][l4 * 72];
    const int qi = q0 + l4;

    short8 ones;
#pragma unroll
    for (int j = 0; j < 8; j++) ones[j] = (short)0x3F80;

    const int sr = tid >> 3;
    const int sc_ = (tid & 7) ^ (sr & 7);

    auto stage = [&](int s0, int buf) {
        char* kd = (char*)Kl + buf * 8192;
        char* vd = (char*)Vl + buf * 8192;
        gload_lds16(Kbase + (size_t)(s0 + sr) * ldk + sc_ * 8, kd + tid * 16);
        gload_lds16(Vbase + (size_t)sr * 1024 + s0 + sc_ * 8, vd + tid * 16);
    };

    stage(0, 0);
    __syncthreads();
    int buf = 0;
    const int sw = l4 & 7;

    for (int t = 0; t < nT; ++t) {
        const int s0 = t * 64;
        if (t + 1 < nT) stage(s0 + 64, buf ^ 1);
        if (!CAUSAL || s0 <= q0 + 15) {
            const unsigned short* Kb_ = Kl + buf * 4096;
            const unsigned short* Vb_ = Vl + buf * 4096;
            f32x4 st[4];
            f32x4 z = {0.f, 0.f, 0.f, 0.f};
            __builtin_amdgcn_s_setprio(1);
#pragma unroll
            for (int c = 0; c < 4; c++) {
                const unsigned short* kr = Kb_ + (c * 16 + l4) * 64;
                short8 ka0 = *(const short8*)(kr + ((g ^ sw) * 8));
                short8 ka1 = *(const short8*)(kr + (((g + 4) ^ sw) * 8));
                st[c] = __builtin_amdgcn_mfma_f32_16x16x32_bf16(ka0, qf0, z, 0, 0, 0);
                st[c] = __builtin_amdgcn_mfma_f32_16x16x32_bf16(ka1, qf1, st[c], 0, 0, 0);
            }
            __builtin_amdgcn_s_setprio(0);
            float p[16];
            const bool domask = CAUSAL && (s0 + 63 > q0);
#pragma unroll
            for (int c = 0; c < 4; c++)
#pragma unroll
                for (int r = 0; r < 4; r++) {
                    float v = st[c][r];
                    if (domask && (s0 + c * 16 + g * 4 + r) > qi) v = -1e9f;
                    p[c * 4 + r] = v;
                }
            float m1 = fmaxf(fmaxf(p[0], p[1]), p[2]);
            float m2 = fmaxf(fmaxf(p[3], p[4]), p[5]);
            float m3 = fmaxf(fmaxf(p[6], p[7]), p[8]);
            float m4 = fmaxf(fmaxf(p[9], p[10]), p[11]);
            float m5 = fmaxf(fmaxf(p[12], p[13]), p[14]);
            float tmax = fmaxf(fmaxf(fmaxf(m1, m2), fmaxf(m3, m4)), fmaxf(m5, p[15]));
            tmax = fmaxf(tmax, __shfl_xor(tmax, 16));
            tmax = fmaxf(tmax, __shfl_xor(tmax, 32));
            if (!__all(tmax <= mrun + 11.5f)) {
                float mnew = fmaxf(mrun, tmax);
                float al = fexp2(mrun - mnew);
                lrun *= al;
#pragma unroll
                for (int d = 0; d < 4; d++) o[d] *= al;
                mrun = mnew;
            }
#pragma unroll
            for (int i = 0; i < 16; i++) p[i] = fexp2(p[i] - mrun);
#pragma unroll
            for (int c = 0; c < 4; c++) {
                uint2 u;
                u.x = cvtpk(p[c * 4 + 0], p[c * 4 + 1]);
                u.y = cvtpk(p[c * 4 + 2], p[c * 4 + 3]);
                *(uint2*)(pw + c * 16 + g * 4) = u;
            }
            short8 pb_lo = *(const short8*)(pw + g * 8);
            short8 pb_hi = *(const short8*)(pw + 32 + g * 8);
            __builtin_amdgcn_s_setprio(1);
            f32x4 s4 = __builtin_amdgcn_mfma_f32_16x16x32_bf16(ones, pb_lo, z, 0, 0, 0);
            s4 = __builtin_amdgcn_mfma_f32_16x16x32_bf16(ones, pb_hi, s4, 0, 0, 0);
#pragma unroll
            for (int d = 0; d < 4; d++) {
                const unsigned short* vr = Vb_ + (d * 16 + l4) * 64;
                short8 va0 = *(const short8*)(vr + ((g ^ sw) * 8));
                short8 va1 = *(const short8*)(vr + (((g + 4) ^ sw) * 8));
                o[d] = __builtin_amdgcn_mfma_f32_16x16x32_bf16(va0, pb_lo, o[d], 0, 0, 0);
                o[d] = __builtin_amdgcn_mfma_f32_16x16x32_bf16(va1, pb_hi, o[d], 0, 0, 0);
            }
            __builtin_amdgcn_s_setprio(0);
            lrun += s4[0];
        }
        __syncthreads();
        buf ^= 1;
    }
    float inv = 1.f / lrun;
    unsigned short* Ob = O + (size_t)(b * Tc + q0 + l4) * Dc + h * DHc;
#pragma unroll
    for (int d = 0; d < 4; d++) {
#pragma unroll
        for (int r = 0; r < 4; r++) Ob[d * 16 + g * 4 + r] = f2bf(o[d][r] * inv);
    }
}

// ---------------- fused residual-add + LayerNorm (bf16 a + bf16 res) ----------------
__global__ __launch_bounds__(256) void ln_bf(const unsigned short* __restrict__ a,
                                             const unsigned short* __restrict__ res,
                                             const float* __restrict__ gam,
                                             const float* __restrict__ bet,
                                             unsigned short* __restrict__ outB,
                                             float* __restrict__ outF) {
    int row = blockIdx.x, t = threadIdx.x;
    size_t base = (size_t)row * Dc + t * 4;
    short4v av = *(const short4v*)(a + base);
    short4v rv = *(const short4v*)(res + base);
    float x0 = bf2f((unsigned short)av[0]) + bf2f((unsigned short)rv[0]);
    float x1 = bf2f((unsigned short)av[1]) + bf2f((unsigned short)rv[1]);
    float x2 = bf2f((unsigned short)av[2]) + bf2f((unsigned short)rv[2]);
    float x3 = bf2f((unsigned short)av[3]) + bf2f((unsigned short)rv[3]);
    float s = x0 + x1 + x2 + x3;
    float ss = x0 * x0 + x1 * x1 + x2 * x2 + x3 * x3;
    for (int o = 1; o < 64; o <<= 1) { s += __shfl_xor(s, o); ss += __shfl_xor(ss, o); }
    __shared__ float S1[4], S2[4];
    int w = t >> 6;
    if ((t & 63) == 0) { S1[w] = s; S2[w] = ss; }
    __syncthreads();
    s = S1[0] + S1[1] + S1[2] + S1[3];
    ss = S2[0] + S2[1] + S2[2] + S2[3];
    float mean = s * (1.f / Dc);
    float var = ss * (1.f / Dc) - mean * mean;
    float rstd = rsqrtf(var + 1e-5f);
    int c = t * 4;
    float4 g4 = *(const float4*)(gam + c);
    float4 b4 = *(const float4*)(bet + c);
    float y0 = (x0 - mean) * rstd * g4.x + b4.x;
    float y1 = (x1 - mean) * rstd * g4.y + b4.y;
    float y2 = (x2 - mean) * rstd * g4.z + b4.z;
    float y3 = (x3 - mean) * rstd * g4.w + b4.w;
    if (outB) {
        short4v ob;
        ob[0] = f2bf(y0); ob[1] = f2bf(y1); ob[2] = f2bf(y2); ob[3] = f2bf(y3);
        *(short4v*)(outB + base) = ob;
    }
    if (outF) { float4 ov = {y0, y1, y2, y3}; *(float4*)(outF + base) = ov; }
}

// ---------------- LN over 4 bf16 split-K partials + bf16 residual -> f32 out ----------------
__global__ __launch_bounds__(256) void ln_4b(const unsigned short* __restrict__ p,
                                             const unsigned short* __restrict__ res,
                                             const float* __restrict__ gam,
                                             const float* __restrict__ bet,
                                             float* __restrict__ outF) {
    const size_t PS = (size_t)4096 * 1024;
    int row = blockIdx.x, t = threadIdx.x;
    size_t base = (size_t)row * Dc + t * 4;
    float x0, x1, x2, x3;
    {
        short4v rv = *(const short4v*)(res + base);
        x0 = bf2f((unsigned short)rv[0]); x1 = bf2f((unsigned short)rv[1]);
        x2 = bf2f((unsigned short)rv[2]); x3 = bf2f((unsigned short)rv[3]);
    }
#pragma unroll
    for (int j = 0; j < 4; j++) {
        short4v v = *(const short4v*)(p + j * PS + base);
        x0 += bf2f((unsigned short)v[0]); x1 += bf2f((unsigned short)v[1]);
        x2 += bf2f((unsigned short)v[2]); x3 += bf2f((unsigned short)v[3]);
    }
    float s = x0 + x1 + x2 + x3;
    float ss = x0 * x0 + x1 * x1 + x2 * x2 + x3 * x3;
    for (int o = 1; o < 64; o <<= 1) { s += __shfl_xor(s, o); ss += __shfl_xor(ss, o); }
    __shared__ float S1[4], S2[4];
    int w = t >> 6;
    if ((t & 63) == 0) { S1[w] = s; S2[w] = ss; }
    __syncthreads();
    s = S1[0] + S1[1] + S1[2] + S1[3];
    ss = S2[0] + S2[1] + S2[2] + S2[3];
    float mean = s * (1.f / Dc);
    float var = ss * (1.f / Dc) - mean * mean;
    float rstd = rsqrtf(var + 1e-5f);
    int c = t * 4;
    float4 g4 = *(const float4*)(gam + c);
    float4 b4 = *(const float4*)(bet + c);
    float4 ov;
    ov.x = (x0 - mean) * rstd * g4.x + b4.x;
    ov.y = (x1 - mean) * rstd * g4.y + b4.y;
    ov.z = (x2 - mean) * rstd * g4.z + b4.z;
    ov.w = (x3 - mean) * rstd * g4.w + b4.w;
    *(float4*)(outF + base) = ov;
}

// ---------------- launch ----------------
extern "C" void kernel_launch(void* const* d_in, const int* in_sizes, int n_in,
                              void* d_out, int out_size, void* d_ws, size_t ws_size,
                              hipStream_t stream) {
    const float* x   = (const float*)d_in[0];
    const float* enc = (const float*)d_in[1];
    const float* dWq = (const float*)d_in[4];  const float* dbq = (const float*)d_in[5];
    const float* dWk = (const float*)d_in[6];  const float* dbk = (const float*)d_in[7];
    const float* dWv = (const float*)d_in[8];  const float* dbv = (const float*)d_in[9];
    const float* dWo = (const float*)d_in[10]; const float* dbo = (const float*)d_in[11];
    const float* eWq = (const float*)d_in[12]; const float* ebq = (const float*)d_in[13];
    const float* eWk = (const float*)d_in[14]; const float* ebk = (const float*)d_in[15];
    const float* eWv = (const float*)d_in[16]; const float* ebv = (const float*)d_in[17];
    const float* eWo = (const float*)d_in[18]; const float* ebo = (const float*)d_in[19];
    const float* fW1 = (const float*)d_in[20]; const float* fb1 = (const float*)d_in[21];
    const float* fW2 = (const float*)d_in[22]; const float* fb2 = (const float*)d_in[23];
    const float* g1 = (const float*)d_in[24];  const float* be1 = (const float*)d_in[25];
    const float* g2 = (const float*)d_in[26];  const float* be2 = (const float*)d_in[27];
    const float* g3 = (const float*)d_in[28];  const float* be3 = (const float*)d_in[29];

    const float SC = 0.125f * 1.44269504f;

    char* ws = (char*)d_ws;
    size_t off = 0;
    auto alloc = [&](size_t bytes) -> void* {
        void* p = ws + off;
        off += (bytes + 255) & ~(size_t)255;
        return p;
    };
    const size_t A = (size_t)4096 * 1024;
    const size_t MB1 = (size_t)1024 * 1024;
    char* R1 = (char*)alloc(32 * 1024 * 1024);
    unsigned short* qkv = (unsigned short*)R1;                       // stride 3072 (Q,K; V fused out)
    unsigned short* kvx = (unsigned short*)R1;                       // stride 2048 (eKV partial0)
    unsigned short* qx  = (unsigned short*)(R1 + 16 * 1024 * 1024);  // stride 1024
    unsigned short* h1  = (unsigned short*)R1;                       // 4096x4096
    unsigned short* xb   = (unsigned short*)alloc(A * 2);
    unsigned short* encb = (unsigned short*)alloc(A * 2);
    unsigned short* wqkv = (unsigned short*)alloc(3 * MB1 * 2);
    unsigned short* wekv = (unsigned short*)alloc(2 * MB1 * 2);
    unsigned short* weq  = (unsigned short*)alloc(MB1 * 2);
    unsigned short* wdo  = (unsigned short*)alloc(MB1 * 2);
    unsigned short* weo  = (unsigned short*)alloc(MB1 * 2);
    unsigned short* wf1  = (unsigned short*)alloc(4 * MB1 * 2);
    unsigned short* wf2  = (unsigned short*)alloc(4 * MB1 * 2);
    float* bqkv = (float*)alloc(3072 * 4);
    float* bekv = (float*)alloc(2048 * 4);
    float* ebq_s = (float*)alloc(1024 * 4);
    unsigned short* VtB = (unsigned short*)alloc(A * 2);
    unsigned short* ab  = (unsigned short*)alloc(A * 2);
    unsigned short* tmpB = (unsigned short*)alloc(A * 2);
    unsigned short* dB = (unsigned short*)alloc(A * 2);
    unsigned short* fB = (unsigned short*)alloc(A * 2);
    unsigned short* pfb = VtB;
    (void)ws_size; (void)in_sizes; (void)n_in; (void)out_size;

    cast2_f32_bf16<<<dim3(2048, 2), 256, 0, stream>>>(x, enc, xb, encb, (int)(A / 8));

    TJ16 tj;
    tj.j[0] = {dWq, wqkv,           1024, 1024, SC};
    tj.j[1] = {dWk, wqkv + MB1,     1024, 1024, 1.f};
    tj.j[2] = {dWv, wqkv + 2 * MB1, 1024, 1024, 1.f};
    tj.j[3] = {eWk, wekv,           1024, 1024, 1.f};
    tj.j[4] = {eWv, wekv + MB1,     1024, 1024, 1.f};
    tj.j[5] = {eWq, weq,            1024, 1024, SC};
    tj.j[6] = {dWo, wdo,            1024, 1024, 1.f};
    tj.j[7] = {eWo, weo,            1024, 1024, 1.f};
    for (int jj = 0; jj < 4; jj++) {
        tj.j[8 + jj]  = {fW1 + 1024 * jj, wf1 + (size_t)1024 * jj * 1024, 4096, 1024, 1.f};
        tj.j[12 + jj] = {fW2 + (size_t)1024 * jj * 1024, wf2 + 1024 * jj, 1024, 4096, 1.f};
    }
    transpose_cast16<<<dim3(16, 16, 16), 256, 0, stream>>>(tj);
    prep_bias<<<24, 256, 0, stream>>>(dbq, dbk, dbv, ebk, ebv, ebq, bqkv, bekv, ebq_s, SC);

    P8 z8{};

    // ---- self-attention block (QKV GEMM writes V^T directly into VtB) ----
    {
        P8 pq{};
        pq.o[0] = VtB;
        gemm256<4><<<dim3(12, 16), 512, 0, stream>>>(xb, wqkv, bqkv, qkv, 3072, 1024, 1024, 16, pq);
    }
    attn6_kernel<1><<<dim3(64, 8), 512, 0, stream>>>(qkv, 3072, qkv + 1024, 3072, VtB, ab);
    gemm64_db<0><<<dim3(8, 64), 256, 0, stream>>>(ab, wdo, dbo, nullptr, tmpB, 4096, 1024, 1024, 1024, 1024);
    ln_bf<<<4096, 256, 0, stream>>>(tmpB, xb, g1, be1, dB, nullptr);

    // ---- cross-attention block ----
    {
        P8 pe{};
        pe.o[0] = kvx;
        pe.o[1] = VtB;
        gemm256<3><<<dim3(8, 16, 2), 512, 0, stream>>>(encb, wekv, bekv, nullptr, 2048, 1024, 1024, 8, pe);
        // fused: K-sum in place (kvx) + V-sum transposed into tmpB
        combineKV<<<3072, 256, 0, stream>>>(kvx, VtB, tmpB);
    }
    gemm64_db<0><<<dim3(8, 64), 256, 0, stream>>>(dB, weq, ebq_s, nullptr, qx, 4096, 1024, 1024, 1024, 1024);
    attn6_kernel<0><<<dim3(64, 8), 512, 0, stream>>>(qx, 1024, kvx, 2048, tmpB, ab);
    gemm64_db<0><<<dim3(8, 64), 256, 0, stream>>>(ab, weo, ebo, nullptr, tmpB, 4096, 1024, 1024, 1024, 1024);
    ln_bf<<<4096, 256, 0, stream>>>(tmpB, dB, g2, be2, fB, nullptr);

    // ---- FFN block ----
    gemm256<2><<<dim3(16, 16), 512, 0, stream>>>(fB, wf1, fb1, h1, 4096, 1024, 1024, 16, z8);
    {
        P8 pf{};
        pf.o[0] = pfb;
        pf.o[1] = pfb + A;
        pf.o[2] = pfb + 2 * A;
        pf.o[3] = pfb + 3 * A;
        gemm256<3><<<dim3(4, 16, 4), 512, 0, stream>>>(h1, wf2, fb2, nullptr, 1024, 4096, 4096, 16, pf);
    }
    ln_4b<<<4096, 256, 0, stream>>>(pfb, fB, g3, be3, (float*)d_out);
}

// Round 18
// 314.181 us; speedup vs baseline: 1.0715x; 1.0189x over previous
//
#include <hip/hip_runtime.h>

static constexpr int Bc = 4, Tc = 1024, Sc = 1024, Dc = 1024, Hc = 16, DHc = 64, FFc = 4096;

typedef __attribute__((ext_vector_type(8))) short short8;
typedef __attribute__((ext_vector_type(4))) short short4v;
typedef __attribute__((ext_vector_type(4))) float f32x4;

struct P8 { unsigned short* o[8]; };

__device__ __forceinline__ unsigned short f2bf(float f) {
    unsigned int u = __float_as_uint(f);
    unsigned int r = u + 0x7fffu + ((u >> 16) & 1u);
    return (unsigned short)(r >> 16);
}
__device__ __forceinline__ float bf2f(unsigned short u) {
    return __uint_as_float(((unsigned int)u) << 16);
}
__device__ __forceinline__ float fexp2(float x) {
    float r; asm("v_exp_f32 %0, %1" : "=v"(r) : "v"(x)); return r;
}
__device__ __forceinline__ unsigned int cvtpk(float a, float b) {
    unsigned int r;
    asm("v_cvt_pk_bf16_f32 %0, %1, %2" : "=v"(r) : "v"(a), "v"(b));
    return r;
}

__device__ __forceinline__ void gload_lds16(const void* g, void* l) {
    __builtin_amdgcn_global_load_lds((const __attribute__((address_space(1))) void*)g,
                                     (__attribute__((address_space(3))) void*)l, 16, 0, 0);
}

// ---------------- cast f32 -> bf16 (two tensors in one launch) ----------------
__global__ __launch_bounds__(256) void cast2_f32_bf16(const float* __restrict__ inA,
                                                      const float* __restrict__ inB,
                                                      unsigned short* __restrict__ outA,
                                                      unsigned short* __restrict__ outB, int n8) {
    int i = blockIdx.x * 256 + threadIdx.x;
    if (i >= n8) return;
    const float* in = blockIdx.y ? inB : inA;
    unsigned short* out = blockIdx.y ? outB : outA;
    const float4* p = (const float4*)in + (size_t)i * 2;
    float4 a = p[0], b = p[1];
    short8 o;
    o[0] = f2bf(a.x); o[1] = f2bf(a.y); o[2] = f2bf(a.z); o[3] = f2bf(a.w);
    o[4] = f2bf(b.x); o[5] = f2bf(b.y); o[6] = f2bf(b.z); o[7] = f2bf(b.w);
    *(short8*)(out + (size_t)i * 8) = o;
}

// ---------------- unified weight transpose+cast: 16 jobs of 1024x1024 views ----------------
struct TJ { const float* s; unsigned short* d; int ss, ds; float scl; };
struct TJ16 { TJ j[16]; };
__global__ __launch_bounds__(256) void transpose_cast16(TJ16 p) {
    __shared__ float t[64][65];
    const TJ jb = p.j[blockIdx.z];
    const int c0 = blockIdx.x * 64, r0 = blockIdx.y * 64;
    const int tid = threadIdx.x;
    const int rr = tid >> 2, cc = (tid & 3) * 16;
    const float* src = jb.s + (size_t)(r0 + rr) * jb.ss + c0 + cc;
#pragma unroll
    for (int i = 0; i < 4; i++) {
        float4 v = *(const float4*)(src + i * 4);
        t[rr][cc + i * 4 + 0] = v.x;
        t[rr][cc + i * 4 + 1] = v.y;
        t[rr][cc + i * 4 + 2] = v.z;
        t[rr][cc + i * 4 + 3] = v.w;
    }
    __syncthreads();
#pragma unroll
    for (int half = 0; half < 2; half++) {
        const int id = half * 256 + tid;
        const int a = id >> 3, b0 = id & 7;
        short8 o;
#pragma unroll
        for (int e = 0; e < 8; e++) o[e] = f2bf(t[b0 * 8 + e][a] * jb.scl);
        *(short8*)(jb.d + (size_t)(c0 + a) * jb.ds + r0 + b0 * 8) = o;
    }
}

// ---------------- all bias prep in one launch (6144 elems) ----------------
__global__ void prep_bias(const float* dbq, const float* dbk, const float* dbv,
                          const float* ebk, const float* ebv, const float* ebq,
                          float* __restrict__ bqkv, float* __restrict__ bekv,
                          float* __restrict__ ebq_s, float SC) {
    int i = blockIdx.x * 256 + threadIdx.x;
    int seg = i >> 10, j = i & 1023;
    switch (seg) {
        case 0: bqkv[j] = dbq[j] * SC; break;
        case 1: bqkv[1024 + j] = dbk[j]; break;
        case 2: bqkv[2048 + j] = dbv[j]; break;
        case 3: bekv[j] = ebk[j]; break;
        case 4: bekv[1024 + j] = ebv[j]; break;
        default: ebq_s[j] = ebq[j] * SC; break;
    }
}

// ---- block remap: chunked-XCD + group-major rasterization (bijective, nwg%8==0) ----
struct BlkMap { int m, n, z; };
__device__ __forceinline__ BlkMap remap_block() {
    const int gx = gridDim.x, gy = gridDim.y;
    const int nxy = gx * gy;
    const int nwg = nxy * gridDim.z;
    const int flat = (blockIdx.z * gy + blockIdx.y) * gx + blockIdx.x;
    const int id = (flat & 7) * (nwg >> 3) + (flat >> 3);
    const int pz = id / nxy;
    const int rz = id - pz * nxy;
    const int gwsh = (gx & 7) ? 2 : 3;
    const int gw = 1 << gwsh;
    const int gsz = gw * gy;
    const int grp = rz / gsz;
    const int rem = rz - grp * gsz;
    BlkMap r;
    r.m = rem >> gwsh;
    r.n = (grp << gwsh) + (rem & (gw - 1));
    r.z = pz;
    return r;
}

// shared inner K-loop body (8-phase m201 schedule) as a macro over lambdas
#define G256_BODY()                                                                            \
    stB(0, 0, 0); stA(0, 0, 0); stB(0, 1, 0); stA(0, 1, 0);                                    \
    stB(1, 0, 64); stA(1, 0, 64); stB(1, 1, 64);                                               \
    asm volatile("s_waitcnt vmcnt(6)" ::: "memory");                                           \
    __builtin_amdgcn_s_barrier();                                                              \
    const int nIter = nk >> 1;                                                                 \
    for (int it = 0; it < nIter; ++it) {                                                       \
        const int t_ = 2 * it, u_ = t_ + 1;                                                    \
        const int ku = u_ * 64;                                                                \
        const int kv = ((t_ + 2 < nk) ? t_ + 2 : t_) * 64;                                     \
        const int kw = ((u_ + 2 < nk) ? u_ + 2 : u_) * 64;                                     \
        ldB(0, 0, b0); ldA(0, 0, aF, aH);                                                      \
        stA(1, 1, ku);                                                                         \
        asm volatile("s_waitcnt lgkmcnt(8)" ::: "memory");                                     \
        __builtin_amdgcn_s_barrier();                                                          \
        asm volatile("s_waitcnt lgkmcnt(0)" ::: "memory");                                     \
        __builtin_amdgcn_s_setprio(1); MFMA16(aF, b0, 0); __builtin_amdgcn_s_setprio(0);       \
        __builtin_amdgcn_s_barrier();                                                          \
        ldB(0, 1, b1);                                                                         \
        stB(0, 0, kv);                                                                         \
        __builtin_amdgcn_s_barrier();                                                          \
        asm volatile("s_waitcnt lgkmcnt(0)" ::: "memory");                                     \
        __builtin_amdgcn_s_setprio(1); MFMA16(aH, b1, 0); __builtin_amdgcn_s_setprio(0);       \
        __builtin_amdgcn_s_barrier();                                                          \
        ldA(0, 1, aF, aH);                                                                     \
        stA(0, 0, kv);                                                                         \
        __builtin_amdgcn_s_barrier();                                                          \
        asm volatile("s_waitcnt lgkmcnt(0)" ::: "memory");                                     \
        __builtin_amdgcn_s_setprio(1); MFMA16(aH, b1, 4); __builtin_amdgcn_s_setprio(0);       \
        __builtin_amdgcn_s_barrier();                                                          \
        stB(0, 1, kv);                                                                         \
        __builtin_amdgcn_s_barrier();                                                          \
        __builtin_amdgcn_s_setprio(1); MFMA16(aF, b0, 4); __builtin_amdgcn_s_setprio(0);       \
        asm volatile("s_waitcnt vmcnt(6)" ::: "memory");                                       \
        __builtin_amdgcn_s_barrier();                                                          \
        ldB(1, 0, b0); ldA(1, 0, aF, aH);                                                      \
        stA(0, 1, kv);                                                                         \
        asm volatile("s_waitcnt lgkmcnt(8)" ::: "memory");                                     \
        __builtin_amdgcn_s_barrier();                                                          \
        asm volatile("s_waitcnt lgkmcnt(0)" ::: "memory");                                     \
        __builtin_amdgcn_s_setprio(1); MFMA16(aF, b0, 0); __builtin_amdgcn_s_setprio(0);       \
        __builtin_amdgcn_s_barrier();                                                          \
        ldB(1, 1, b1);                                                                         \
        stB(1, 0, kw);                                                                         \
        __builtin_amdgcn_s_barrier();                                                          \
        asm volatile("s_waitcnt lgkmcnt(0)" ::: "memory");                                     \
        __builtin_amdgcn_s_setprio(1); MFMA16(aH, b1, 0); __builtin_amdgcn_s_setprio(0);       \
        __builtin_amdgcn_s_barrier();                                                          \
        ldA(1, 1, aF, aH);                                                                     \
        stA(1, 0, kw);                                                                         \
        __builtin_amdgcn_s_barrier();                                                          \
        asm volatile("s_waitcnt lgkmcnt(0)" ::: "memory");                                     \
        __builtin_amdgcn_s_setprio(1); MFMA16(aH, b1, 4); __builtin_amdgcn_s_setprio(0);       \
        __builtin_amdgcn_s_barrier();                                                          \
        stB(1, 1, kw);                                                                         \
        __builtin_amdgcn_s_barrier();                                                          \
        __builtin_amdgcn_s_setprio(1); MFMA16(aF, b0, 4); __builtin_amdgcn_s_setprio(0);       \
        asm volatile("s_waitcnt vmcnt(6)" ::: "memory");                                       \
        __builtin_amdgcn_s_barrier();                                                          \
    }                                                                                          \
    asm volatile("s_waitcnt vmcnt(0)" ::: "memory");                                           \
    __syncthreads();

#define MFMA16(aa, bb, base)                                                                   \
    _Pragma("unroll") for (int m_ = 0; m_ < 4; m_++)                                           \
        _Pragma("unroll") for (int n_ = 0; n_ < 4; n_++)                                       \
            acc[(base) + m_][n_] = __builtin_amdgcn_mfma_f32_16x16x32_bf16(                    \
                (aa)[m_], (bb)[n_], acc[(base) + m_][n_], 0, 0, 0);

// ================= GEMM 256x256 template (FFN): EPI 2 = relu+bf16; 3 = split-K partial ====
template <int EPI>
__global__ __launch_bounds__(512, 2) void gemm256(const unsigned short* __restrict__ A,
                                                  const unsigned short* __restrict__ Bt,
                                                  const float* __restrict__ bias,
                                                  unsigned short* __restrict__ outB,
                                                  int N, int lda, int ldb, int nk, P8 po) {
    __shared__ unsigned short SM[2][2][2][8192];
    const int tid = threadIdx.x;
    const int lane = tid & 63, wid = tid >> 6;
    const int l4 = lane & 15, g = lane >> 4;
    const int wr = wid >> 2, wc = wid & 3;
    BlkMap bm = remap_block();
    const int m0 = bm.m * 256, n0 = bm.n * 256, z = bm.z;
    A += (size_t)z * (nk * 64);
    Bt += (size_t)z * (nk * 64);
    const int sw = l4 & 7;

    const int fl0 = tid, fl1 = 512 + tid;
    const int lr0 = fl0 >> 3, ch0 = (fl0 & 7) ^ (lr0 & 7);
    const int lr1 = fl1 >> 3, ch1 = (fl1 & 7) ^ (lr1 & 7);
    const size_t A64 = (size_t)64 * lda;
    const unsigned short* pA0 = A + (size_t)(m0 + (lr0 >> 6) * 128 + (lr0 & 63)) * lda + ch0 * 8;
    const unsigned short* pA1 = A + (size_t)(m0 + (lr1 >> 6) * 128 + (lr1 & 63)) * lda + ch1 * 8;
    const unsigned short* pB0 = Bt + (size_t)(n0 + (ch0 >> 2) * 128 + lr0) * ldb + (ch0 & 3) * 8;
    const unsigned short* pB1 = Bt + (size_t)(n0 + (ch1 >> 2) * 128 + lr1) * ldb + (ch1 & 3) * 8;

    auto stA = [&](int d, int mh, int kofs) {
        char* base = (char*)&SM[0][d][mh][0];
        gload_lds16(pA0 + (size_t)mh * A64 + kofs, base + fl0 * 16);
        gload_lds16(pA1 + (size_t)mh * A64 + kofs, base + fl1 * 16);
    };
    auto stB = [&](int d, int ks, int kofs) {
        char* base = (char*)&SM[1][d][ks][0];
        gload_lds16(pB0 + ks * 32 + kofs, base + fl0 * 16);
        gload_lds16(pB1 + ks * 32 + kofs, base + fl1 * 16);
    };

    f32x4 acc[8][4] = {};
    short8 aF[4], aH[4], b0[4], b1[4];

    auto ldA = [&](int d, int mh, short8* d0, short8* d1) {
#pragma unroll
        for (int m = 0; m < 4; m++) {
            const char* rp = (const char*)&SM[0][d][mh][0] + (wr * 64 + m * 16 + l4) * 128;
            d0[m] = *(const short8*)(rp + ((g ^ sw) * 16));
            d1[m] = *(const short8*)(rp + (((4 + g) ^ sw) * 16));
        }
    };
    auto ldB = [&](int d, int ks, short8* dst) {
#pragma unroll
        for (int n = 0; n < 4; n++) {
            const char* rp = (const char*)&SM[1][d][ks][0] + ((wc & 1) * 64 + n * 16 + l4) * 128;
            dst[n] = *(const short8*)(rp + ((((wc >> 1) * 4 + g) ^ sw) * 16));
        }
    };

    G256_BODY()

    unsigned short* eb = (unsigned short*)SM;
    unsigned short* oB = (EPI == 3) ? po.o[z] : outB;
    const int colL = wc * 64 + l4;
#pragma unroll
    for (int h = 0; h < 2; ++h) {
        if (wr == h) {
#pragma unroll
            for (int mm = 0; mm < 8; mm++) {
                const int base_r = (mm < 4 ? mm * 16 : 64 + (mm - 4) * 16) + g * 4;
#pragma unroll
                for (int n = 0; n < 4; n++) {
                    float bv = (EPI == 3 && z != 0) ? 0.f : bias[n0 + colL + n * 16];
#pragma unroll
                    for (int r = 0; r < 4; r++) {
                        float v = acc[mm][n][r] + bv;
                        if (EPI == 2) v = fmaxf(v, 0.f);
                        eb[(base_r + r) * 260 + colL + n * 16] = f2bf(v);
                    }
                }
            }
        }
        __syncthreads();
        const int gr0 = m0 + h * 128;
#pragma unroll
        for (int j = 0; j < 8; j++) {
            const int f = j * 8192 + tid * 16;
            const int row = f >> 9;
            const int colb = f & 511;
            short8 v = *(const short8*)((const char*)eb + row * 520 + colb);
            *(short8*)(oB + (size_t)(gr0 + row) * N + n0 + (colb >> 1)) = v;
        }
        if (h == 0) __syncthreads();
    }
}

// ================= fused multi-job GEMM (QKV + eKV), runtime epilogue ===================
// job: A(M=4096,K) lda; Bt ldb; rowmajor out (stride N) for cols < vthresh;
// cols >= vthresh -> per-head V^T into vt.
struct GJob {
    const unsigned short *A, *Bt;
    const float* bias;
    unsigned short *out, *vt;
    int N, lda, ldb, nk, vthresh, nwg, gx;
};
struct GJ2 { GJob j[2]; };
__global__ __launch_bounds__(512, 2) void gemm256j(GJ2 p) {
    __shared__ unsigned short SM[2][2][2][8192];
    const int tid = threadIdx.x;
    const int lane = tid & 63, wid = tid >> 6;
    const int l4 = lane & 15, g = lane >> 4;
    const int wr = wid >> 2, wc = wid & 3;

    int f = blockIdx.x;
    const int ji = (f < p.j[0].nwg) ? 0 : 1;
    if (ji) f -= p.j[0].nwg;
    const GJob jb = p.j[ji];
    // job-local chunked-XCD + group-major remap
    const int id = (f & 7) * (jb.nwg >> 3) + (f >> 3);
    const int gwsh = (jb.gx & 7) ? 2 : 3;
    const int gw = 1 << gwsh;
    const int gy = jb.nwg / jb.gx;
    const int gsz = gw * gy;
    const int grp = id / gsz;
    const int rem = id - grp * gsz;
    const int m0 = (rem >> gwsh) * 256;
    const int n0 = ((grp << gwsh) + (rem & (gw - 1))) * 256;

    const unsigned short* A = jb.A;
    const unsigned short* Bt = jb.Bt;
    const int lda = jb.lda, ldb = jb.ldb, nk = jb.nk;
    const int sw = l4 & 7;

    const int fl0 = tid, fl1 = 512 + tid;
    const int lr0 = fl0 >> 3, ch0 = (fl0 & 7) ^ (lr0 & 7);
    const int lr1 = fl1 >> 3, ch1 = (fl1 & 7) ^ (lr1 & 7);
    const size_t A64 = (size_t)64 * lda;
    const unsigned short* pA0 = A + (size_t)(m0 + (lr0 >> 6) * 128 + (lr0 & 63)) * lda + ch0 * 8;
    const unsigned short* pA1 = A + (size_t)(m0 + (lr1 >> 6) * 128 + (lr1 & 63)) * lda + ch1 * 8;
    const unsigned short* pB0 = Bt + (size_t)(n0 + (ch0 >> 2) * 128 + lr0) * ldb + (ch0 & 3) * 8;
    const unsigned short* pB1 = Bt + (size_t)(n0 + (ch1 >> 2) * 128 + lr1) * ldb + (ch1 & 3) * 8;

    auto stA = [&](int d, int mh, int kofs) {
        char* base = (char*)&SM[0][d][mh][0];
        gload_lds16(pA0 + (size_t)mh * A64 + kofs, base + fl0 * 16);
        gload_lds16(pA1 + (size_t)mh * A64 + kofs, base + fl1 * 16);
    };
    auto stB = [&](int d, int ks, int kofs) {
        char* base = (char*)&SM[1][d][ks][0];
        gload_lds16(pB0 + ks * 32 + kofs, base + fl0 * 16);
        gload_lds16(pB1 + ks * 32 + kofs, base + fl1 * 16);
    };

    f32x4 acc[8][4] = {};
    short8 aF[4], aH[4], b0[4], b1[4];

    auto ldA = [&](int d, int mh, short8* d0, short8* d1) {
#pragma unroll
        for (int m = 0; m < 4; m++) {
            const char* rp = (const char*)&SM[0][d][mh][0] + (wr * 64 + m * 16 + l4) * 128;
            d0[m] = *(const short8*)(rp + ((g ^ sw) * 16));
            d1[m] = *(const short8*)(rp + (((4 + g) ^ sw) * 16));
        }
    };
    auto ldB = [&](int d, int ks, short8* dst) {
#pragma unroll
        for (int n = 0; n < 4; n++) {
            const char* rp = (const char*)&SM[1][d][ks][0] + ((wc & 1) * 64 + n * 16 + l4) * 128;
            dst[n] = *(const short8*)(rp + ((((wc >> 1) * 4 + g) ^ sw) * 16));
        }
    };

    G256_BODY()

    unsigned short* eb = (unsigned short*)SM;
    const int colL = wc * 64 + l4;
#pragma unroll
    for (int h = 0; h < 2; ++h) {
        if (wr == h) {
#pragma unroll
            for (int mm = 0; mm < 8; mm++) {
                const int base_r = (mm < 4 ? mm * 16 : 64 + (mm - 4) * 16) + g * 4;
#pragma unroll
                for (int n = 0; n < 4; n++) {
                    float bv = jb.bias[n0 + colL + n * 16];
#pragma unroll
                    for (int r = 0; r < 4; r++)
                        eb[(base_r + r) * 260 + colL + n * 16] = f2bf(acc[mm][n][r] + bv);
                }
            }
        }
        __syncthreads();
        const int gr0 = m0 + h * 128;
        if (n0 >= jb.vthresh) {
            // V segment: write per-head transposed [bh][dh][s]
            const int b_ = gr0 >> 10, sb = gr0 & 1023;
#pragma unroll
            for (int j = 0; j < 4; j++) {
                const int id2 = j * 512 + tid;
                const int col = id2 & 255, rseg = id2 >> 8;
                const int rel = n0 - jb.vthresh + col;
                const int hh = rel >> 6, dh = rel & 63;
                short8 v0, v1;
#pragma unroll
                for (int e = 0; e < 8; e++) {
                    v0[e] = eb[(rseg * 16 + e) * 260 + col];
                    v1[e] = eb[(rseg * 16 + 8 + e) * 260 + col];
                }
                unsigned short* dp = jb.vt +
                    ((size_t)(b_ * 16 + hh) * 64 + dh) * 1024 + sb + rseg * 16;
                *(short8*)dp = v0;
                *(short8*)(dp + 8) = v1;
            }
        } else {
#pragma unroll
            for (int j = 0; j < 8; j++) {
                const int ff = j * 8192 + tid * 16;
                const int row = ff >> 9;
                const int colb = ff & 511;
                short8 v = *(const short8*)((const char*)eb + row * 520 + colb);
                *(short8*)(jb.out + (size_t)(gr0 + row) * jb.N + n0 + (colb >> 1)) = v;
            }
        }
        if (h == 0) __syncthreads();
    }
}

// ---------------- GEMM 64x128: 3-buffer depth-2, counted vmcnt, XCD-swizzled ----------------
template <int EPI>
__global__ __launch_bounds__(256) void gemm64_db(const unsigned short* __restrict__ A,
                                                 const unsigned short* __restrict__ Bt,
                                                 const float* __restrict__ bias,
                                                 float* __restrict__ outF,
                                                 unsigned short* __restrict__ outB,
                                                 int M, int N, int Kloop, int lda, int ldb) {
    __shared__ unsigned short As[3][64 * 32];
    __shared__ unsigned short Bs[3][128 * 32];
    const int tid = threadIdx.x;
    const int w = tid >> 6, lane = tid & 63, l4 = lane & 15, g = lane >> 4;
    BlkMap bm = remap_block();
    const int m0 = bm.m * 64, n0 = bm.n * 128;
    f32x4 acc[4][2] = {};
    const int r0 = tid >> 2;
    const int kk = ((tid & 3) ^ ((tid >> 3) & 3)) * 8;
    const int sk = (l4 >> 1) & 3;
    const unsigned short* Ar0 = A + (size_t)(m0 + r0) * lda + kk;
    const unsigned short* Br0 = Bt + (size_t)(n0 + r0) * ldb + kk;
    const unsigned short* Br1 = Bt + (size_t)(n0 + 64 + r0) * ldb + kk;
    auto stage = [&](int sb, int k0) {
        gload_lds16(Ar0 + k0, (char*)As[sb] + tid * 16);
        gload_lds16(Br0 + k0, (char*)Bs[sb] + tid * 16);
        gload_lds16(Br1 + k0, (char*)Bs[sb] + 4096 + tid * 16);
    };
    const int nk = Kloop >> 5;
    stage(0, 0);
    stage(1, 32);
    asm volatile("s_waitcnt vmcnt(3)" ::: "memory");
    __builtin_amdgcn_s_barrier();
    asm volatile("" ::: "memory");
    int buf = 0;
    for (int t = 0; t < nk; ++t) {
        if (t + 2 < nk) {
            int b2 = buf + 2; if (b2 >= 3) b2 -= 3;
            stage(b2, (t + 2) * 32);
        }
        short8 a[4], b[2];
#pragma unroll
        for (int m = 0; m < 4; m++)
            a[m] = *(const short8*)(As[buf] + (m * 16 + l4) * 32 + (g ^ sk) * 8);
#pragma unroll
        for (int n = 0; n < 2; n++)
            b[n] = *(const short8*)(Bs[buf] + (w * 32 + n * 16 + l4) * 32 + (g ^ sk) * 8);
#pragma unroll
        for (int m = 0; m < 4; m++)
#pragma unroll
            for (int n = 0; n < 2; n++)
                acc[m][n] = __builtin_amdgcn_mfma_f32_16x16x32_bf16(a[m], b[n], acc[m][n], 0, 0, 0);
        if (t + 1 < nk) {
            if (t + 2 < nk) asm volatile("s_waitcnt vmcnt(3)" ::: "memory");
            else            asm volatile("s_waitcnt vmcnt(0)" ::: "memory");
            __builtin_amdgcn_s_barrier();
            asm volatile("" ::: "memory");
        }
        buf = (buf + 1 == 3) ? 0 : buf + 1;
    }
    const int rowB = m0 + g * 4;
    const int colB = n0 + w * 32 + l4;
#pragma unroll
    for (int n = 0; n < 2; n++) {
        float bv = bias[colB + n * 16];
#pragma unroll
        for (int m = 0; m < 4; m++) {
#pragma unroll
            for (int r = 0; r < 4; r++) {
                float v = acc[m][n][r] + bv;
                if (EPI == 2) v = fmaxf(v, 0.f);
                size_t idx = (size_t)(rowB + m * 16 + r) * N + colB + n * 16;
                if (EPI == 1) outF[idx] = v;
                else outB[idx] = f2bf(v);
            }
        }
    }
}

// ---------------- flash attention v6: 8 waves / 128 q-rows per block ----------------
template <int CAUSAL>
__global__ __launch_bounds__(512) void attn6_kernel(const unsigned short* __restrict__ Q, int ldq,
                                                    const unsigned short* __restrict__ Kg, int ldk,
                                                    const unsigned short* __restrict__ Vt,
                                                    unsigned short* __restrict__ O) {
    __shared__ unsigned short Kl[2 * 64 * 64];
    __shared__ unsigned short Vl[2 * 64 * 64];
    __shared__ unsigned short Pl[8][16 * 72];
    const int bh = blockIdx.x;
    const int qb = CAUSAL ? (gridDim.y - 1 - blockIdx.y) : blockIdx.y;
    const int b = bh >> 4, h = bh & 15;
    const int tid = threadIdx.x, w = tid >> 6, lane = tid & 63;
    const int l4 = lane & 15, g = lane >> 4;
    const int q0 = qb * 128 + w * 16;
    const unsigned short* Qp = Q + (size_t)(b * Tc + q0 + l4) * ldq + h * DHc + g * 8;
    short8 qf0 = *(const short8*)Qp;
    short8 qf1 = *(const short8*)(Qp + 32);
    const unsigned short* Kbase = Kg + (size_t)(b * 1024) * ldk + h * DHc;
    const unsigned short* Vbase = Vt + (size_t)bh * DHc * 1024;
    f32x4 o[4] = {};
    float mrun = -1e30f, lrun = 0.f;
    const int nT = CAUSAL ? 2 * qb + 2 : 16;
    unsigned short* pw = &Pl[w][l4 * 72];
    const int qi = q0 + l4;

    short8 ones;
#pragma unroll
    for (int j = 0; j < 8; j++) ones[j] = (short)0x3F80;

    const int sr = tid >> 3;
    const int sc_ = (tid & 7) ^ (sr & 7);

    auto stage = [&](int s0, int buf) {
        char* kd = (char*)Kl + buf * 8192;
        char* vd = (char*)Vl + buf * 8192;
        gload_lds16(Kbase + (size_t)(s0 + sr) * ldk + sc_ * 8, kd + tid * 16);
        gload_lds16(Vbase + (size_t)sr * 1024 + s0 + sc_ * 8, vd + tid * 16);
    };

    stage(0, 0);
    __syncthreads();
    int buf = 0;
    const int sw = l4 & 7;

    for (int t = 0; t < nT; ++t) {
        const int s0 = t * 64;
        if (t + 1 < nT) stage(s0 + 64, buf ^ 1);
        if (!CAUSAL || s0 <= q0 + 15) {
            const unsigned short* Kb_ = Kl + buf * 4096;
            const unsigned short* Vb_ = Vl + buf * 4096;
            f32x4 st[4];
            f32x4 z = {0.f, 0.f, 0.f, 0.f};
            __builtin_amdgcn_s_setprio(1);
#pragma unroll
            for (int c = 0; c < 4; c++) {
                const unsigned short* kr = Kb_ + (c * 16 + l4) * 64;
                short8 ka0 = *(const short8*)(kr + ((g ^ sw) * 8));
                short8 ka1 = *(const short8*)(kr + (((g + 4) ^ sw) * 8));
                st[c] = __builtin_amdgcn_mfma_f32_16x16x32_bf16(ka0, qf0, z, 0, 0, 0);
                st[c] = __builtin_amdgcn_mfma_f32_16x16x32_bf16(ka1, qf1, st[c], 0, 0, 0);
            }
            __builtin_amdgcn_s_setprio(0);
            float p[16];
            const bool domask = CAUSAL && (s0 + 63 > q0);
#pragma unroll
            for (int c = 0; c < 4; c++)
#pragma unroll
                for (int r = 0; r < 4; r++) {
                    float v = st[c][r];
                    if (domask && (s0 + c * 16 + g * 4 + r) > qi) v = -1e9f;
                    p[c * 4 + r] = v;
                }
            float m1 = fmaxf(fmaxf(p[0], p[1]), p[2]);
            float m2 = fmaxf(fmaxf(p[3], p[4]), p[5]);
            float m3 = fmaxf(fmaxf(p[6], p[7]), p[8]);
            float m4 = fmaxf(fmaxf(p[9], p[10]), p[11]);
            float m5 = fmaxf(fmaxf(p[12], p[13]), p[14]);
            float tmax = fmaxf(fmaxf(fmaxf(m1, m2), fmaxf(m3, m4)), fmaxf(m5, p[15]));
            tmax = fmaxf(tmax, __shfl_xor(tmax, 16));
            tmax = fmaxf(tmax, __shfl_xor(tmax, 32));
            if (!__all(tmax <= mrun + 11.5f)) {
                float mnew = fmaxf(mrun, tmax);
                float al = fexp2(mrun - mnew);
                lrun *= al;
#pragma unroll
                for (int d = 0; d < 4; d++) o[d] *= al;
                mrun = mnew;
            }
#pragma unroll
            for (int i = 0; i < 16; i++) p[i] = fexp2(p[i] - mrun);
#pragma unroll
            for (int c = 0; c < 4; c++) {
                uint2 u;
                u.x = cvtpk(p[c * 4 + 0], p[c * 4 + 1]);
                u.y = cvtpk(p[c * 4 + 2], p[c * 4 + 3]);
                *(uint2*)(pw + c * 16 + g * 4) = u;
            }
            short8 pb_lo = *(const short8*)(pw + g * 8);
            short8 pb_hi = *(const short8*)(pw + 32 + g * 8);
            __builtin_amdgcn_s_setprio(1);
            f32x4 s4 = __builtin_amdgcn_mfma_f32_16x16x32_bf16(ones, pb_lo, z, 0, 0, 0);
            s4 = __builtin_amdgcn_mfma_f32_16x16x32_bf16(ones, pb_hi, s4, 0, 0, 0);
#pragma unroll
            for (int d = 0; d < 4; d++) {
                const unsigned short* vr = Vb_ + (d * 16 + l4) * 64;
                short8 va0 = *(const short8*)(vr + ((g ^ sw) * 8));
                short8 va1 = *(const short8*)(vr + (((g + 4) ^ sw) * 8));
                o[d] = __builtin_amdgcn_mfma_f32_16x16x32_bf16(va0, pb_lo, o[d], 0, 0, 0);
                o[d] = __builtin_amdgcn_mfma_f32_16x16x32_bf16(va1, pb_hi, o[d], 0, 0, 0);
            }
            __builtin_amdgcn_s_setprio(0);
            lrun += s4[0];
        }
        __syncthreads();
        buf ^= 1;
    }
    float inv = 1.f / lrun;
    unsigned short* Ob = O + (size_t)(b * Tc + q0 + l4) * Dc + h * DHc;
#pragma unroll
    for (int d = 0; d < 4; d++) {
#pragma unroll
        for (int r = 0; r < 4; r++) Ob[d * 16 + g * 4 + r] = f2bf(o[d][r] * inv);
    }
}

// ---------------- fused residual-add + LayerNorm (bf16 a + bf16 res) ----------------
__global__ __launch_bounds__(256) void ln_bf(const unsigned short* __restrict__ a,
                                             const unsigned short* __restrict__ res,
                                             const float* __restrict__ gam,
                                             const float* __restrict__ bet,
                                             unsigned short* __restrict__ outB,
                                             float* __restrict__ outF) {
    int row = blockIdx.x, t = threadIdx.x;
    size_t base = (size_t)row * Dc + t * 4;
    short4v av = *(const short4v*)(a + base);
    short4v rv = *(const short4v*)(res + base);
    float x0 = bf2f((unsigned short)av[0]) + bf2f((unsigned short)rv[0]);
    float x1 = bf2f((unsigned short)av[1]) + bf2f((unsigned short)rv[1]);
    float x2 = bf2f((unsigned short)av[2]) + bf2f((unsigned short)rv[2]);
    float x3 = bf2f((unsigned short)av[3]) + bf2f((unsigned short)rv[3]);
    float s = x0 + x1 + x2 + x3;
    float ss = x0 * x0 + x1 * x1 + x2 * x2 + x3 * x3;
    for (int o = 1; o < 64; o <<= 1) { s += __shfl_xor(s, o); ss += __shfl_xor(ss, o); }
    __shared__ float S1[4], S2[4];
    int w = t >> 6;
    if ((t & 63) == 0) { S1[w] = s; S2[w] = ss; }
    __syncthreads();
    s = S1[0] + S1[1] + S1[2] + S1[3];
    ss = S2[0] + S2[1] + S2[2] + S2[3];
    float mean = s * (1.f / Dc);
    float var = ss * (1.f / Dc) - mean * mean;
    float rstd = rsqrtf(var + 1e-5f);
    int c = t * 4;
    float4 g4 = *(const float4*)(gam + c);
    float4 b4 = *(const float4*)(bet + c);
    float y0 = (x0 - mean) * rstd * g4.x + b4.x;
    float y1 = (x1 - mean) * rstd * g4.y + b4.y;
    float y2 = (x2 - mean) * rstd * g4.z + b4.z;
    float y3 = (x3 - mean) * rstd * g4.w + b4.w;
    if (outB) {
        short4v ob;
        ob[0] = f2bf(y0); ob[1] = f2bf(y1); ob[2] = f2bf(y2); ob[3] = f2bf(y3);
        *(short4v*)(outB + base) = ob;
    }
    if (outF) { float4 ov = {y0, y1, y2, y3}; *(float4*)(outF + base) = ov; }
}

// ---------------- LN over 4 bf16 split-K partials + bf16 residual -> f32 out ----------------
__global__ __launch_bounds__(256) void ln_4b(const unsigned short* __restrict__ p,
                                             const unsigned short* __restrict__ res,
                                             const float* __restrict__ gam,
                                             const float* __restrict__ bet,
                                             float* __restrict__ outF) {
    const size_t PS = (size_t)4096 * 1024;
    int row = blockIdx.x, t = threadIdx.x;
    size_t base = (size_t)row * Dc + t * 4;
    float x0, x1, x2, x3;
    {
        short4v rv = *(const short4v*)(res + base);
        x0 = bf2f((unsigned short)rv[0]); x1 = bf2f((unsigned short)rv[1]);
        x2 = bf2f((unsigned short)rv[2]); x3 = bf2f((unsigned short)rv[3]);
    }
#pragma unroll
    for (int j = 0; j < 4; j++) {
        short4v v = *(const short4v*)(p + j * PS + base);
        x0 += bf2f((unsigned short)v[0]); x1 += bf2f((unsigned short)v[1]);
        x2 += bf2f((unsigned short)v[2]); x3 += bf2f((unsigned short)v[3]);
    }
    float s = x0 + x1 + x2 + x3;
    float ss = x0 * x0 + x1 * x1 + x2 * x2 + x3 * x3;
    for (int o = 1; o < 64; o <<= 1) { s += __shfl_xor(s, o); ss += __shfl_xor(ss, o); }
    __shared__ float S1[4], S2[4];
    int w = t >> 6;
    if ((t & 63) == 0) { S1[w] = s; S2[w] = ss; }
    __syncthreads();
    s = S1[0] + S1[1] + S1[2] + S1[3];
    ss = S2[0] + S2[1] + S2[2] + S2[3];
    float mean = s * (1.f / Dc);
    float var = ss * (1.f / Dc) - mean * mean;
    float rstd = rsqrtf(var + 1e-5f);
    int c = t * 4;
    float4 g4 = *(const float4*)(gam + c);
    float4 b4 = *(const float4*)(bet + c);
    float4 ov;
    ov.x = (x0 - mean) * rstd * g4.x + b4.x;
    ov.y = (x1 - mean) * rstd * g4.y + b4.y;
    ov.z = (x2 - mean) * rstd * g4.z + b4.z;
    ov.w = (x3 - mean) * rstd * g4.w + b4.w;
    *(float4*)(outF + base) = ov;
}

// ---------------- launch ----------------
extern "C" void kernel_launch(void* const* d_in, const int* in_sizes, int n_in,
                              void* d_out, int out_size, void* d_ws, size_t ws_size,
                              hipStream_t stream) {
    const float* x   = (const float*)d_in[0];
    const float* enc = (const float*)d_in[1];
    const float* dWq = (const float*)d_in[4];  const float* dbq = (const float*)d_in[5];
    const float* dWk = (const float*)d_in[6];  const float* dbk = (const float*)d_in[7];
    const float* dWv = (const float*)d_in[8];  const float* dbv = (const float*)d_in[9];
    const float* dWo = (const float*)d_in[10]; const float* dbo = (const float*)d_in[11];
    const float* eWq = (const float*)d_in[12]; const float* ebq = (const float*)d_in[13];
    const float* eWk = (const float*)d_in[14]; const float* ebk = (const float*)d_in[15];
    const float* eWv = (const float*)d_in[16]; const float* ebv = (const float*)d_in[17];
    const float* eWo = (const float*)d_in[18]; const float* ebo = (const float*)d_in[19];
    const float* fW1 = (const float*)d_in[20]; const float* fb1 = (const float*)d_in[21];
    const float* fW2 = (const float*)d_in[22]; const float* fb2 = (const float*)d_in[23];
    const float* g1 = (const float*)d_in[24];  const float* be1 = (const float*)d_in[25];
    const float* g2 = (const float*)d_in[26];  const float* be2 = (const float*)d_in[27];
    const float* g3 = (const float*)d_in[28];  const float* be3 = (const float*)d_in[29];

    const float SC = 0.125f * 1.44269504f;

    char* ws = (char*)d_ws;
    size_t off = 0;
    auto alloc = [&](size_t bytes) -> void* {
        void* p = ws + off;
        off += (bytes + 255) & ~(size_t)255;
        return p;
    };
    const size_t A = (size_t)4096 * 1024;
    const size_t MB1 = (size_t)1024 * 1024;
    char* R1 = (char*)alloc(32 * 1024 * 1024);
    unsigned short* qkv = (unsigned short*)R1;                       // stride 3072 (Q,K cols only)
    unsigned short* qx  = (unsigned short*)(R1 + 16 * 1024 * 1024);  // stride 1024
    unsigned short* h1  = (unsigned short*)R1;                       // 4096x4096
    unsigned short* xb   = (unsigned short*)alloc(A * 2);
    unsigned short* encb = (unsigned short*)alloc(A * 2);
    unsigned short* wqkv = (unsigned short*)alloc(3 * MB1 * 2);
    unsigned short* wekv = (unsigned short*)alloc(2 * MB1 * 2);
    unsigned short* weq  = (unsigned short*)alloc(MB1 * 2);
    unsigned short* wdo  = (unsigned short*)alloc(MB1 * 2);
    unsigned short* weo  = (unsigned short*)alloc(MB1 * 2);
    unsigned short* wf1  = (unsigned short*)alloc(4 * MB1 * 2);
    unsigned short* wf2  = (unsigned short*)alloc(4 * MB1 * 2);
    float* bqkv = (float*)alloc(3072 * 4);
    float* bekv = (float*)alloc(2048 * 4);
    float* ebq_s = (float*)alloc(1024 * 4);
    unsigned short* VtB = (unsigned short*)alloc(A * 2);
    unsigned short* ab  = (unsigned short*)alloc(A * 2);
    unsigned short* tmpB = (unsigned short*)alloc(A * 2);
    unsigned short* dB = (unsigned short*)alloc(A * 2);
    unsigned short* fB = (unsigned short*)alloc(A * 2);
    unsigned short* kb  = (unsigned short*)alloc(A * 2);   // cross-K rows (stride 1024)
    unsigned short* vtc = (unsigned short*)alloc(A * 2);   // cross V^T
    unsigned short* pfb = VtB;                             // FFN2 partials alias VtB..dB
    (void)ws_size; (void)in_sizes; (void)n_in; (void)out_size;

    cast2_f32_bf16<<<dim3(2048, 2), 256, 0, stream>>>(x, enc, xb, encb, (int)(A / 8));

    TJ16 tj;
    tj.j[0] = {dWq, wqkv,           1024, 1024, SC};
    tj.j[1] = {dWk, wqkv + MB1,     1024, 1024, 1.f};
    tj.j[2] = {dWv, wqkv + 2 * MB1, 1024, 1024, 1.f};
    tj.j[3] = {eWk, wekv,           1024, 1024, 1.f};
    tj.j[4] = {eWv, wekv + MB1,     1024, 1024, 1.f};
    tj.j[5] = {eWq, weq,            1024, 1024, SC};
    tj.j[6] = {dWo, wdo,            1024, 1024, 1.f};
    tj.j[7] = {eWo, weo,            1024, 1024, 1.f};
    for (int jj = 0; jj < 4; jj++) {
        tj.j[8 + jj]  = {fW1 + 1024 * jj, wf1 + (size_t)1024 * jj * 1024, 4096, 1024, 1.f};
        tj.j[12 + jj] = {fW2 + (size_t)1024 * jj * 1024, wf2 + 1024 * jj, 1024, 4096, 1.f};
    }
    transpose_cast16<<<dim3(16, 16, 16), 256, 0, stream>>>(tj);
    prep_bias<<<24, 256, 0, stream>>>(dbq, dbk, dbv, ebk, ebv, ebq, bqkv, bekv, ebq_s, SC);

    P8 z8{};

    // ---- fused QKV + eKV dispatch (320 blocks) ----
    {
        GJ2 gj;
        // job0: QKV. A=xb, Bt=wqkv, N(out stride)=3072, vthresh=2048 -> V^T to VtB
        gj.j[0] = {xb, wqkv, bqkv, qkv, VtB, 3072, 1024, 1024, 16, 2048, 192, 12};
        // job1: eKV. A=encb, Bt=wekv, K rows -> kb (stride 1024), vthresh=1024 -> V^T to vtc
        gj.j[1] = {encb, wekv, bekv, kb, vtc, 1024, 1024, 1024, 16, 1024, 128, 8};
        gemm256j<<<dim3(320), 512, 0, stream>>>(gj);
    }

    // ---- self-attention block ----
    attn6_kernel<1><<<dim3(64, 8), 512, 0, stream>>>(qkv, 3072, qkv + 1024, 3072, VtB, ab);
    gemm64_db<0><<<dim3(8, 64), 256, 0, stream>>>(ab, wdo, dbo, nullptr, tmpB, 4096, 1024, 1024, 1024, 1024);
    ln_bf<<<4096, 256, 0, stream>>>(tmpB, xb, g1, be1, dB, nullptr);

    // ---- cross-attention block ----
    gemm64_db<0><<<dim3(8, 64), 256, 0, stream>>>(dB, weq, ebq_s, nullptr, qx, 4096, 1024, 1024, 1024, 1024);
    attn6_kernel<0><<<dim3(64, 8), 512, 0, stream>>>(qx, 1024, kb, 1024, vtc, ab);
    gemm64_db<0><<<dim3(8, 64), 256, 0, stream>>>(ab, weo, ebo, nullptr, tmpB, 4096, 1024, 1024, 1024, 1024);
    ln_bf<<<4096, 256, 0, stream>>>(tmpB, dB, g2, be2, fB, nullptr);

    // ---- FFN block ----
    gemm256<2><<<dim3(16, 16), 512, 0, stream>>>(fB, wf1, fb1, h1, 4096, 1024, 1024, 16, z8);
    {
        P8 pf{};
        pf.o[0] = pfb;
        pf.o[1] = pfb + A;
        pf.o[2] = pfb + 2 * A;
        pf.o[3] = pfb + 3 * A;
        gemm256<3><<<dim3(4, 16, 4), 512, 0, stream>>>(h1, wf2, fb2, nullptr, 1024, 4096, 4096, 16, pf);
    }
    ln_4b<<<4096, 256, 0, stream>>>(pfb, fB, g3, be3, (float*)d_out);
}